// Round 1
// baseline (1762.658 us; speedup 1.0000x reference)
//
#include <hip/hip_runtime.h>
#include <math.h>

constexpr int kB = 8;
constexpr int kC = 512;
constexpr int kC4 = 128;
constexpr int kN = 2048;

// ---------------------------------------------------------------- mask count
__global__ __launch_bounds__(256) void k_cnt(const int* __restrict__ mask,
                                             float* __restrict__ cnt) {
  const int b = blockIdx.x;
  const int t = threadIdx.x;
  int s = 0;
  for (int i = t; i < kN; i += 256) s += mask[b * kN + i];
  __shared__ int red[256];
  red[t] = s;
  __syncthreads();
  for (int off = 128; off > 0; off >>= 1) {
    if (t < off) red[t] += red[t + off];
    __syncthreads();
  }
  if (t == 0) cnt[b] = (float)red[0];
}

// ------------------------------------------------- 1x1 conv projections (GEMM)
// out[b,m,n] = sum_c W[m,c] * X[b,c,n] (+ bias[m])
template <int M, bool HASB>
__global__ __launch_bounds__(256) void k_proj(const float* __restrict__ W,
                                              const float* __restrict__ X,
                                              const float* __restrict__ bias,
                                              float* __restrict__ out) {
  const int b = blockIdx.z;
  const int m0 = blockIdx.y * 64;
  const int n0 = blockIdx.x * 64;
  __shared__ float Ws[32][68];  // [k][m]
  __shared__ float Xs[32][68];  // [k][n]
  const int tid = threadIdx.x;
  const int tx = tid & 15, ty = tid >> 4;
  float acc[4][4] = {};
  const float* Xb = X + (size_t)b * kC * kN;
  for (int k0 = 0; k0 < kC; k0 += 32) {
    {
      const int lc = tid & 31, lr = tid >> 5;
#pragma unroll
      for (int rr = 0; rr < 64; rr += 8)
        Ws[lc][lr + rr] = W[(size_t)(m0 + lr + rr) * kC + k0 + lc];
    }
    {
      const int qc = tid & 15, qr = tid >> 4;
#pragma unroll
      for (int rr = 0; rr < 32; rr += 16)
        *(float4*)&Xs[qr + rr][qc * 4] =
            *(const float4*)&Xb[(size_t)(k0 + qr + rr) * kN + n0 + qc * 4];
    }
    __syncthreads();
#pragma unroll
    for (int k = 0; k < 32; k++) {
      const float4 a4 = *(const float4*)&Ws[k][ty * 4];
      const float4 b4 = *(const float4*)&Xs[k][tx * 4];
      const float av[4] = {a4.x, a4.y, a4.z, a4.w};
      const float bv2[4] = {b4.x, b4.y, b4.z, b4.w};
#pragma unroll
      for (int i = 0; i < 4; i++)
#pragma unroll
        for (int j = 0; j < 4; j++) acc[i][j] = fmaf(av[i], bv2[j], acc[i][j]);
    }
    __syncthreads();
  }
#pragma unroll
  for (int i = 0; i < 4; i++) {
    const int m = m0 + ty * 4 + i;
    const float bb = HASB ? bias[m] : 0.0f;
    float4 o = {acc[i][0] + bb, acc[i][1] + bb, acc[i][2] + bb, acc[i][3] + bb};
    *(float4*)&out[((size_t)b * M + m) * kN + n0 + tx * 4] = o;
  }
}

// ----------------------------------------------- pass 1: row max / sum of exp
// z[n,m] = m2 ? e/(cnt+1e-9) : (mask[m] ? -9e15/(cnt+1e-9) : -9e24)
__global__ __launch_bounds__(256) void k_stats(
    const float* __restrict__ qt, const float* __restrict__ kt,
    const int* __restrict__ mask, const float* __restrict__ cnt,
    float* __restrict__ rowmax, float* __restrict__ rowsum) {
  const int b = blockIdx.y;
  const int n0 = blockIdx.x * 64;
  __shared__ float qs[kC4][68];
  __shared__ float ks[kC4][68];
  __shared__ int ms[64];
  const int tid = threadIdx.x;
  const int tm = tid & 15, tn = tid >> 4;
  const float cb = cnt[b];
  const float invd = 1.0f / (cb + 1e-9f);
  const float zrow = -9e15f * invd;
  {
    const int c4 = tid & 15, d0 = tid >> 4;
    for (int dd = 0; dd < kC4; dd += 16)
      *(float4*)&qs[d0 + dd][c4 * 4] =
          *(const float4*)&qt[((size_t)b * kC4 + d0 + dd) * kN + n0 + c4 * 4];
  }
  int mn[4];
#pragma unroll
  for (int i = 0; i < 4; i++) mn[i] = mask[b * kN + n0 + tn * 4 + i];
  float rm[4], rs[4];
#pragma unroll
  for (int i = 0; i < 4; i++) {
    rm[i] = -INFINITY;
    rs[i] = 0.0f;
  }
  for (int m0 = 0; m0 < kN; m0 += 64) {
    __syncthreads();
    {
      const int c4 = tid & 15, d0 = tid >> 4;
      for (int dd = 0; dd < kC4; dd += 16)
        *(float4*)&ks[d0 + dd][c4 * 4] =
            *(const float4*)&kt[((size_t)b * kC4 + d0 + dd) * kN + m0 + c4 * 4];
      if (tid < 64) ms[tid] = mask[b * kN + m0 + tid];
    }
    __syncthreads();
    float e[4][4] = {};
#pragma unroll 4
    for (int d = 0; d < kC4; d++) {
      const float4 a4 = *(const float4*)&qs[d][tn * 4];
      const float4 b4 = *(const float4*)&ks[d][tm * 4];
      const float av[4] = {a4.x, a4.y, a4.z, a4.w};
      const float bv2[4] = {b4.x, b4.y, b4.z, b4.w};
#pragma unroll
      for (int i = 0; i < 4; i++)
#pragma unroll
        for (int j = 0; j < 4; j++) e[i][j] = fmaf(av[i], bv2[j], e[i][j]);
    }
    int mm[4];
#pragma unroll
    for (int j = 0; j < 4; j++) mm[j] = ms[tm * 4 + j];
#pragma unroll
    for (int i = 0; i < 4; i++) {
      float z[4];
#pragma unroll
      for (int j = 0; j < 4; j++)
        z[j] = mm[j] ? ((mn[i] && mm[j]) ? e[i][j] * invd : zrow) : -9e24f;
      float tmax = fmaxf(fmaxf(z[0], z[1]), fmaxf(z[2], z[3]));
#pragma unroll
      for (int off = 1; off < 16; off <<= 1)
        tmax = fmaxf(tmax, __shfl_xor(tmax, off, 16));
      const float newm = fmaxf(rm[i], tmax);
      float p = 0.0f;
#pragma unroll
      for (int j = 0; j < 4; j++) p += __expf(z[j] - newm);
#pragma unroll
      for (int off = 1; off < 16; off <<= 1) p += __shfl_xor(p, off, 16);
      rs[i] = rs[i] * __expf(rm[i] - newm) + p;
      rm[i] = newm;
    }
  }
  if (tm == 0) {
#pragma unroll
    for (int i = 0; i < 4; i++) {
      rowmax[b * kN + n0 + tn * 4 + i] = rm[i];
      rowsum[b * kN + n0 + tn * 4 + i] = rs[i];
    }
  }
}

// --------------------- pass 2: x_r = x_v @ A  (recompute energy), h = x - x_r
__global__ __launch_bounds__(512) void k_attn(
    const float* __restrict__ qt, const float* __restrict__ kt,
    const float* __restrict__ xv, const float* __restrict__ x,
    const int* __restrict__ mask, const float* __restrict__ cnt,
    const float* __restrict__ rowmax, const float* __restrict__ rowsum,
    float* __restrict__ hout) {
  const int b = blockIdx.y;
  const int m0 = blockIdx.x * 32;
  __shared__ float ks[kC4][36];    // K-tile [d][m]
  __shared__ float xvs[256][36];   // half of x_v c-rows for current n-tile
  __shared__ float As[32][36];     // attention tile [n][m]
  __shared__ int msm[32];
  const int tid = threadIdx.x;
  const float cb = cnt[b];
  const float invd = 1.0f / (cb + 1e-9f);
  const float zrow = -9e15f * invd;
  {
    const int q = tid & 7, r = tid >> 3;
    for (int dd = 0; dd < kC4; dd += 64)
      *(float4*)&ks[dd + r][q * 4] =
          *(const float4*)&kt[((size_t)b * kC4 + dd + r) * kN + m0 + q * 4];
    if (tid < 32) msm[tid] = mask[b * kN + m0 + tid];
  }
  const int tx = tid & 7, ty = tid >> 3;        // accumulate layout
  const int en = tid & 31, em = (tid >> 5) * 2; // energy layout
  float acc[8][4] = {};
  const float* qb = qt + (size_t)b * kC4 * kN;
  for (int n0 = 0; n0 < kN; n0 += 32) {
    __syncthreads();
    // stage x_v rows [0,256) for this n-tile
    {
      const int q = tid & 7, r = tid >> 3;
      for (int cc = 0; cc < 256; cc += 64)
        *(float4*)&xvs[cc + r][q * 4] =
            *(const float4*)&xv[((size_t)b * kC + cc + r) * kN + n0 + q * 4];
    }
    // energy -> attention weights (qt read straight from global/L2)
    {
      float e0 = 0.0f, e1 = 0.0f;
      const float* qp = qb + n0 + en;
#pragma unroll 8
      for (int d = 0; d < kC4; d++) {
        const float a = qp[(size_t)d * kN];
        e0 = fmaf(a, ks[d][em], e0);
        e1 = fmaf(a, ks[d][em + 1], e1);
      }
      const int mnv = mask[b * kN + n0 + en];
      const float rmv = rowmax[b * kN + n0 + en];
      const float rinv = 1.0f / rowsum[b * kN + n0 + en];
      const int mm0 = msm[em], mm1 = msm[em + 1];
      const float z0 = mm0 ? (mnv ? e0 * invd : zrow) : -9e24f;
      const float z1 = mm1 ? (mnv ? e1 * invd : zrow) : -9e24f;
      As[en][em] = __expf(z0 - rmv) * rinv;
      As[en][em + 1] = __expf(z1 - rmv) * rinv;
    }
    __syncthreads();
    // accumulate c-rows [0,256): c = ty + 64*ic
#pragma unroll 2
    for (int nn = 0; nn < 32; nn++) {
      const float4 av = *(const float4*)&As[nn][tx * 4];
#pragma unroll
      for (int ic = 0; ic < 4; ic++) {
        const float xvv = xvs[ty + 64 * ic][nn];
        acc[ic][0] = fmaf(xvv, av.x, acc[ic][0]);
        acc[ic][1] = fmaf(xvv, av.y, acc[ic][1]);
        acc[ic][2] = fmaf(xvv, av.z, acc[ic][2]);
        acc[ic][3] = fmaf(xvv, av.w, acc[ic][3]);
      }
    }
    __syncthreads();
    // stage x_v rows [256,512)
    {
      const int q = tid & 7, r = tid >> 3;
      for (int cc = 0; cc < 256; cc += 64)
        *(float4*)&xvs[cc + r][q * 4] =
            *(const float4*)&xv[((size_t)b * kC + 256 + cc + r) * kN + n0 + q * 4];
    }
    __syncthreads();
#pragma unroll 2
    for (int nn = 0; nn < 32; nn++) {
      const float4 av = *(const float4*)&As[nn][tx * 4];
#pragma unroll
      for (int ic = 4; ic < 8; ic++) {
        const float xvv = xvs[ty + 64 * (ic - 4)][nn];
        acc[ic][0] = fmaf(xvv, av.x, acc[ic][0]);
        acc[ic][1] = fmaf(xvv, av.y, acc[ic][1]);
        acc[ic][2] = fmaf(xvv, av.z, acc[ic][2]);
        acc[ic][3] = fmaf(xvv, av.w, acc[ic][3]);
      }
    }
  }
  // h = x - x_r
#pragma unroll
  for (int ic = 0; ic < 8; ic++) {
    const size_t base = ((size_t)b * kC + ty + 64 * ic) * kN + m0 + tx * 4;
    const float4 xval = *(const float4*)&x[base];
    float4 h = {xval.x - acc[ic][0], xval.y - acc[ic][1],
                xval.z - acc[ic][2], xval.w - acc[ic][3]};
    *(float4*)&hout[base] = h;
  }
}

// -------- pass 3 (in-place on d_out): wt@h + bt -> BN(eval) -> ReLU -> +x
__global__ __launch_bounds__(256) void k_final(
    const float* __restrict__ x, const float* __restrict__ wt,
    const float* __restrict__ bt, const float* __restrict__ gamma,
    const float* __restrict__ beta, const float* __restrict__ rmean,
    const float* __restrict__ rvar, float* __restrict__ io) {
  const int b = blockIdx.y;
  const int n0 = blockIdx.x * 16;
  __shared__ float hs[kC][20];
  const int tid = threadIdx.x;
  {
    const int q = tid & 3, r = tid >> 2;
    for (int cc = 0; cc < kC; cc += 64)
      *(float4*)&hs[cc + r][q * 4] =
          *(const float4*)&io[((size_t)b * kC + cc + r) * kN + n0 + q * 4];
  }
  __syncthreads();
  const int tn = tid & 15, tg = tid >> 4;
  float acc[32] = {};
  for (int kt8 = 0; kt8 < 8; kt8++) {  // k-slab of 64
    float hv[64];
#pragma unroll
    for (int u = 0; u < 64; u++) hv[u] = hs[kt8 * 64 + u][tn];
#pragma unroll
    for (int j = 0; j < 32; j++) {
      const float* wrow = &wt[(size_t)(tg * 32 + j) * kC + kt8 * 64];
      float s = acc[j];
#pragma unroll
      for (int q = 0; q < 16; q++) {
        const float4 w = *(const float4*)&wrow[q * 4];
        s = fmaf(hv[q * 4 + 0], w.x, s);
        s = fmaf(hv[q * 4 + 1], w.y, s);
        s = fmaf(hv[q * 4 + 2], w.z, s);
        s = fmaf(hv[q * 4 + 3], w.w, s);
      }
      acc[j] = s;
    }
  }
#pragma unroll
  for (int j = 0; j < 32; j++) {
    const int cp = tg * 32 + j;
    float val = acc[j] + bt[cp];
    val = (val - rmean[cp]) * (gamma[cp] * rsqrtf(rvar[cp] + 1e-5f)) + beta[cp];
    val = fmaxf(val, 0.0f);
    const size_t idx = ((size_t)b * kC + cp) * kN + n0 + tn;
    io[idx] = x[idx] + val;
  }
}

extern "C" void kernel_launch(void* const* d_in, const int* in_sizes, int n_in,
                              void* d_out, int out_size, void* d_ws,
                              size_t ws_size, hipStream_t stream) {
  const float* x = (const float*)d_in[0];
  const float* query = (const float*)d_in[1];
  const int* mask = (const int*)d_in[2];
  const float* wqk = (const float*)d_in[3];
  const float* wv = (const float*)d_in[4];
  const float* bv = (const float*)d_in[5];
  const float* wt = (const float*)d_in[6];
  const float* bt = (const float*)d_in[7];
  const float* gamma = (const float*)d_in[8];
  const float* beta = (const float*)d_in[9];
  const float* rmean = (const float*)d_in[10];
  const float* rvar = (const float*)d_in[11];
  float* out = (float*)d_out;
  float* ws = (float*)d_ws;

  // workspace layout (floats): ~48.1 MB total
  float* qt = ws;                                  // [B][C4][N]
  float* kt = qt + (size_t)kB * kC4 * kN;          // [B][C4][N]
  float* xv = kt + (size_t)kB * kC4 * kN;          // [B][C][N]
  float* rowmax = xv + (size_t)kB * kC * kN;       // [B][N]
  float* rowsum = rowmax + kB * kN;                // [B][N]
  float* cnt = rowsum + kB * kN;                   // [B]

  k_cnt<<<kB, 256, 0, stream>>>(mask, cnt);
  k_proj<kC4, false><<<dim3(kN / 64, kC4 / 64, kB), 256, 0, stream>>>(
      wqk, query, nullptr, qt);
  k_proj<kC4, false><<<dim3(kN / 64, kC4 / 64, kB), 256, 0, stream>>>(
      wqk, x, nullptr, kt);
  k_proj<kC, true><<<dim3(kN / 64, kC / 64, kB), 256, 0, stream>>>(
      wv, x, bv, xv);
  k_stats<<<dim3(kN / 64, kB), 256, 0, stream>>>(qt, kt, mask, cnt, rowmax,
                                                 rowsum);
  k_attn<<<dim3(kN / 32, kB), 512, 0, stream>>>(qt, kt, xv, x, mask, cnt,
                                                rowmax, rowsum, out);
  k_final<<<dim3(kN / 16, kB), 256, 0, stream>>>(x, wt, bt, gamma, beta, rmean,
                                                 rvar, out);
}

// Round 3
// 791.147 us; speedup vs baseline: 2.2280x; 2.2280x over previous
//
#include <hip/hip_runtime.h>
#include <math.h>

typedef __bf16 bf16;
typedef bf16 bf16x8 __attribute__((ext_vector_type(8)));
typedef bf16 bf16x4 __attribute__((ext_vector_type(4)));
typedef float f32x4 __attribute__((ext_vector_type(4)));

constexpr int kB = 8, kC = 512, kC4 = 128, kN = 2048;

#define MFMA16(a, b, c) __builtin_amdgcn_mfma_f32_16x16x32_bf16(a, b, c, 0, 0, 0)

// ---------------------------------------------------------------- prep:
// mask popcount per batch + weight conversions (wqk, wv -> bf16; wt -> hi/lo
// bf16 split) + invg = gamma*rsqrt(rvar+eps)
__global__ __launch_bounds__(256) void k_prep(
    const int* __restrict__ mask, const float* __restrict__ wqk,
    const float* __restrict__ wv, const float* __restrict__ wt,
    const float* __restrict__ gamma, const float* __restrict__ rvar,
    float* __restrict__ cnt, bf16* __restrict__ wqk_bf,
    bf16* __restrict__ wv_bf, bf16* __restrict__ wt_hi,
    bf16* __restrict__ wt_lo, float* __restrict__ invg) {
  const int t = threadIdx.x;
  if (blockIdx.x < 8) {
    const int b = blockIdx.x;
    int s = 0;
    for (int i = t; i < kN; i += 256) s += mask[b * kN + i];
    __shared__ int red[256];
    red[t] = s;
    __syncthreads();
    for (int off = 128; off > 0; off >>= 1) {
      if (t < off) red[t] += red[t + off];
      __syncthreads();
    }
    if (t == 0) cnt[b] = (float)red[0];
    return;
  }
  const int total = 65536 + 262144 + 262144 + 512;
  for (int i = (blockIdx.x - 8) * 256 + t; i < total; i += 128 * 256) {
    if (i < 65536) {
      wqk_bf[i] = (bf16)wqk[i];
    } else if (i < 327680) {
      wv_bf[i - 65536] = (bf16)wv[i - 65536];
    } else if (i < 589824) {
      const int j = i - 327680;
      const float wf = wt[j];
      const bf16 h = (bf16)wf;
      wt_hi[j] = h;
      wt_lo[j] = (bf16)(wf - (float)h);
    } else {
      const int j = i - 589824;
      invg[j] = gamma[j] * rsqrtf(rvar[j] + 1e-5f);
    }
  }
}

// ------------------------------------- transpose+convert: [C][N] f32 -> [N][C] bf16
__global__ __launch_bounds__(256) void k_tr(const float* __restrict__ X,
                                            bf16* __restrict__ XT) {
  __shared__ float tile[32][69];
  const int b = blockIdx.z, c0 = blockIdx.y * 32, n0 = blockIdx.x * 64;
  const int t = threadIdx.x;
  const int cc = t >> 4, n4 = (t & 15) * 4;
#pragma unroll
  for (int p = 0; p < 2; p++) {
    const int c = p * 16 + cc;
    const f32x4 v = *(const f32x4*)&X[((size_t)(b * kC + c0 + c)) * kN + n0 + n4];
    tile[c][n4 + 0] = v[0];
    tile[c][n4 + 1] = v[1];
    tile[c][n4 + 2] = v[2];
    tile[c][n4 + 3] = v[3];
  }
  __syncthreads();
  const int n = t >> 2, c8 = (t & 3) * 8;
  bf16x8 o;
#pragma unroll
  for (int j = 0; j < 8; j++) o[j] = (bf16)tile[c8 + j][n];
  *(bf16x8*)&XT[((size_t)(b * kN + n0 + n)) * kC + c0 + c8] = o;
}

// -------------- projection to TRANSPOSED output: OT[b][n][128] = (W @ X)^T
__global__ __launch_bounds__(256) void k_projT(const bf16* __restrict__ XT,
                                               const bf16* __restrict__ W,
                                               bf16* __restrict__ OT) {
  const int b = blockIdx.y, n0 = blockIdx.x * 64;
  const int t = threadIdx.x, w = t >> 6, l = t & 63, lo4 = l & 15, g = l >> 4;
  const int n = n0 + w * 16 + lo4;
  f32x4 acc[8] = {};
  const bf16* xrow = &XT[((size_t)(b * kN + n)) * kC + g * 8];
#pragma unroll
  for (int ks = 0; ks < 16; ks++) {
    const bf16x8 bfr = *(const bf16x8*)&xrow[ks * 32];
#pragma unroll
    for (int mf = 0; mf < 8; mf++) {
      const bf16x8 afr =
          *(const bf16x8*)&W[(size_t)(mf * 16 + lo4) * kC + ks * 32 + g * 8];
      acc[mf] = MFMA16(afr, bfr, acc[mf]);
    }
  }
  bf16* orow = &OT[((size_t)(b * kN + n)) * kC4];
#pragma unroll
  for (int mf = 0; mf < 8; mf++) {
    bf16x4 o;
#pragma unroll
    for (int r = 0; r < 4; r++) o[r] = (bf16)acc[mf][r];
    *(bf16x4*)&orow[mf * 16 + g * 4] = o;
  }
}

// -------------- value projection: xv[b][c][n] bf16 = wv @ x + bv
__global__ __launch_bounds__(256) void k_projV(const bf16* __restrict__ XT,
                                               const bf16* __restrict__ Wv,
                                               const float* __restrict__ bv,
                                               bf16* __restrict__ xv) {
  __shared__ __align__(16) bf16 bnc[4][16][136];
  const int b = blockIdx.z, c0 = blockIdx.y * 64, n0 = blockIdx.x * 128;
  const int t = threadIdx.x, w = t >> 6, l = t & 63, lo4 = l & 15, g = l >> 4;
  const int crow = c0 + w * 16 + lo4;
  f32x4 acc[8] = {};
#pragma unroll
  for (int ks = 0; ks < 16; ks++) {
    const bf16x8 afr = *(const bf16x8*)&Wv[(size_t)crow * kC + ks * 32 + g * 8];
#pragma unroll
    for (int nf = 0; nf < 8; nf++) {
      const bf16x8 bfr =
          *(const bf16x8*)&XT[((size_t)(b * kN + n0 + nf * 16 + lo4)) * kC +
                              ks * 32 + g * 8];
      acc[nf] = MFMA16(afr, bfr, acc[nf]);
    }
  }
  float bvv[4];
#pragma unroll
  for (int r = 0; r < 4; r++) bvv[r] = bv[c0 + w * 16 + 4 * g + r];
#pragma unroll
  for (int nf = 0; nf < 8; nf++)
#pragma unroll
    for (int r = 0; r < 4; r++)
      bnc[w][4 * g + r][nf * 16 + lo4] = (bf16)(acc[nf][r] + bvv[r]);
  // per-wave LDS transpose readout (same-wave DS ops execute in order)
  const int rr = l >> 2, seg = (l & 3) * 32;
  const bf16x8 v0 = *(const bf16x8*)&bnc[w][rr][seg];
  const bf16x8 v1 = *(const bf16x8*)&bnc[w][rr][seg + 8];
  const bf16x8 v2 = *(const bf16x8*)&bnc[w][rr][seg + 16];
  const bf16x8 v3 = *(const bf16x8*)&bnc[w][rr][seg + 24];
  bf16* orow = &xv[((size_t)(b * kC + c0 + w * 16 + rr)) * kN + n0 + seg];
  *(bf16x8*)&orow[0] = v0;
  *(bf16x8*)&orow[8] = v1;
  *(bf16x8*)&orow[16] = v2;
  *(bf16x8*)&orow[24] = v3;
}

// ---------------- pass 1: per-row (n) softmax max & sum-of-exp via MFMA
__global__ __launch_bounds__(256) void k_stats(
    const bf16* __restrict__ qT, const bf16* __restrict__ kT,
    const int* __restrict__ mask, const float* __restrict__ cnt,
    float* __restrict__ rowmax, float* __restrict__ rowsum) {
  const int b = blockIdx.y, n0 = blockIdx.x * 64;
  const int t = threadIdx.x, w = t >> 6, l = t & 63, lo4 = l & 15, g = l >> 4;
  const float invd = 1.0f / (cnt[b] + 1e-9f);
  const float zrow = -9e15f * invd;
  bf16x8 aq[4];
#pragma unroll
  for (int ks = 0; ks < 4; ks++)
    aq[ks] = *(const bf16x8*)&qT[((size_t)(b * kN + n0 + w * 16 + lo4)) * kC4 +
                                 ks * 32 + g * 8];
  int mn[4];
#pragma unroll
  for (int r = 0; r < 4; r++) mn[r] = mask[b * kN + n0 + w * 16 + 4 * g + r];
  float rm[4] = {-INFINITY, -INFINITY, -INFINITY, -INFINITY};
  float rs[4] = {0.0f, 0.0f, 0.0f, 0.0f};
  for (int m0 = 0; m0 < kN; m0 += 64) {
    f32x4 e[4] = {};
#pragma unroll
    for (int mf = 0; mf < 4; mf++) {
#pragma unroll
      for (int ks = 0; ks < 4; ks++) {
        const bf16x8 bk =
            *(const bf16x8*)&kT[((size_t)(b * kN + m0 + mf * 16 + lo4)) * kC4 +
                                ks * 32 + g * 8];
        e[mf] = MFMA16(aq[ks], bk, e[mf]);
      }
    }
    int mm[4];
#pragma unroll
    for (int mf = 0; mf < 4; mf++) mm[mf] = mask[b * kN + m0 + mf * 16 + lo4];
    float z[4][4];
#pragma unroll
    for (int mf = 0; mf < 4; mf++)
#pragma unroll
      for (int r = 0; r < 4; r++)
        z[mf][r] = mm[mf] ? (mn[r] ? e[mf][r] * invd : zrow) : -9e24f;
#pragma unroll
    for (int r = 0; r < 4; r++) {
      float vmax = fmaxf(fmaxf(z[0][r], z[1][r]), fmaxf(z[2][r], z[3][r]));
#pragma unroll
      for (int off = 1; off < 16; off <<= 1)
        vmax = fmaxf(vmax, __shfl_xor(vmax, off));
      const float nm = fmaxf(rm[r], vmax);
      float se = __expf(z[0][r] - nm) + __expf(z[1][r] - nm) +
                 __expf(z[2][r] - nm) + __expf(z[3][r] - nm);
#pragma unroll
      for (int off = 1; off < 16; off <<= 1) se += __shfl_xor(se, off);
      rs[r] = rs[r] * __expf(rm[r] - nm) + se;
      rm[r] = nm;
    }
  }
  if (lo4 == 0) {
#pragma unroll
    for (int r = 0; r < 4; r++) {
      rowmax[b * kN + n0 + w * 16 + 4 * g + r] = rm[r];
      rowsum[b * kN + n0 + w * 16 + 4 * g + r] = rs[r];
    }
  }
}

// -------- pass 2: x_r^T = P @ x_v^T (P = normalized attention^T), h = x - x_r
// writes h^T as bf16 hi/lo split for the final GEMM
__global__ __launch_bounds__(512) void k_attn(
    const bf16* __restrict__ qT, const bf16* __restrict__ kT,
    const bf16* __restrict__ xv, const float* __restrict__ x,
    const int* __restrict__ mask, const float* __restrict__ cnt,
    const float* __restrict__ rowmax, const float* __restrict__ rowsum,
    bf16* __restrict__ hT_hi, bf16* __restrict__ hT_lo) {
  __shared__ __align__(16) bf16 P[2][64][40];
  __shared__ __align__(16) bf16 bnc[8][16][72];
  const int b = blockIdx.y, m0 = blockIdx.x * 64;
  const int t = threadIdx.x, w = t >> 6, l = t & 63, lo4 = l & 15, g = l >> 4;
  const int wm = w >> 1, wc = w & 1;
  const float invd = 1.0f / (cnt[b] + 1e-9f);
  const float zrow = -9e15f * invd;
  bf16x8 ak[4];
#pragma unroll
  for (int ks = 0; ks < 4; ks++)
    ak[ks] = *(const bf16x8*)&kT[((size_t)(b * kN + m0 + wm * 16 + lo4)) * kC4 +
                                 ks * 32 + g * 8];
  int mm[4];
#pragma unroll
  for (int r = 0; r < 4; r++) mm[r] = mask[b * kN + m0 + wm * 16 + 4 * g + r];
  f32x4 acc[16] = {};
  for (int tt = 0; tt < kN / 32; tt++) {
    const int n0 = tt * 32;
    f32x4 e = {};
#pragma unroll
    for (int ks = 0; ks < 4; ks++) {
      const bf16x8 bq =
          *(const bf16x8*)&qT[((size_t)(b * kN + n0 + wc * 16 + lo4)) * kC4 +
                              ks * 32 + g * 8];
      e = MFMA16(ak[ks], bq, e);
    }
    const int nidx = b * kN + n0 + wc * 16 + lo4;
    const int mn = mask[nidx];
    const float rmv = rowmax[nidx];
    const float rinv = 1.0f / rowsum[nidx];
#pragma unroll
    for (int r = 0; r < 4; r++) {
      const float zz = mm[r] ? (mn ? e[r] * invd : zrow) : -9e24f;
      P[tt & 1][wm * 16 + 4 * g + r][wc * 16 + lo4] =
          (bf16)(__expf(zz - rmv) * rinv);
    }
    __syncthreads();
    const bf16x8 pa = *(const bf16x8*)&P[tt & 1][wm * 16 + lo4][g * 8];
#pragma unroll
    for (int cf = 0; cf < 16; cf++) {
      const bf16x8 bv8 =
          *(const bf16x8*)&xv[((size_t)(b * kC + wc * 256 + cf * 16 + lo4)) *
                                  kN +
                              n0 + g * 8];
      acc[cf] = MFMA16(pa, bv8, acc[cf]);
    }
  }
  // epilogue: h = x - x_r; emit h^T hi/lo via per-wave LDS transpose
#pragma unroll
  for (int ch = 0; ch < 4; ch++) {
    float hh[4][4];
#pragma unroll
    for (int q = 0; q < 4; q++) {
      const int cf = ch * 4 + q;
      const int c = wc * 256 + cf * 16 + lo4;
      const f32x4 xval =
          *(const f32x4*)&x[((size_t)(b * kC + c)) * kN + m0 + wm * 16 + 4 * g];
#pragma unroll
      for (int r = 0; r < 4; r++) hh[q][r] = xval[r] - acc[cf][r];
    }
#pragma unroll
    for (int q = 0; q < 4; q++)
#pragma unroll
      for (int r = 0; r < 4; r++)
        bnc[w][4 * g + r][q * 16 + lo4] = (bf16)hh[q][r];
    {
      const int rr = l >> 2, seg = (l & 3) * 16;
      const bf16x8 v0 = *(const bf16x8*)&bnc[w][rr][seg];
      const bf16x8 v1 = *(const bf16x8*)&bnc[w][rr][seg + 8];
      bf16* orow = &hT_hi[((size_t)(b * kN + m0 + wm * 16 + rr)) * kC +
                          wc * 256 + ch * 64 + seg];
      *(bf16x8*)&orow[0] = v0;
      *(bf16x8*)&orow[8] = v1;
    }
#pragma unroll
    for (int q = 0; q < 4; q++)
#pragma unroll
      for (int r = 0; r < 4; r++) {
        const float hv = hh[q][r];
        const bf16 hb = (bf16)hv;
        bnc[w][4 * g + r][q * 16 + lo4] = (bf16)(hv - (float)hb);
      }
    {
      const int rr = l >> 2, seg = (l & 3) * 16;
      const bf16x8 v0 = *(const bf16x8*)&bnc[w][rr][seg];
      const bf16x8 v1 = *(const bf16x8*)&bnc[w][rr][seg + 8];
      bf16* orow = &hT_lo[((size_t)(b * kN + m0 + wm * 16 + rr)) * kC +
                          wc * 256 + ch * 64 + seg];
      *(bf16x8*)&orow[0] = v0;
      *(bf16x8*)&orow[8] = v1;
    }
  }
}

// -------- final: y^T = h^T @ wt^T (3-term hi/lo split), BN(eval)+ReLU+residual
__global__ __launch_bounds__(256) void k_final(
    const bf16* __restrict__ hT_hi, const bf16* __restrict__ hT_lo,
    const bf16* __restrict__ wt_hi, const bf16* __restrict__ wt_lo,
    const float* __restrict__ x, const float* __restrict__ bt,
    const float* __restrict__ beta, const float* __restrict__ rmean,
    const float* __restrict__ invg, float* __restrict__ out) {
  const int b = blockIdx.z, c0 = blockIdx.y * 128, n0 = blockIdx.x * 64;
  const int t = threadIdx.x, w = t >> 6, l = t & 63, lo4 = l & 15, g = l >> 4;
  const int n = n0 + w * 16 + lo4;
  f32x4 acc[8] = {};
  const bf16* hh = &hT_hi[((size_t)(b * kN + n)) * kC + g * 8];
  const bf16* hl = &hT_lo[((size_t)(b * kN + n)) * kC + g * 8];
#pragma unroll
  for (int ks = 0; ks < 16; ks++) {
    const bf16x8 ah = *(const bf16x8*)&hh[ks * 32];
    const bf16x8 al = *(const bf16x8*)&hl[ks * 32];
#pragma unroll
    for (int cf = 0; cf < 8; cf++) {
      const bf16x8 wh = *(const bf16x8*)&wt_hi[(size_t)(c0 + cf * 16 + lo4) * kC +
                                               ks * 32 + g * 8];
      const bf16x8 wl = *(const bf16x8*)&wt_lo[(size_t)(c0 + cf * 16 + lo4) * kC +
                                               ks * 32 + g * 8];
      acc[cf] = MFMA16(ah, wh, acc[cf]);
      acc[cf] = MFMA16(al, wh, acc[cf]);
      acc[cf] = MFMA16(ah, wl, acc[cf]);
    }
  }
#pragma unroll
  for (int cf = 0; cf < 8; cf++) {
    const int cc = c0 + cf * 16 + lo4;
    const float btv = bt[cc], rmv = rmean[cc], igv = invg[cc], bev = beta[cc];
    const size_t base = ((size_t)(b * kC + cc)) * kN + n0 + w * 16 + 4 * g;
    const f32x4 xval = *(const f32x4*)&x[base];
    f32x4 o;
#pragma unroll
    for (int r = 0; r < 4; r++) {
      float v = (acc[cf][r] + btv - rmv) * igv + bev;
      v = fmaxf(v, 0.0f);
      o[r] = xval[r] + v;
    }
    *(f32x4*)&out[base] = o;
  }
}

extern "C" void kernel_launch(void* const* d_in, const int* in_sizes, int n_in,
                              void* d_out, int out_size, void* d_ws,
                              size_t ws_size, hipStream_t stream) {
  const float* x = (const float*)d_in[0];
  const float* query = (const float*)d_in[1];
  const int* mask = (const int*)d_in[2];
  const float* wqk = (const float*)d_in[3];
  const float* wv = (const float*)d_in[4];
  const float* bv = (const float*)d_in[5];
  const float* wt = (const float*)d_in[6];
  const float* bt = (const float*)d_in[7];
  const float* gamma = (const float*)d_in[8];
  const float* beta = (const float*)d_in[9];
  const float* rmean = (const float*)d_in[10];
  const float* rvar = (const float*)d_in[11];
  float* out = (float*)d_out;
  char* wsb = (char*)d_ws;

  const size_t MB = 1024 * 1024;
  bf16* trbuf = (bf16*)wsb;                      // 16 MB (queryT/xT, later hT)
  bf16* hT_hi = trbuf;                           // 8 MB [B][N][C]
  bf16* hT_lo = trbuf + (size_t)kB * kN * kC;    // 8 MB
  bf16* qT = (bf16*)(wsb + 16 * MB);             // 4 MB [B][N][C4]
  bf16* kT = (bf16*)(wsb + 20 * MB);             // 4 MB [B][N][C4]
  bf16* xv = (bf16*)(wsb + 24 * MB);             // 16 MB [B][C][N]
  bf16* wqk_bf = (bf16*)(wsb + 40 * MB);         // 131072 B
  bf16* wv_bf = wqk_bf + 65536;                  // 524288 B
  bf16* wt_hi = wv_bf + 262144;                  // 524288 B
  bf16* wt_lo = wt_hi + 262144;                  // 524288 B
  float* invg = (float*)(wt_lo + 262144);        // 2048 B
  float* rowmax = invg + 512;                    // 64 KB
  float* rowsum = rowmax + kB * kN;              // 64 KB
  float* cnt = rowsum + kB * kN;                 // 32 B

  k_prep<<<136, 256, 0, stream>>>(mask, wqk, wv, wt, gamma, rvar, cnt, wqk_bf,
                                  wv_bf, wt_hi, wt_lo, invg);
  // queryT -> q~T
  k_tr<<<dim3(kN / 64, kC / 32, kB), 256, 0, stream>>>(query, trbuf);
  k_projT<<<dim3(kN / 64, kB), 256, 0, stream>>>(trbuf, wqk_bf, qT);
  // xT -> k~T, x_v
  k_tr<<<dim3(kN / 64, kC / 32, kB), 256, 0, stream>>>(x, trbuf);
  k_projT<<<dim3(kN / 64, kB), 256, 0, stream>>>(trbuf, wqk_bf, kT);
  k_projV<<<dim3(kN / 128, kC / 64, kB), 256, 0, stream>>>(trbuf, wv_bf, bv,
                                                           xv);
  k_stats<<<dim3(kN / 64, kB), 256, 0, stream>>>(qT, kT, mask, cnt, rowmax,
                                                 rowsum);
  k_attn<<<dim3(kN / 64, kB), 512, 0, stream>>>(qT, kT, xv, x, mask, cnt,
                                                rowmax, rowsum, hT_hi, hT_lo);
  k_final<<<dim3(kN / 64, kC / 128, kB), 256, 0, stream>>>(
      hT_hi, hT_lo, wt_hi, wt_lo, x, bt, beta, rmean, invg, out);
}

// Round 4
// 505.129 us; speedup vs baseline: 3.4895x; 1.5662x over previous
//
#include <hip/hip_runtime.h>
#include <math.h>

typedef __bf16 bf16;
typedef bf16 bf16x8 __attribute__((ext_vector_type(8)));
typedef bf16 bf16x4 __attribute__((ext_vector_type(4)));
typedef float f32x4 __attribute__((ext_vector_type(4)));

constexpr int kB = 8, kC = 512, kC4 = 128, kN = 2048;

#define MFMA16(a, b, c) __builtin_amdgcn_mfma_f32_16x16x32_bf16(a, b, c, 0, 0, 0)

// ---------------------------------------------------------------- prep
__global__ __launch_bounds__(256) void k_prep(
    const int* __restrict__ mask, const float* __restrict__ wqk,
    const float* __restrict__ wv, const float* __restrict__ wt,
    const float* __restrict__ gamma, const float* __restrict__ rvar,
    float* __restrict__ cnt, bf16* __restrict__ wqk_bf,
    bf16* __restrict__ wv_bf, bf16* __restrict__ wt_hi,
    bf16* __restrict__ wt_lo, float* __restrict__ invg) {
  const int t = threadIdx.x;
  if (blockIdx.x < 8) {
    const int b = blockIdx.x;
    int s = 0;
    for (int i = t; i < kN; i += 256) s += mask[b * kN + i];
    __shared__ int red[256];
    red[t] = s;
    __syncthreads();
    for (int off = 128; off > 0; off >>= 1) {
      if (t < off) red[t] += red[t + off];
      __syncthreads();
    }
    if (t == 0) cnt[b] = (float)red[0];
    return;
  }
  const int total = 65536 + 262144 + 262144 + 512;
  for (int i = (blockIdx.x - 8) * 256 + t; i < total; i += 128 * 256) {
    if (i < 65536) {
      wqk_bf[i] = (bf16)wqk[i];
    } else if (i < 327680) {
      wv_bf[i - 65536] = (bf16)wv[i - 65536];
    } else if (i < 589824) {
      const int j = i - 327680;
      const float wf = wt[j];
      const bf16 h = (bf16)wf;
      wt_hi[j] = h;
      wt_lo[j] = (bf16)(wf - (float)h);
    } else {
      const int j = i - 589824;
      invg[j] = gamma[j] * rsqrtf(rvar[j] + 1e-5f);
    }
  }
}

// ------------------------------------- transpose+convert: [C][N] f32 -> [N][C] bf16
__global__ __launch_bounds__(256) void k_tr(const float* __restrict__ X,
                                            bf16* __restrict__ XT) {
  __shared__ float tile[32][69];
  const int b = blockIdx.z, c0 = blockIdx.y * 32, n0 = blockIdx.x * 64;
  const int t = threadIdx.x;
  const int cc = t >> 4, n4 = (t & 15) * 4;
#pragma unroll
  for (int p = 0; p < 2; p++) {
    const int c = p * 16 + cc;
    const f32x4 v = *(const f32x4*)&X[((size_t)(b * kC + c0 + c)) * kN + n0 + n4];
    tile[c][n4 + 0] = v[0];
    tile[c][n4 + 1] = v[1];
    tile[c][n4 + 2] = v[2];
    tile[c][n4 + 3] = v[3];
  }
  __syncthreads();
  const int n = t >> 2, c8 = (t & 3) * 8;
  bf16x8 o;
#pragma unroll
  for (int j = 0; j < 8; j++) o[j] = (bf16)tile[c8 + j][n];
  *(bf16x8*)&XT[((size_t)(b * kN + n0 + n)) * kC + c0 + c8] = o;
}

// -------------- projection to TRANSPOSED output: OT[b][n][128] = (W @ X)^T
__global__ __launch_bounds__(256) void k_projT(const bf16* __restrict__ XT,
                                               const bf16* __restrict__ W,
                                               bf16* __restrict__ OT) {
  const int b = blockIdx.y, n0 = blockIdx.x * 64;
  const int t = threadIdx.x, w = t >> 6, l = t & 63, lo4 = l & 15, g = l >> 4;
  const int n = n0 + w * 16 + lo4;
  f32x4 acc[8] = {};
  const bf16* xrow = &XT[((size_t)(b * kN + n)) * kC + g * 8];
#pragma unroll
  for (int ks = 0; ks < 16; ks++) {
    const bf16x8 bfr = *(const bf16x8*)&xrow[ks * 32];
#pragma unroll
    for (int mf = 0; mf < 8; mf++) {
      const bf16x8 afr =
          *(const bf16x8*)&W[(size_t)(mf * 16 + lo4) * kC + ks * 32 + g * 8];
      acc[mf] = MFMA16(afr, bfr, acc[mf]);
    }
  }
  bf16* orow = &OT[((size_t)(b * kN + n)) * kC4];
#pragma unroll
  for (int mf = 0; mf < 8; mf++) {
    bf16x4 o;
#pragma unroll
    for (int r = 0; r < 4; r++) o[r] = (bf16)acc[mf][r];
    *(bf16x4*)&orow[mf * 16 + g * 4] = o;
  }
}

// -------------- value projection: xv[b][c][n] bf16 = wv @ x + bv
__global__ __launch_bounds__(256) void k_projV(const bf16* __restrict__ XT,
                                               const bf16* __restrict__ Wv,
                                               const float* __restrict__ bv,
                                               bf16* __restrict__ xv) {
  __shared__ __align__(16) bf16 bnc[4][16][136];
  const int b = blockIdx.z, c0 = blockIdx.y * 64, n0 = blockIdx.x * 128;
  const int t = threadIdx.x, w = t >> 6, l = t & 63, lo4 = l & 15, g = l >> 4;
  const int crow = c0 + w * 16 + lo4;
  f32x4 acc[8] = {};
#pragma unroll
  for (int ks = 0; ks < 16; ks++) {
    const bf16x8 afr = *(const bf16x8*)&Wv[(size_t)crow * kC + ks * 32 + g * 8];
#pragma unroll
    for (int nf = 0; nf < 8; nf++) {
      const bf16x8 bfr =
          *(const bf16x8*)&XT[((size_t)(b * kN + n0 + nf * 16 + lo4)) * kC +
                              ks * 32 + g * 8];
      acc[nf] = MFMA16(afr, bfr, acc[nf]);
    }
  }
  float bvv[4];
#pragma unroll
  for (int r = 0; r < 4; r++) bvv[r] = bv[c0 + w * 16 + 4 * g + r];
#pragma unroll
  for (int nf = 0; nf < 8; nf++)
#pragma unroll
    for (int r = 0; r < 4; r++)
      bnc[w][4 * g + r][nf * 16 + lo4] = (bf16)(acc[nf][r] + bvv[r]);
  const int rr = l >> 2, seg = (l & 3) * 32;
  const bf16x8 v0 = *(const bf16x8*)&bnc[w][rr][seg];
  const bf16x8 v1 = *(const bf16x8*)&bnc[w][rr][seg + 8];
  const bf16x8 v2 = *(const bf16x8*)&bnc[w][rr][seg + 16];
  const bf16x8 v3 = *(const bf16x8*)&bnc[w][rr][seg + 24];
  bf16* orow = &xv[((size_t)(b * kC + c0 + w * 16 + rr)) * kN + n0 + seg];
  *(bf16x8*)&orow[0] = v0;
  *(bf16x8*)&orow[8] = v1;
  *(bf16x8*)&orow[16] = v2;
  *(bf16x8*)&orow[24] = v3;
}

// ---------------- pass 1: per-row (n) softmax max & sum-of-exp
// swapped-operand energy MFMA(K,Q): lane holds 16 m-values for one n ->
// in-register m-reduction. kT tile staged in LDS (XOR-swizzled), dbuf.
// batch pinned to XCD via blk&7.
__global__ __launch_bounds__(256) void k_stats(
    const bf16* __restrict__ qT, const bf16* __restrict__ kT,
    const int* __restrict__ mask, const float* __restrict__ cnt,
    float* __restrict__ rowmax, float* __restrict__ rowsum) {
  __shared__ __align__(16) bf16 kts[2][64][128];
  __shared__ int mss[2][64];
  const int blk = blockIdx.x;
  const int b = blk & 7, n0 = (blk >> 3) * 64;
  const int t_ = threadIdx.x, w = t_ >> 6, l = t_ & 63, lo4 = l & 15, g = l >> 4;
  const float invd = 1.0f / (cnt[b] + 1e-9f);
  const float zrow = -9e15f * invd;
  const int n = n0 + w * 16 + lo4;
  bf16x8 aq[4];
#pragma unroll
  for (int ks = 0; ks < 4; ks++)
    aq[ks] = *(const bf16x8*)&qT[((size_t)(b * kN + n)) * kC4 + ks * 32 + g * 8];
  const int mn = mask[b * kN + n];
  float rm = -INFINITY, rs = 0.0f;
  bf16x8 rg[4];
  // prologue: stage m-tile 0
#pragma unroll
  for (int i = 0; i < 4; i++) {
    const int row = w * 16 + i * 4 + g;
    const int q = (l & 15) ^ (row & 7);
    rg[i] = *(const bf16x8*)&kT[((size_t)(b * kN + row)) * kC4 + q * 8];
  }
#pragma unroll
  for (int i = 0; i < 4; i++) {
    const int row = w * 16 + i * 4 + g;
    *(bf16x8*)&kts[0][row][(l & 15) * 8] = rg[i];
  }
  if (t_ < 16) *(int4*)&mss[0][t_ * 4] = *(const int4*)&mask[b * kN + t_ * 4];
  __syncthreads();
  for (int tt = 0; tt < 32; tt++) {
    const int buf = tt & 1;
    if (tt < 31) {
      const int m0 = (tt + 1) * 64;
#pragma unroll
      for (int i = 0; i < 4; i++) {
        const int row = w * 16 + i * 4 + g;
        const int q = (l & 15) ^ (row & 7);
        rg[i] = *(const bf16x8*)&kT[((size_t)(b * kN + m0 + row)) * kC4 + q * 8];
      }
    }
    f32x4 e[4] = {};
#pragma unroll
    for (int mf = 0; mf < 4; mf++) {
#pragma unroll
      for (int ks = 0; ks < 4; ks++) {
        const bf16x8 bk =
            *(const bf16x8*)&kts[buf][mf * 16 + lo4]
                                 [((ks * 4 + g) ^ (lo4 & 7)) * 8];
        e[mf] = MFMA16(bk, aq[ks], e[mf]);
      }
    }
    float z[4][4];
#pragma unroll
    for (int mf = 0; mf < 4; mf++) {
      const int4 mi = *(const int4*)&mss[buf][mf * 16 + g * 4];
      const int mm4[4] = {mi.x, mi.y, mi.z, mi.w};
#pragma unroll
      for (int r = 0; r < 4; r++)
        z[mf][r] = mm4[r] ? (mn ? e[mf][r] * invd : zrow) : -9e24f;
    }
    float vmax = z[0][0];
#pragma unroll
    for (int mf = 0; mf < 4; mf++)
#pragma unroll
      for (int r = 0; r < 4; r++) vmax = fmaxf(vmax, z[mf][r]);
    vmax = fmaxf(vmax, __shfl_xor(vmax, 16));
    vmax = fmaxf(vmax, __shfl_xor(vmax, 32));
    const float nm = fmaxf(rm, vmax);
    float se = 0.0f;
#pragma unroll
    for (int mf = 0; mf < 4; mf++)
#pragma unroll
      for (int r = 0; r < 4; r++) se += __expf(z[mf][r] - nm);
    se += __shfl_xor(se, 16);
    se += __shfl_xor(se, 32);
    rs = rs * __expf(rm - nm) + se;
    rm = nm;
    if (tt < 31) {
#pragma unroll
      for (int i = 0; i < 4; i++) {
        const int row = w * 16 + i * 4 + g;
        *(bf16x8*)&kts[buf ^ 1][row][(l & 15) * 8] = rg[i];
      }
      if (t_ < 16)
        *(int4*)&mss[buf ^ 1][t_ * 4] =
            *(const int4*)&mask[b * kN + (tt + 1) * 64 + t_ * 4];
    }
    __syncthreads();
  }
  if (g == 0) {
    rowmax[b * kN + n] = rm;
    rowsum[b * kN + n] = rs;
  }
}

// -------- pass 2: x_r^T = P @ x_v^T, h = x - x_r, write hT hi/lo
// block tile 128m x 256c (c-split x2); 8 waves = 2 m-halves x 4 c-quads,
// wave acc 64m x 64c. xv staged in LDS (dbuf 16KB tiles); batch->XCD pin.
__global__ __launch_bounds__(512) void k_attn(
    const bf16* __restrict__ qT, const bf16* __restrict__ kT,
    const bf16* __restrict__ xv, const float* __restrict__ x,
    const int* __restrict__ mask, const float* __restrict__ cnt,
    const float* __restrict__ rowmax, const float* __restrict__ rowsum,
    bf16* __restrict__ hT_hi, bf16* __restrict__ hT_lo) {
  __shared__ __align__(16) bf16 xvs[2][256][32];
  __shared__ __align__(16) bf16 P[128][40];
  __shared__ __align__(16) bf16 bnc[8][16][72];
  const int blk = blockIdx.x;  // 256 = 8 b x 16 mb x 2 ch
  const int b = blk & 7;
  const int mb = (blk >> 3) & 15;
  const int ch = blk >> 7;
  const int m0 = mb * 128;
  const int c0 = ch * 256;
  const int t_ = threadIdx.x, w = t_ >> 6, l = t_ & 63, lo4 = l & 15, g = l >> 4;
  const int mh = w >> 2, cq = w & 3;
  const float invd = 1.0f / (cnt[b] + 1e-9f);
  const float zrow = -9e15f * invd;
  // A-fragments of K for this wave's 16-m energy chunk (m = m0 + w*16 + ..)
  bf16x8 ak[4];
#pragma unroll
  for (int ks = 0; ks < 4; ks++)
    ak[ks] = *(const bf16x8*)&kT[((size_t)(b * kN + m0 + w * 16 + lo4)) * kC4 +
                                 ks * 32 + g * 8];
  const int4 mi = *(const int4*)&mask[b * kN + m0 + w * 16 + g * 4];
  const int mm4[4] = {mi.x, mi.y, mi.z, mi.w};
  f32x4 acc[4][4] = {};
  bf16x8 rg[2];
  // prologue: stage n-tile 0
#pragma unroll
  for (int i = 0; i < 2; i++) {
    const int row = w * 32 + i * 16 + (l >> 2);
    rg[i] = *(const bf16x8*)&xv[((size_t)(b * kC + c0 + row)) * kN + (l & 3) * 8];
  }
#pragma unroll
  for (int i = 0; i < 2; i++) {
    const int row = w * 32 + i * 16 + (l >> 2);
    *(bf16x8*)&xvs[0][row][(l & 3) * 8] = rg[i];
  }
  __syncthreads();
  for (int tt = 0; tt < 64; tt++) {
    const int buf = tt & 1;
    if (tt < 63) {
      const int nt = (tt + 1) * 32;
#pragma unroll
      for (int i = 0; i < 2; i++) {
        const int row = w * 32 + i * 16 + (l >> 2);
        rg[i] = *(const bf16x8*)&xv[((size_t)(b * kC + c0 + row)) * kN + nt +
                                    (l & 3) * 8];
      }
    }
    // energy for this wave's 16m x 32n
    f32x4 e[2] = {};
#pragma unroll
    for (int nf = 0; nf < 2; nf++) {
      const bf16* qrow =
          &qT[((size_t)(b * kN + tt * 32 + nf * 16 + lo4)) * kC4 + g * 8];
#pragma unroll
      for (int ks = 0; ks < 4; ks++)
        e[nf] = MFMA16(ak[ks], *(const bf16x8*)&qrow[ks * 32], e[nf]);
    }
#pragma unroll
    for (int nf = 0; nf < 2; nf++) {
      const int nidx = b * kN + tt * 32 + nf * 16 + lo4;
      const int mn = mask[nidx];
      const float rmv = rowmax[nidx];
      const float rinv = 1.0f / rowsum[nidx];
#pragma unroll
      for (int r = 0; r < 4; r++) {
        const float zz = mm4[r] ? (mn ? e[nf][r] * invd : zrow) : -9e24f;
        P[w * 16 + g * 4 + r][nf * 16 + lo4] = (bf16)(__expf(zz - rmv) * rinv);
      }
    }
    __syncthreads();
    if (tt < 63) {
#pragma unroll
      for (int i = 0; i < 2; i++) {
        const int row = w * 32 + i * 16 + (l >> 2);
        *(bf16x8*)&xvs[buf ^ 1][row][(l & 3) * 8] = rg[i];
      }
    }
    // PV: acc[mf][cf] += P(m x n) @ xv^T(n x c)
    bf16x8 bvr[4];
#pragma unroll
    for (int cf = 0; cf < 4; cf++)
      bvr[cf] = *(const bf16x8*)&xvs[buf][cq * 64 + cf * 16 + lo4][g * 8];
#pragma unroll
    for (int mf = 0; mf < 4; mf++) {
      const bf16x8 pa = *(const bf16x8*)&P[mh * 64 + mf * 16 + lo4][g * 8];
#pragma unroll
      for (int cf = 0; cf < 4; cf++)
        acc[mf][cf] = MFMA16(pa, bvr[cf], acc[mf][cf]);
    }
    __syncthreads();
  }
  // epilogue: h = x - x_r; per-wave LDS transpose; hi/lo split
#pragma unroll
  for (int mf = 0; mf < 4; mf++) {
    float hh[4][4];
#pragma unroll
    for (int cf = 0; cf < 4; cf++) {
      const int c = c0 + cq * 64 + cf * 16 + lo4;
      const f32x4 xval = *(const f32x4*)&x[((size_t)(b * kC + c)) * kN + m0 +
                                           mh * 64 + mf * 16 + g * 4];
#pragma unroll
      for (int r = 0; r < 4; r++) hh[cf][r] = xval[r] - acc[mf][cf][r];
    }
#pragma unroll
    for (int cf = 0; cf < 4; cf++)
#pragma unroll
      for (int r = 0; r < 4; r++)
        bnc[w][4 * g + r][cf * 16 + lo4] = (bf16)hh[cf][r];
    {
      const int rr = l >> 2, seg = (l & 3) * 16;
      const bf16x8 v0 = *(const bf16x8*)&bnc[w][rr][seg];
      const bf16x8 v1 = *(const bf16x8*)&bnc[w][rr][seg + 8];
      bf16* orow = &hT_hi[((size_t)(b * kN + m0 + mh * 64 + mf * 16 + rr)) * kC +
                          c0 + cq * 64 + seg];
      *(bf16x8*)&orow[0] = v0;
      *(bf16x8*)&orow[8] = v1;
    }
#pragma unroll
    for (int cf = 0; cf < 4; cf++)
#pragma unroll
      for (int r = 0; r < 4; r++) {
        const float hv = hh[cf][r];
        const bf16 hb = (bf16)hv;
        bnc[w][4 * g + r][cf * 16 + lo4] = (bf16)(hv - (float)hb);
      }
    {
      const int rr = l >> 2, seg = (l & 3) * 16;
      const bf16x8 v0 = *(const bf16x8*)&bnc[w][rr][seg];
      const bf16x8 v1 = *(const bf16x8*)&bnc[w][rr][seg + 8];
      bf16* orow = &hT_lo[((size_t)(b * kN + m0 + mh * 64 + mf * 16 + rr)) * kC +
                          c0 + cq * 64 + seg];
      *(bf16x8*)&orow[0] = v0;
      *(bf16x8*)&orow[8] = v1;
    }
  }
}

// -------- final: y^T = h^T @ wt^T (3-term hi/lo), BN(eval)+ReLU+residual
__global__ __launch_bounds__(256) void k_final(
    const bf16* __restrict__ hT_hi, const bf16* __restrict__ hT_lo,
    const bf16* __restrict__ wt_hi, const bf16* __restrict__ wt_lo,
    const float* __restrict__ x, const float* __restrict__ bt,
    const float* __restrict__ beta, const float* __restrict__ rmean,
    const float* __restrict__ invg, float* __restrict__ out) {
  const int b = blockIdx.z, c0 = blockIdx.y * 128, n0 = blockIdx.x * 64;
  const int t = threadIdx.x, w = t >> 6, l = t & 63, lo4 = l & 15, g = l >> 4;
  const int n = n0 + w * 16 + lo4;
  f32x4 acc[8] = {};
  const bf16* hh = &hT_hi[((size_t)(b * kN + n)) * kC + g * 8];
  const bf16* hl = &hT_lo[((size_t)(b * kN + n)) * kC + g * 8];
#pragma unroll
  for (int ks = 0; ks < 16; ks++) {
    const bf16x8 ah = *(const bf16x8*)&hh[ks * 32];
    const bf16x8 al = *(const bf16x8*)&hl[ks * 32];
#pragma unroll
    for (int cf = 0; cf < 8; cf++) {
      const bf16x8 wh = *(const bf16x8*)&wt_hi[(size_t)(c0 + cf * 16 + lo4) * kC +
                                               ks * 32 + g * 8];
      const bf16x8 wl = *(const bf16x8*)&wt_lo[(size_t)(c0 + cf * 16 + lo4) * kC +
                                               ks * 32 + g * 8];
      acc[cf] = MFMA16(ah, wh, acc[cf]);
      acc[cf] = MFMA16(al, wh, acc[cf]);
      acc[cf] = MFMA16(ah, wl, acc[cf]);
    }
  }
#pragma unroll
  for (int cf = 0; cf < 8; cf++) {
    const int cc = c0 + cf * 16 + lo4;
    const float btv = bt[cc], rmv = rmean[cc], igv = invg[cc], bev = beta[cc];
    const size_t base = ((size_t)(b * kC + cc)) * kN + n0 + w * 16 + 4 * g;
    const f32x4 xval = *(const f32x4*)&x[base];
    f32x4 o;
#pragma unroll
    for (int r = 0; r < 4; r++) {
      float v = (acc[cf][r] + btv - rmv) * igv + bev;
      v = fmaxf(v, 0.0f);
      o[r] = xval[r] + v;
    }
    *(f32x4*)&out[base] = o;
  }
}

extern "C" void kernel_launch(void* const* d_in, const int* in_sizes, int n_in,
                              void* d_out, int out_size, void* d_ws,
                              size_t ws_size, hipStream_t stream) {
  const float* x = (const float*)d_in[0];
  const float* query = (const float*)d_in[1];
  const int* mask = (const int*)d_in[2];
  const float* wqk = (const float*)d_in[3];
  const float* wv = (const float*)d_in[4];
  const float* bv = (const float*)d_in[5];
  const float* wt = (const float*)d_in[6];
  const float* bt = (const float*)d_in[7];
  const float* gamma = (const float*)d_in[8];
  const float* beta = (const float*)d_in[9];
  const float* rmean = (const float*)d_in[10];
  const float* rvar = (const float*)d_in[11];
  float* out = (float*)d_out;
  char* wsb = (char*)d_ws;

  const size_t MB = 1024 * 1024;
  bf16* trbuf = (bf16*)wsb;                      // 16 MB (queryT/xT, later hT)
  bf16* hT_hi = trbuf;                           // 8 MB [B][N][C]
  bf16* hT_lo = trbuf + (size_t)kB * kN * kC;    // 8 MB
  bf16* qT = (bf16*)(wsb + 16 * MB);             // 4 MB [B][N][C4]
  bf16* kT = (bf16*)(wsb + 20 * MB);             // 4 MB [B][N][C4]
  bf16* xv = (bf16*)(wsb + 24 * MB);             // 16 MB [B][C][N]
  bf16* wqk_bf = (bf16*)(wsb + 40 * MB);         // 131072 B
  bf16* wv_bf = wqk_bf + 65536;                  // 524288 B
  bf16* wt_hi = wv_bf + 262144;                  // 524288 B
  bf16* wt_lo = wt_hi + 262144;                  // 524288 B
  float* invg = (float*)(wt_lo + 262144);        // 2048 B
  float* rowmax = invg + 512;                    // 64 KB
  float* rowsum = rowmax + kB * kN;              // 64 KB
  float* cnt = rowsum + kB * kN;                 // 32 B

  k_prep<<<136, 256, 0, stream>>>(mask, wqk, wv, wt, gamma, rvar, cnt, wqk_bf,
                                  wv_bf, wt_hi, wt_lo, invg);
  k_tr<<<dim3(kN / 64, kC / 32, kB), 256, 0, stream>>>(query, trbuf);
  k_projT<<<dim3(kN / 64, kB), 256, 0, stream>>>(trbuf, wqk_bf, qT);
  k_tr<<<dim3(kN / 64, kC / 32, kB), 256, 0, stream>>>(x, trbuf);
  k_projT<<<dim3(kN / 64, kB), 256, 0, stream>>>(trbuf, wqk_bf, kT);
  k_projV<<<dim3(kN / 128, kC / 64, kB), 256, 0, stream>>>(trbuf, wv_bf, bv,
                                                           xv);
  k_stats<<<256, 256, 0, stream>>>(qT, kT, mask, cnt, rowmax, rowsum);
  k_attn<<<256, 512, 0, stream>>>(qT, kT, xv, x, mask, cnt, rowmax, rowsum,
                                  hT_hi, hT_lo);
  k_final<<<dim3(kN / 64, kC / 128, kB), 256, 0, stream>>>(
      hT_hi, hT_lo, wt_hi, wt_lo, x, bt, beta, rmean, invg, out);
}

// Round 5
// 478.465 us; speedup vs baseline: 3.6840x; 1.0557x over previous
//
#include <hip/hip_runtime.h>
#include <math.h>

typedef __bf16 bf16;
typedef bf16 bf16x8 __attribute__((ext_vector_type(8)));
typedef bf16 bf16x4 __attribute__((ext_vector_type(4)));
typedef float f32x4 __attribute__((ext_vector_type(4)));

constexpr int kB = 8, kC = 512, kC4 = 128, kN = 2048;

#define MFMA16(a, b, c) __builtin_amdgcn_mfma_f32_16x16x32_bf16(a, b, c, 0, 0, 0)

// ---------------------------------------------------------------- prep
__global__ __launch_bounds__(256) void k_prep(
    const int* __restrict__ mask, const float* __restrict__ wqk,
    const float* __restrict__ wv, const float* __restrict__ wt,
    const float* __restrict__ gamma, const float* __restrict__ rvar,
    float* __restrict__ cnt, bf16* __restrict__ wqk_bf,
    bf16* __restrict__ wv_bf, bf16* __restrict__ wt_hi,
    bf16* __restrict__ wt_lo, float* __restrict__ invg) {
  const int t = threadIdx.x;
  if (blockIdx.x < 8) {
    const int b = blockIdx.x;
    int s = 0;
    for (int i = t; i < kN; i += 256) s += mask[b * kN + i];
    __shared__ int red[256];
    red[t] = s;
    __syncthreads();
    for (int off = 128; off > 0; off >>= 1) {
      if (t < off) red[t] += red[t + off];
      __syncthreads();
    }
    if (t == 0) cnt[b] = (float)red[0];
    return;
  }
  const int total = 65536 + 262144 + 262144 + 512;
  for (int i = (blockIdx.x - 8) * 256 + t; i < total; i += 128 * 256) {
    if (i < 65536) {
      wqk_bf[i] = (bf16)wqk[i];
    } else if (i < 327680) {
      wv_bf[i - 65536] = (bf16)wv[i - 65536];
    } else if (i < 589824) {
      const int j = i - 327680;
      const float wf = wt[j];
      const bf16 h = (bf16)wf;
      wt_hi[j] = h;
      wt_lo[j] = (bf16)(wf - (float)h);
    } else {
      const int j = i - 589824;
      invg[j] = gamma[j] * rsqrtf(rvar[j] + 1e-5f);
    }
  }
}

// ------------------------------------- transpose+convert: [C][N] f32 -> [N][C] bf16
__global__ __launch_bounds__(256) void k_tr(const float* __restrict__ X,
                                            bf16* __restrict__ XT) {
  __shared__ float tile[32][69];
  const int b = blockIdx.z, c0 = blockIdx.y * 32, n0 = blockIdx.x * 64;
  const int t = threadIdx.x;
  const int cc = t >> 4, n4 = (t & 15) * 4;
#pragma unroll
  for (int p = 0; p < 2; p++) {
    const int c = p * 16 + cc;
    const f32x4 v = *(const f32x4*)&X[((size_t)(b * kC + c0 + c)) * kN + n0 + n4];
    tile[c][n4 + 0] = v[0];
    tile[c][n4 + 1] = v[1];
    tile[c][n4 + 2] = v[2];
    tile[c][n4 + 3] = v[3];
  }
  __syncthreads();
  const int n = t >> 2, c8 = (t & 3) * 8;
  bf16x8 o;
#pragma unroll
  for (int j = 0; j < 8; j++) o[j] = (bf16)tile[c8 + j][n];
  *(bf16x8*)&XT[((size_t)(b * kN + n0 + n)) * kC + c0 + c8] = o;
}

// -------------- projection to TRANSPOSED output: OT[b][n][128] = (W @ X)^T
__global__ __launch_bounds__(256) void k_projT(const bf16* __restrict__ XT,
                                               const bf16* __restrict__ W,
                                               bf16* __restrict__ OT) {
  const int b = blockIdx.y, n0 = blockIdx.x * 64;
  const int t = threadIdx.x, w = t >> 6, l = t & 63, lo4 = l & 15, g = l >> 4;
  const int n = n0 + w * 16 + lo4;
  f32x4 acc[8] = {};
  const bf16* xrow = &XT[((size_t)(b * kN + n)) * kC + g * 8];
#pragma unroll
  for (int ks = 0; ks < 16; ks++) {
    const bf16x8 bfr = *(const bf16x8*)&xrow[ks * 32];
#pragma unroll
    for (int mf = 0; mf < 8; mf++) {
      const bf16x8 afr =
          *(const bf16x8*)&W[(size_t)(mf * 16 + lo4) * kC + ks * 32 + g * 8];
      acc[mf] = MFMA16(afr, bfr, acc[mf]);
    }
  }
  bf16* orow = &OT[((size_t)(b * kN + n)) * kC4];
#pragma unroll
  for (int mf = 0; mf < 8; mf++) {
    bf16x4 o;
#pragma unroll
    for (int r = 0; r < 4; r++) o[r] = (bf16)acc[mf][r];
    *(bf16x4*)&orow[mf * 16 + g * 4] = o;
  }
}

// -------------- value projection: xv[b][c][n] bf16 = wv @ x + bv
__global__ __launch_bounds__(256) void k_projV(const bf16* __restrict__ XT,
                                               const bf16* __restrict__ Wv,
                                               const float* __restrict__ bv,
                                               bf16* __restrict__ xv) {
  __shared__ __align__(16) bf16 bnc[4][16][136];
  const int b = blockIdx.z, c0 = blockIdx.y * 64, n0 = blockIdx.x * 128;
  const int t = threadIdx.x, w = t >> 6, l = t & 63, lo4 = l & 15, g = l >> 4;
  const int crow = c0 + w * 16 + lo4;
  f32x4 acc[8] = {};
#pragma unroll
  for (int ks = 0; ks < 16; ks++) {
    const bf16x8 afr = *(const bf16x8*)&Wv[(size_t)crow * kC + ks * 32 + g * 8];
#pragma unroll
    for (int nf = 0; nf < 8; nf++) {
      const bf16x8 bfr =
          *(const bf16x8*)&XT[((size_t)(b * kN + n0 + nf * 16 + lo4)) * kC +
                              ks * 32 + g * 8];
      acc[nf] = MFMA16(afr, bfr, acc[nf]);
    }
  }
  float bvv[4];
#pragma unroll
  for (int r = 0; r < 4; r++) bvv[r] = bv[c0 + w * 16 + 4 * g + r];
#pragma unroll
  for (int nf = 0; nf < 8; nf++)
#pragma unroll
    for (int r = 0; r < 4; r++)
      bnc[w][4 * g + r][nf * 16 + lo4] = (bf16)(acc[nf][r] + bvv[r]);
  const int rr = l >> 2, seg = (l & 3) * 32;
  const bf16x8 v0 = *(const bf16x8*)&bnc[w][rr][seg];
  const bf16x8 v1 = *(const bf16x8*)&bnc[w][rr][seg + 8];
  const bf16x8 v2 = *(const bf16x8*)&bnc[w][rr][seg + 16];
  const bf16x8 v3 = *(const bf16x8*)&bnc[w][rr][seg + 24];
  bf16* orow = &xv[((size_t)(b * kC + c0 + w * 16 + rr)) * kN + n0 + seg];
  *(bf16x8*)&orow[0] = v0;
  *(bf16x8*)&orow[8] = v1;
  *(bf16x8*)&orow[16] = v2;
  *(bf16x8*)&orow[24] = v3;
}

// ---------------- pass 1: per-row (n) softmax max & sum-of-exp
__global__ __launch_bounds__(256) void k_stats(
    const bf16* __restrict__ qT, const bf16* __restrict__ kT,
    const int* __restrict__ mask, const float* __restrict__ cnt,
    float* __restrict__ rowmax, float* __restrict__ rowsum) {
  __shared__ __align__(16) bf16 kts[2][64][128];
  __shared__ int mss[2][64];
  const int blk = blockIdx.x;
  const int b = blk & 7, n0 = (blk >> 3) * 64;
  const int t_ = threadIdx.x, w = t_ >> 6, l = t_ & 63, lo4 = l & 15, g = l >> 4;
  const float invd = 1.0f / (cnt[b] + 1e-9f);
  const float zrow = -9e15f * invd;
  const int n = n0 + w * 16 + lo4;
  bf16x8 aq[4];
#pragma unroll
  for (int ks = 0; ks < 4; ks++)
    aq[ks] = *(const bf16x8*)&qT[((size_t)(b * kN + n)) * kC4 + ks * 32 + g * 8];
  const int mn = mask[b * kN + n];
  float rm = -INFINITY, rs = 0.0f;
  bf16x8 rg[4];
#pragma unroll
  for (int i = 0; i < 4; i++) {
    const int row = w * 16 + i * 4 + g;
    const int q = (l & 15) ^ (row & 7);
    rg[i] = *(const bf16x8*)&kT[((size_t)(b * kN + row)) * kC4 + q * 8];
  }
#pragma unroll
  for (int i = 0; i < 4; i++) {
    const int row = w * 16 + i * 4 + g;
    *(bf16x8*)&kts[0][row][(l & 15) * 8] = rg[i];
  }
  if (t_ < 16) *(int4*)&mss[0][t_ * 4] = *(const int4*)&mask[b * kN + t_ * 4];
  __syncthreads();
  for (int tt = 0; tt < 32; tt++) {
    const int buf = tt & 1;
    if (tt < 31) {
      const int m0 = (tt + 1) * 64;
#pragma unroll
      for (int i = 0; i < 4; i++) {
        const int row = w * 16 + i * 4 + g;
        const int q = (l & 15) ^ (row & 7);
        rg[i] = *(const bf16x8*)&kT[((size_t)(b * kN + m0 + row)) * kC4 + q * 8];
      }
    }
    f32x4 e[4] = {};
#pragma unroll
    for (int mf = 0; mf < 4; mf++) {
#pragma unroll
      for (int ks = 0; ks < 4; ks++) {
        const bf16x8 bk =
            *(const bf16x8*)&kts[buf][mf * 16 + lo4]
                                 [((ks * 4 + g) ^ (lo4 & 7)) * 8];
        e[mf] = MFMA16(bk, aq[ks], e[mf]);
      }
    }
    float z[4][4];
#pragma unroll
    for (int mf = 0; mf < 4; mf++) {
      const int4 mi = *(const int4*)&mss[buf][mf * 16 + g * 4];
      const int mm4[4] = {mi.x, mi.y, mi.z, mi.w};
#pragma unroll
      for (int r = 0; r < 4; r++)
        z[mf][r] = mm4[r] ? (mn ? e[mf][r] * invd : zrow) : -9e24f;
    }
    float vmax = z[0][0];
#pragma unroll
    for (int mf = 0; mf < 4; mf++)
#pragma unroll
      for (int r = 0; r < 4; r++) vmax = fmaxf(vmax, z[mf][r]);
    vmax = fmaxf(vmax, __shfl_xor(vmax, 16));
    vmax = fmaxf(vmax, __shfl_xor(vmax, 32));
    const float nm = fmaxf(rm, vmax);
    float se = 0.0f;
#pragma unroll
    for (int mf = 0; mf < 4; mf++)
#pragma unroll
      for (int r = 0; r < 4; r++) se += __expf(z[mf][r] - nm);
    se += __shfl_xor(se, 16);
    se += __shfl_xor(se, 32);
    rs = rs * __expf(rm - nm) + se;
    rm = nm;
    if (tt < 31) {
#pragma unroll
      for (int i = 0; i < 4; i++) {
        const int row = w * 16 + i * 4 + g;
        *(bf16x8*)&kts[buf ^ 1][row][(l & 15) * 8] = rg[i];
      }
      if (t_ < 16)
        *(int4*)&mss[buf ^ 1][t_ * 4] =
            *(const int4*)&mask[b * kN + (tt + 1) * 64 + t_ * 4];
    }
    __syncthreads();
  }
  if (g == 0) {
    rowmax[b * kN + n] = rm;
    rowsum[b * kN + n] = rs;
  }
}

// -------- pass 2: block 64m x 512c (full C), 8 waves = 8 c-slices of 64.
// energy via MFMA(Q,K) -> D[n][m]: packed b64 P-writes; P dbuf, 1 barrier/iter;
// xv read straight from L2 (no staging). h = x - x_r -> hT hi/lo.
__global__ __launch_bounds__(512) void k_attn(
    const bf16* __restrict__ qT, const bf16* __restrict__ kT,
    const bf16* __restrict__ xv, const float* __restrict__ x,
    const int* __restrict__ mask, const float* __restrict__ cnt,
    const float* __restrict__ rowmax, const float* __restrict__ rowsum,
    bf16* __restrict__ hT_hi, bf16* __restrict__ hT_lo) {
  __shared__ __align__(16) bf16 P[2][64][40];
  __shared__ __align__(16) bf16 bnc[8][16][72];
  const int blk = blockIdx.x;  // 256 = 8 b x 32 mb
  const int b = blk & 7;
  const int m0 = (blk >> 3) * 64;
  const int t_ = threadIdx.x, w = t_ >> 6, l = t_ & 63, lo4 = l & 15, g = l >> 4;
  const int mc = w & 3, nf = w >> 2, cb = w * 64;
  const float invd = 1.0f / (cnt[b] + 1e-9f);
  const float zrow = -9e15f * invd;
  // B-fragments of K (cols m = m0 + mc*16 + lo4)
  bf16x8 ak[4];
#pragma unroll
  for (int ks = 0; ks < 4; ks++)
    ak[ks] = *(const bf16x8*)&kT[((size_t)(b * kN + m0 + mc * 16 + lo4)) * kC4 +
                                 ks * 32 + g * 8];
  const int mm = mask[b * kN + m0 + mc * 16 + lo4];
  const bf16* xvb = &xv[((size_t)(b * kC + cb)) * kN];
  f32x4 acc[4][4] = {};

#define ENERGY(TT, PBUF)                                                       \
  {                                                                            \
    const int nb = (TT)*32 + nf * 16;                                          \
    f32x4 e = {};                                                              \
    const bf16* qrow = &qT[((size_t)(b * kN + nb + lo4)) * kC4 + g * 8];       \
    _Pragma("unroll") for (int ks = 0; ks < 4; ks++) e =                       \
        MFMA16(*(const bf16x8*)&qrow[ks * 32], ak[ks], e);                     \
    const int nr = b * kN + nb + g * 4;                                        \
    const int4 mi = *(const int4*)&mask[nr];                                   \
    const f32x4 rmv = *(const f32x4*)&rowmax[nr];                              \
    const f32x4 rsv = *(const f32x4*)&rowsum[nr];                              \
    const int mn4[4] = {mi.x, mi.y, mi.z, mi.w};                               \
    bf16x4 pk;                                                                 \
    _Pragma("unroll") for (int r = 0; r < 4; r++) {                            \
      const float zz = mm ? (mn4[r] ? e[r] * invd : zrow) : -9e24f;            \
      pk[r] = (bf16)(__expf(zz - rmv[r]) * (1.0f / rsv[r]));                   \
    }                                                                          \
    *(bf16x4*)&P[PBUF][mc * 16 + lo4][nf * 16 + g * 4] = pk;                   \
  }

  ENERGY(0, 0);
  __syncthreads();
  for (int tt = 0; tt < 64; tt++) {
    const int buf = tt & 1;
    if (tt < 63) ENERGY(tt + 1, buf ^ 1);
    // PV: acc[mf][cf] += P[m][n] @ xv[c][n]^T
    bf16x8 bvr[4];
#pragma unroll
    for (int cf = 0; cf < 4; cf++)
      bvr[cf] =
          *(const bf16x8*)&xvb[(size_t)(cf * 16 + lo4) * kN + tt * 32 + g * 8];
#pragma unroll
    for (int mf = 0; mf < 4; mf++) {
      const bf16x8 pa = *(const bf16x8*)&P[buf][mf * 16 + lo4][g * 8];
#pragma unroll
      for (int cf = 0; cf < 4; cf++)
        acc[mf][cf] = MFMA16(pa, bvr[cf], acc[mf][cf]);
    }
    __syncthreads();
  }
#undef ENERGY
  // epilogue: h = x - x_r; per-wave LDS transpose; hi/lo split
#pragma unroll
  for (int mf = 0; mf < 4; mf++) {
    float hh[4][4];
#pragma unroll
    for (int cf = 0; cf < 4; cf++) {
      const int c = cb + cf * 16 + lo4;
      const f32x4 xval = *(const f32x4*)&x[((size_t)(b * kC + c)) * kN + m0 +
                                           mf * 16 + g * 4];
#pragma unroll
      for (int r = 0; r < 4; r++) hh[cf][r] = xval[r] - acc[mf][cf][r];
    }
#pragma unroll
    for (int cf = 0; cf < 4; cf++)
#pragma unroll
      for (int r = 0; r < 4; r++)
        bnc[w][4 * g + r][cf * 16 + lo4] = (bf16)hh[cf][r];
    {
      const int rr = l >> 2, seg = (l & 3) * 16;
      const bf16x8 v0 = *(const bf16x8*)&bnc[w][rr][seg];
      const bf16x8 v1 = *(const bf16x8*)&bnc[w][rr][seg + 8];
      bf16* orow =
          &hT_hi[((size_t)(b * kN + m0 + mf * 16 + rr)) * kC + cb + seg];
      *(bf16x8*)&orow[0] = v0;
      *(bf16x8*)&orow[8] = v1;
    }
#pragma unroll
    for (int cf = 0; cf < 4; cf++)
#pragma unroll
      for (int r = 0; r < 4; r++) {
        const float hv = hh[cf][r];
        const bf16 hb = (bf16)hv;
        bnc[w][4 * g + r][cf * 16 + lo4] = (bf16)(hv - (float)hb);
      }
    {
      const int rr = l >> 2, seg = (l & 3) * 16;
      const bf16x8 v0 = *(const bf16x8*)&bnc[w][rr][seg];
      const bf16x8 v1 = *(const bf16x8*)&bnc[w][rr][seg + 8];
      bf16* orow =
          &hT_lo[((size_t)(b * kN + m0 + mf * 16 + rr)) * kC + cb + seg];
      *(bf16x8*)&orow[0] = v0;
      *(bf16x8*)&orow[8] = v1;
    }
  }
}

// -------- final: y^T = h^T @ wt^T (3-term hi/lo), BN(eval)+ReLU+residual
__global__ __launch_bounds__(256) void k_final(
    const bf16* __restrict__ hT_hi, const bf16* __restrict__ hT_lo,
    const bf16* __restrict__ wt_hi, const bf16* __restrict__ wt_lo,
    const float* __restrict__ x, const float* __restrict__ bt,
    const float* __restrict__ beta, const float* __restrict__ rmean,
    const float* __restrict__ invg, float* __restrict__ out) {
  const int b = blockIdx.z, c0 = blockIdx.y * 128, n0 = blockIdx.x * 64;
  const int t = threadIdx.x, w = t >> 6, l = t & 63, lo4 = l & 15, g = l >> 4;
  const int n = n0 + w * 16 + lo4;
  f32x4 acc[8] = {};
  const bf16* hh = &hT_hi[((size_t)(b * kN + n)) * kC + g * 8];
  const bf16* hl = &hT_lo[((size_t)(b * kN + n)) * kC + g * 8];
#pragma unroll
  for (int ks = 0; ks < 16; ks++) {
    const bf16x8 ah = *(const bf16x8*)&hh[ks * 32];
    const bf16x8 al = *(const bf16x8*)&hl[ks * 32];
#pragma unroll
    for (int cf = 0; cf < 8; cf++) {
      const bf16x8 wh = *(const bf16x8*)&wt_hi[(size_t)(c0 + cf * 16 + lo4) * kC +
                                               ks * 32 + g * 8];
      const bf16x8 wl = *(const bf16x8*)&wt_lo[(size_t)(c0 + cf * 16 + lo4) * kC +
                                               ks * 32 + g * 8];
      acc[cf] = MFMA16(ah, wh, acc[cf]);
      acc[cf] = MFMA16(al, wh, acc[cf]);
      acc[cf] = MFMA16(ah, wl, acc[cf]);
    }
  }
#pragma unroll
  for (int cf = 0; cf < 8; cf++) {
    const int cc = c0 + cf * 16 + lo4;
    const float btv = bt[cc], rmv = rmean[cc], igv = invg[cc], bev = beta[cc];
    const size_t base = ((size_t)(b * kC + cc)) * kN + n0 + w * 16 + 4 * g;
    const f32x4 xval = *(const f32x4*)&x[base];
    f32x4 o;
#pragma unroll
    for (int r = 0; r < 4; r++) {
      float v = (acc[cf][r] + btv - rmv) * igv + bev;
      v = fmaxf(v, 0.0f);
      o[r] = xval[r] + v;
    }
    *(f32x4*)&out[base] = o;
  }
}

extern "C" void kernel_launch(void* const* d_in, const int* in_sizes, int n_in,
                              void* d_out, int out_size, void* d_ws,
                              size_t ws_size, hipStream_t stream) {
  const float* x = (const float*)d_in[0];
  const float* query = (const float*)d_in[1];
  const int* mask = (const int*)d_in[2];
  const float* wqk = (const float*)d_in[3];
  const float* wv = (const float*)d_in[4];
  const float* bv = (const float*)d_in[5];
  const float* wt = (const float*)d_in[6];
  const float* bt = (const float*)d_in[7];
  const float* gamma = (const float*)d_in[8];
  const float* beta = (const float*)d_in[9];
  const float* rmean = (const float*)d_in[10];
  const float* rvar = (const float*)d_in[11];
  float* out = (float*)d_out;
  char* wsb = (char*)d_ws;

  const size_t MB = 1024 * 1024;
  bf16* trbuf = (bf16*)wsb;                      // 16 MB (queryT/xT, later hT)
  bf16* hT_hi = trbuf;                           // 8 MB [B][N][C]
  bf16* hT_lo = trbuf + (size_t)kB * kN * kC;    // 8 MB
  bf16* qT = (bf16*)(wsb + 16 * MB);             // 4 MB [B][N][C4]
  bf16* kT = (bf16*)(wsb + 20 * MB);             // 4 MB [B][N][C4]
  bf16* xv = (bf16*)(wsb + 24 * MB);             // 16 MB [B][C][N]
  bf16* wqk_bf = (bf16*)(wsb + 40 * MB);         // 131072 B
  bf16* wv_bf = wqk_bf + 65536;                  // 524288 B
  bf16* wt_hi = wv_bf + 262144;                  // 524288 B
  bf16* wt_lo = wt_hi + 262144;                  // 524288 B
  float* invg = (float*)(wt_lo + 262144);        // 2048 B
  float* rowmax = invg + 512;                    // 64 KB
  float* rowsum = rowmax + kB * kN;              // 64 KB
  float* cnt = rowsum + kB * kN;                 // 32 B

  k_prep<<<136, 256, 0, stream>>>(mask, wqk, wv, wt, gamma, rvar, cnt, wqk_bf,
                                  wv_bf, wt_hi, wt_lo, invg);
  k_tr<<<dim3(kN / 64, kC / 32, kB), 256, 0, stream>>>(query, trbuf);
  k_projT<<<dim3(kN / 64, kB), 256, 0, stream>>>(trbuf, wqk_bf, qT);
  k_tr<<<dim3(kN / 64, kC / 32, kB), 256, 0, stream>>>(x, trbuf);
  k_projT<<<dim3(kN / 64, kB), 256, 0, stream>>>(trbuf, wqk_bf, kT);
  k_projV<<<dim3(kN / 128, kC / 64, kB), 256, 0, stream>>>(trbuf, wv_bf, bv,
                                                           xv);
  k_stats<<<256, 256, 0, stream>>>(qT, kT, mask, cnt, rowmax, rowsum);
  k_attn<<<256, 512, 0, stream>>>(qT, kT, xv, x, mask, cnt, rowmax, rowsum,
                                  hT_hi, hT_lo);
  k_final<<<dim3(kN / 64, kC / 128, kB), 256, 0, stream>>>(
      hT_hi, hT_lo, wt_hi, wt_lo, x, bt, beta, rmean, invg, out);
}

// Round 7
// 369.670 us; speedup vs baseline: 4.7682x; 1.2943x over previous
//
#include <hip/hip_runtime.h>
#include <math.h>

typedef __bf16 bf16;
typedef bf16 bf16x8 __attribute__((ext_vector_type(8)));
typedef bf16 bf16x4 __attribute__((ext_vector_type(4)));
typedef float f32x4 __attribute__((ext_vector_type(4)));

constexpr int kB = 8, kC = 512, kC4 = 128, kN = 2048;

#define MFMA16(a, b, c) __builtin_amdgcn_mfma_f32_16x16x32_bf16(a, b, c, 0, 0, 0)

// ---------------------------------------------------------------- prep
__global__ __launch_bounds__(256) void k_prep(
    const int* __restrict__ mask, const float* __restrict__ wqk,
    const float* __restrict__ wv, const float* __restrict__ wt,
    const float* __restrict__ gamma, const float* __restrict__ rvar,
    float* __restrict__ cnt, bf16* __restrict__ wqk_bf,
    bf16* __restrict__ wv_bf, bf16* __restrict__ wt_bf,
    float* __restrict__ invg, float* __restrict__ Ssum) {
  const int t = threadIdx.x;
  if (blockIdx.x < 8) {
    const int b = blockIdx.x;
    int s = 0;
    for (int i = t; i < kN; i += 256) s += mask[b * kN + i];
    __shared__ int red[256];
    red[t] = s;
    __syncthreads();
    for (int off = 128; off > 0; off >>= 1) {
      if (t < off) red[t] += red[t + off];
      __syncthreads();
    }
    if (t == 0) cnt[b] = (float)red[0];
    return;
  }
  const int total = 65536 + 262144 + 262144 + 512 + 16384;
  for (int i = (blockIdx.x - 8) * 256 + t; i < total; i += 128 * 256) {
    if (i < 65536) {
      wqk_bf[i] = (bf16)wqk[i];
    } else if (i < 327680) {
      wv_bf[i - 65536] = (bf16)wv[i - 65536];
    } else if (i < 589824) {
      wt_bf[i - 327680] = (bf16)wt[i - 327680];
    } else if (i < 590336) {
      const int j = i - 589824;
      invg[j] = gamma[j] * rsqrtf(rvar[j] + 1e-5f);
    } else {
      Ssum[i - 590336] = 0.0f;
    }
  }
}

// ------------------------------------- transpose+convert: [C][N] f32 -> [N][C] bf16
__global__ __launch_bounds__(256) void k_tr(const float* __restrict__ X,
                                            bf16* __restrict__ XT) {
  __shared__ float tile[32][69];
  const int b = blockIdx.z, c0 = blockIdx.y * 32, n0 = blockIdx.x * 64;
  const int t = threadIdx.x;
  const int cc = t >> 4, n4 = (t & 15) * 4;
#pragma unroll
  for (int p = 0; p < 2; p++) {
    const int c = p * 16 + cc;
    const f32x4 v = *(const f32x4*)&X[((size_t)(b * kC + c0 + c)) * kN + n0 + n4];
    tile[c][n4 + 0] = v[0];
    tile[c][n4 + 1] = v[1];
    tile[c][n4 + 2] = v[2];
    tile[c][n4 + 3] = v[3];
  }
  __syncthreads();
  const int n = t >> 2, c8 = (t & 3) * 8;
  bf16x8 o;
#pragma unroll
  for (int j = 0; j < 8; j++) o[j] = (bf16)tile[c8 + j][n];
  *(bf16x8*)&XT[((size_t)(b * kN + n0 + n)) * kC + c0 + c8] = o;
}

// -------------- projection to TRANSPOSED output: OT[b][n][128] = (W @ X)^T
__global__ __launch_bounds__(256) void k_projT(const bf16* __restrict__ XT,
                                               const bf16* __restrict__ W,
                                               bf16* __restrict__ OT) {
  const int b = blockIdx.y, n0 = blockIdx.x * 64;
  const int t = threadIdx.x, w = t >> 6, l = t & 63, lo4 = l & 15, g = l >> 4;
  const int n = n0 + w * 16 + lo4;
  f32x4 acc[8] = {};
  const bf16* xrow = &XT[((size_t)(b * kN + n)) * kC + g * 8];
#pragma unroll
  for (int ks = 0; ks < 16; ks++) {
    const bf16x8 bfr = *(const bf16x8*)&xrow[ks * 32];
#pragma unroll
    for (int mf = 0; mf < 8; mf++) {
      const bf16x8 afr =
          *(const bf16x8*)&W[(size_t)(mf * 16 + lo4) * kC + ks * 32 + g * 8];
      acc[mf] = MFMA16(afr, bfr, acc[mf]);
    }
  }
  bf16* orow = &OT[((size_t)(b * kN + n)) * kC4];
#pragma unroll
  for (int mf = 0; mf < 8; mf++) {
    bf16x4 o;
#pragma unroll
    for (int r = 0; r < 4; r++) o[r] = (bf16)acc[mf][r];
    *(bf16x4*)&orow[mf * 16 + g * 4] = o;
  }
}

// -------------- value projection -> TILED layout xv2[b][n>>6][c][n&63] bf16
__global__ __launch_bounds__(256) void k_projV(const bf16* __restrict__ XT,
                                               const bf16* __restrict__ Wv,
                                               const float* __restrict__ bv,
                                               bf16* __restrict__ xv2) {
  __shared__ __align__(16) bf16 bnc[4][16][136];
  const int b = blockIdx.z, c0 = blockIdx.y * 64, n0 = blockIdx.x * 128;
  const int t = threadIdx.x, w = t >> 6, l = t & 63, lo4 = l & 15, g = l >> 4;
  const int crow = c0 + w * 16 + lo4;
  f32x4 acc[8] = {};
#pragma unroll
  for (int ks = 0; ks < 16; ks++) {
    const bf16x8 afr = *(const bf16x8*)&Wv[(size_t)crow * kC + ks * 32 + g * 8];
#pragma unroll
    for (int nf = 0; nf < 8; nf++) {
      const bf16x8 bfr =
          *(const bf16x8*)&XT[((size_t)(b * kN + n0 + nf * 16 + lo4)) * kC +
                              ks * 32 + g * 8];
      acc[nf] = MFMA16(afr, bfr, acc[nf]);
    }
  }
  float bvv[4];
#pragma unroll
  for (int r = 0; r < 4; r++) bvv[r] = bv[c0 + w * 16 + 4 * g + r];
#pragma unroll
  for (int nf = 0; nf < 8; nf++)
#pragma unroll
    for (int r = 0; r < 4; r++)
      bnc[w][4 * g + r][nf * 16 + lo4] = (bf16)(acc[nf][r] + bvv[r]);
  const int rr = l >> 2, seg = (l & 3) * 32;
  const bf16x8 v0 = *(const bf16x8*)&bnc[w][rr][seg];
  const bf16x8 v1 = *(const bf16x8*)&bnc[w][rr][seg + 8];
  const bf16x8 v2 = *(const bf16x8*)&bnc[w][rr][seg + 16];
  const bf16x8 v3 = *(const bf16x8*)&bnc[w][rr][seg + 24];
  const int c = c0 + w * 16 + rr;
  const int nn = n0 + seg;  // multiple of 32
  const int nb2 = nn >> 6, ni0 = nn & 63;
  bf16* orow = &xv2[(((size_t)b * 32 + nb2) * kC + c) * 64 + ni0];
  *(bf16x8*)&orow[0] = v0;
  *(bf16x8*)&orow[8] = v1;
  *(bf16x8*)&orow[16] = v2;
  *(bf16x8*)&orow[24] = v3;
}

// ---------------- pass 1: U^T[m][n] = exp-factor, partial S[n] via atomics
__global__ __launch_bounds__(256) void k_sum(
    const bf16* __restrict__ qT, const bf16* __restrict__ kT,
    const int* __restrict__ mask, const float* __restrict__ cnt,
    bf16* __restrict__ UT, float* __restrict__ Ssum) {
  __shared__ __align__(16) bf16 kts[2][64][128];
  __shared__ int mss[2][64];
  const int blk = blockIdx.x;
  const int b = blk & 7, nb = (blk >> 3) & 31, mh2 = blk >> 8;
  const int m00 = mh2 * 1024;
  const int t_ = threadIdx.x, w = t_ >> 6, l = t_ & 63, lo4 = l & 15, g = l >> 4;
  const float invd = 1.0f / (cnt[b] + 1e-9f);
  const int n0 = nb * 64;
  bf16x8 aq[4];
#pragma unroll
  for (int ks = 0; ks < 4; ks++)
    aq[ks] = *(const bf16x8*)&qT[((size_t)(b * kN + n0 + w * 16 + lo4)) * kC4 +
                                 ks * 32 + g * 8];
  const int nq = n0 + w * 16 + g * 4;
  const int4 mi = *(const int4*)&mask[b * kN + nq];
  const int mn4[4] = {mi.x, mi.y, mi.z, mi.w};
  float rs4[4] = {0.0f, 0.0f, 0.0f, 0.0f};
  bf16x8 rg[4];
#pragma unroll
  for (int i = 0; i < 4; i++) {
    const int row = w * 16 + i * 4 + g;
    const int q = (l & 15) ^ (row & 7);
    rg[i] = *(const bf16x8*)&kT[((size_t)(b * kN + m00 + row)) * kC4 + q * 8];
  }
#pragma unroll
  for (int i = 0; i < 4; i++) {
    const int row = w * 16 + i * 4 + g;
    *(bf16x8*)&kts[0][row][(l & 15) * 8] = rg[i];
  }
  if (t_ < 16)
    *(int4*)&mss[0][t_ * 4] = *(const int4*)&mask[b * kN + m00 + t_ * 4];
  __syncthreads();
  for (int tt = 0; tt < 16; tt++) {
    const int buf = tt & 1;
    if (tt < 15) {
      const int m0 = m00 + (tt + 1) * 64;
#pragma unroll
      for (int i = 0; i < 4; i++) {
        const int row = w * 16 + i * 4 + g;
        const int q = (l & 15) ^ (row & 7);
        rg[i] = *(const bf16x8*)&kT[((size_t)(b * kN + m0 + row)) * kC4 + q * 8];
      }
    }
#pragma unroll
    for (int mf = 0; mf < 4; mf++) {
      f32x4 e = {};
#pragma unroll
      for (int ks = 0; ks < 4; ks++) {
        const bf16x8 bk =
            *(const bf16x8*)&kts[buf][mf * 16 + lo4]
                                 [((ks * 4 + g) ^ (lo4 & 7)) * 8];
        e = MFMA16(aq[ks], bk, e);
      }
      const int mmv = mss[buf][mf * 16 + lo4];
      bf16x4 pk;
#pragma unroll
      for (int r = 0; r < 4; r++) {
        const float u = mmv ? (mn4[r] ? __expf(e[r] * invd) : 1.0f) : 0.0f;
        pk[r] = (bf16)u;
        rs4[r] += (float)pk[r];
      }
      const int m = m00 + tt * 64 + mf * 16 + lo4;
      *(bf16x4*)&UT[((size_t)(b * kN + m)) * kN + nq] = pk;
    }
    if (tt < 15) {
#pragma unroll
      for (int i = 0; i < 4; i++) {
        const int row = w * 16 + i * 4 + g;
        *(bf16x8*)&kts[buf ^ 1][row][(l & 15) * 8] = rg[i];
      }
      if (t_ < 16)
        *(int4*)&mss[buf ^ 1][t_ * 4] =
            *(const int4*)&mask[b * kN + m00 + (tt + 1) * 64 + t_ * 4];
    }
    __syncthreads();
  }
#pragma unroll
  for (int r = 0; r < 4; r++) {
#pragma unroll
    for (int off = 1; off < 16; off <<= 1) rs4[r] += __shfl_xor(rs4[r], off);
  }
  if (lo4 == 0) {
#pragma unroll
    for (int r = 0; r < 4; r++) atomicAdd(&Ssum[b * kN + nq + r], rs4[r]);
  }
}

// ---------------- scale xv2 in place by 1/S[n]
__global__ __launch_bounds__(256) void k_scale(bf16* __restrict__ xv2,
                                               const float* __restrict__ Ssum) {
  const int blk = blockIdx.x;  // 512 = 8b x 64 parts
  const int b = blk & 7, part = blk >> 3;
  const size_t base = (size_t)b * (32 * kC * 64);
  for (int it = 0; it < 8; it++) {
    const int chunk = part * 2048 + it * 256 + threadIdx.x;
    const size_t e = (size_t)chunk * 8;
    const int n = ((int)(e >> 15)) * 64 + ((int)e & 63);
    bf16x8 v = *(bf16x8*)&xv2[base + e];
    const f32x4 s0 = *(const f32x4*)&Ssum[b * kN + n];
    const f32x4 s1 = *(const f32x4*)&Ssum[b * kN + n + 4];
    bf16x8 o;
#pragma unroll
    for (int j = 0; j < 4; j++) o[j] = (bf16)((float)v[j] / s0[j]);
#pragma unroll
    for (int j = 0; j < 4; j++) o[4 + j] = (bf16)((float)v[4 + j] / s1[j]);
    *(bf16x8*)&xv2[base + e] = o;
  }
}

// -------- pass 2: pure GEMM x_r^T[m][c] = sum_n UT[m][n] * xv2'[c][n]
// block 64m x 256c, 8 waves = 2mh x 4cq. A-tile (UT 64x64) double-buffered
// via REGISTER staging + XOR-swizzled ds_write_b128; 1 barrier/iter.
__global__ __launch_bounds__(512, 4) void k_attn2(
    const bf16* __restrict__ UT, const bf16* __restrict__ xv2,
    const float* __restrict__ x, bf16* __restrict__ hT) {
  __shared__ __align__(16) bf16 Abuf[2][64][64];
  __shared__ __align__(16) bf16 bnc[8][16][72];
  const int blk = blockIdx.x;  // 512 = 8b x 2cs x 32mb
  const int b = blk & 7, cs = (blk >> 3) & 1, mb = blk >> 4;
  const int m0 = mb * 64, c0 = cs * 256;
  const int t_ = threadIdx.x, w = t_ >> 6, l = t_ & 63, lo4 = l & 15, g = l >> 4;
  const int mh = w >> 2, cq = w & 3;
  // staging: thread -> (row, chunk p); LDS pos = p ^ (row&7)
  const int srow = t_ >> 3, sp = t_ & 7;
  const int spos = sp ^ (srow & 7);
  const bf16* sbase = &UT[((size_t)(b * kN + m0 + srow)) * kN + sp * 8];
  f32x4 acc[2][4] = {};
  bf16x8 rg = *(const bf16x8*)&sbase[0];
  *(bf16x8*)&Abuf[0][srow][spos * 8] = rg;
  __syncthreads();
  for (int tt = 0; tt < 32; tt++) {
    const int buf = tt & 1;
    if (tt < 31) rg = *(const bf16x8*)&sbase[(tt + 1) * 64];
    bf16x8 pa[2][2];
#pragma unroll
    for (int mf = 0; mf < 2; mf++) {
      const int row = mh * 32 + mf * 16 + lo4;
#pragma unroll
      for (int k2 = 0; k2 < 2; k2++)
        pa[mf][k2] =
            *(const bf16x8*)&Abuf[buf][row][((k2 * 4 + g) ^ (row & 7)) * 8];
    }
#pragma unroll
    for (int k2 = 0; k2 < 2; k2++) {
      bf16x8 bvv[4];
#pragma unroll
      for (int cf = 0; cf < 4; cf++)
        bvv[cf] = *(const bf16x8*)&xv2[(((size_t)b * 32 + tt) * kC + c0 +
                                        cq * 64 + cf * 16 + lo4) * 64 +
                                       k2 * 32 + g * 8];
#pragma unroll
      for (int mf = 0; mf < 2; mf++)
#pragma unroll
        for (int cf = 0; cf < 4; cf++)
          acc[mf][cf] = MFMA16(pa[mf][k2], bvv[cf], acc[mf][cf]);
    }
    if (tt < 31) *(bf16x8*)&Abuf[buf ^ 1][srow][spos * 8] = rg;
    __syncthreads();
  }
  // epilogue: h = x - x_r; per-wave LDS transpose -> hT[n][c]
#pragma unroll
  for (int mf = 0; mf < 2; mf++) {
    const int mbase = m0 + mh * 32 + mf * 16;
    float hh[4][4];
#pragma unroll
    for (int cf = 0; cf < 4; cf++) {
      const int c = c0 + cq * 64 + cf * 16 + lo4;
      const f32x4 xval =
          *(const f32x4*)&x[((size_t)(b * kC + c)) * kN + mbase + g * 4];
#pragma unroll
      for (int r = 0; r < 4; r++) hh[cf][r] = xval[r] - acc[mf][cf][r];
    }
#pragma unroll
    for (int cf = 0; cf < 4; cf++)
#pragma unroll
      for (int r = 0; r < 4; r++)
        bnc[w][4 * g + r][cf * 16 + lo4] = (bf16)hh[cf][r];
    {
      const int rr = l >> 2, seg = (l & 3) * 16;
      const bf16x8 v0 = *(const bf16x8*)&bnc[w][rr][seg];
      const bf16x8 v1 = *(const bf16x8*)&bnc[w][rr][seg + 8];
      bf16* orow =
          &hT[((size_t)(b * kN + mbase + rr)) * kC + c0 + cq * 64 + seg];
      *(bf16x8*)&orow[0] = v0;
      *(bf16x8*)&orow[8] = v1;
    }
  }
}

// -------- final: y^T = h^T @ wt^T, BN(eval)+ReLU+residual
__global__ __launch_bounds__(256) void k_final(
    const bf16* __restrict__ hT, const bf16* __restrict__ wt_bf,
    const float* __restrict__ x, const float* __restrict__ bt,
    const float* __restrict__ beta, const float* __restrict__ rmean,
    const float* __restrict__ invg, float* __restrict__ out) {
  const int b = blockIdx.z, c0 = blockIdx.y * 128, n0 = blockIdx.x * 64;
  const int t = threadIdx.x, w = t >> 6, l = t & 63, lo4 = l & 15, g = l >> 4;
  const int n = n0 + w * 16 + lo4;
  f32x4 acc[8] = {};
  const bf16* hh = &hT[((size_t)(b * kN + n)) * kC + g * 8];
#pragma unroll
  for (int ks = 0; ks < 16; ks++) {
    const bf16x8 ah = *(const bf16x8*)&hh[ks * 32];
#pragma unroll
    for (int cf = 0; cf < 8; cf++) {
      const bf16x8 wh = *(const bf16x8*)&wt_bf[(size_t)(c0 + cf * 16 + lo4) * kC +
                                               ks * 32 + g * 8];
      acc[cf] = MFMA16(ah, wh, acc[cf]);
    }
  }
#pragma unroll
  for (int cf = 0; cf < 8; cf++) {
    const int cc = c0 + cf * 16 + lo4;
    const float btv = bt[cc], rmv = rmean[cc], igv = invg[cc], bev = beta[cc];
    const size_t base = ((size_t)(b * kC + cc)) * kN + n0 + w * 16 + 4 * g;
    const f32x4 xval = *(const f32x4*)&x[base];
    f32x4 o;
#pragma unroll
    for (int r = 0; r < 4; r++) {
      float v = (acc[cf][r] + btv - rmv) * igv + bev;
      v = fmaxf(v, 0.0f);
      o[r] = xval[r] + v;
    }
    *(f32x4*)&out[base] = o;
  }
}

extern "C" void kernel_launch(void* const* d_in, const int* in_sizes, int n_in,
                              void* d_out, int out_size, void* d_ws,
                              size_t ws_size, hipStream_t stream) {
  const float* x = (const float*)d_in[0];
  const float* query = (const float*)d_in[1];
  const int* mask = (const int*)d_in[2];
  const float* wqk = (const float*)d_in[3];
  const float* wv = (const float*)d_in[4];
  const float* bv = (const float*)d_in[5];
  const float* wt = (const float*)d_in[6];
  const float* bt = (const float*)d_in[7];
  const float* gamma = (const float*)d_in[8];
  const float* beta = (const float*)d_in[9];
  const float* rmean = (const float*)d_in[10];
  const float* rvar = (const float*)d_in[11];
  float* out = (float*)d_out;
  char* wsb = (char*)d_ws;

  const size_t MB = 1024 * 1024;
  bf16* UT = (bf16*)wsb;                          // 64 MB [b][m][n]
  bf16* trbuf = (bf16*)wsb;                       // 16 MB (overlaps UT; dead pre-k_sum)
  bf16* xv2 = (bf16*)(wsb + 64 * MB);             // 16 MB tiled
  bf16* hT = (bf16*)(wsb + 80 * MB);              // 8 MB [b][n][c]
  bf16* qT = (bf16*)(wsb + 88 * MB);              // 4 MB
  bf16* kT = (bf16*)(wsb + 92 * MB);              // 4 MB
  bf16* wqk_bf = (bf16*)(wsb + 96 * MB);          // 128 KB
  bf16* wv_bf = wqk_bf + 65536;                   // 512 KB
  bf16* wt_bf = wv_bf + 262144;                   // 512 KB
  float* invg = (float*)(wt_bf + 262144);         // 2 KB
  float* Ssum = invg + 512;                       // 64 KB
  float* cnt = Ssum + kB * kN;                    // 32 B

  k_prep<<<136, 256, 0, stream>>>(mask, wqk, wv, wt, gamma, rvar, cnt, wqk_bf,
                                  wv_bf, wt_bf, invg, Ssum);
  k_tr<<<dim3(kN / 64, kC / 32, kB), 256, 0, stream>>>(query, trbuf);
  k_projT<<<dim3(kN / 64, kB), 256, 0, stream>>>(trbuf, wqk_bf, qT);
  k_tr<<<dim3(kN / 64, kC / 32, kB), 256, 0, stream>>>(x, trbuf);
  k_projT<<<dim3(kN / 64, kB), 256, 0, stream>>>(trbuf, wqk_bf, kT);
  k_projV<<<dim3(kN / 128, kC / 64, kB), 256, 0, stream>>>(trbuf, wv_bf, bv,
                                                           xv2);
  k_sum<<<512, 256, 0, stream>>>(qT, kT, mask, cnt, UT, Ssum);
  k_scale<<<512, 256, 0, stream>>>(xv2, Ssum);
  k_attn2<<<512, 512, 0, stream>>>(UT, xv2, x, hT);
  k_final<<<dim3(kN / 64, kC / 128, kB), 256, 0, stream>>>(
      hT, wt_bf, x, bt, beta, rmean, invg, out);
}

// Round 8
// 244.277 us; speedup vs baseline: 7.2158x; 1.5133x over previous
//
#include <hip/hip_runtime.h>
#include <math.h>

typedef __bf16 bf16;
typedef bf16 bf16x8 __attribute__((ext_vector_type(8)));
typedef bf16 bf16x4 __attribute__((ext_vector_type(4)));
typedef float f32x4 __attribute__((ext_vector_type(4)));

constexpr int kB = 8, kC = 512, kC4 = 128, kN = 2048;

#define MFMA16(a, b, c) __builtin_amdgcn_mfma_f32_16x16x32_bf16(a, b, c, 0, 0, 0)

// ---------------------------------------------------------------- prep
__global__ __launch_bounds__(256) void k_prep(
    const int* __restrict__ mask, const float* __restrict__ wqk,
    const float* __restrict__ wv, const float* __restrict__ wt,
    const float* __restrict__ gamma, const float* __restrict__ rvar,
    float* __restrict__ cnt, bf16* __restrict__ wqk_bf,
    bf16* __restrict__ wv_bf, bf16* __restrict__ wt_bf,
    float* __restrict__ invg, float* __restrict__ Ssum) {
  const int t = threadIdx.x;
  if (blockIdx.x < 8) {
    const int b = blockIdx.x;
    int s = 0;
    for (int i = t; i < kN; i += 256) s += mask[b * kN + i];
    __shared__ int red[256];
    red[t] = s;
    __syncthreads();
    for (int off = 128; off > 0; off >>= 1) {
      if (t < off) red[t] += red[t + off];
      __syncthreads();
    }
    if (t == 0) cnt[b] = (float)red[0];
    return;
  }
  const int total = 65536 + 262144 + 262144 + 512 + 16384;
  for (int i = (blockIdx.x - 8) * 256 + t; i < total; i += 128 * 256) {
    if (i < 65536) {
      wqk_bf[i] = (bf16)wqk[i];
    } else if (i < 327680) {
      wv_bf[i - 65536] = (bf16)wv[i - 65536];
    } else if (i < 589824) {
      wt_bf[i - 327680] = (bf16)wt[i - 327680];
    } else if (i < 590336) {
      const int j = i - 589824;
      invg[j] = gamma[j] * rsqrtf(rvar[j] + 1e-5f);
    } else {
      Ssum[i - 590336] = 0.0f;
    }
  }
}

// ------------------------------------- transpose+convert: [C][N] f32 -> [N][C] bf16
__global__ __launch_bounds__(256) void k_tr(const float* __restrict__ X,
                                            bf16* __restrict__ XT) {
  __shared__ float tile[32][69];
  const int b = blockIdx.z, c0 = blockIdx.y * 32, n0 = blockIdx.x * 64;
  const int t = threadIdx.x;
  const int cc = t >> 4, n4 = (t & 15) * 4;
#pragma unroll
  for (int p = 0; p < 2; p++) {
    const int c = p * 16 + cc;
    const f32x4 v = *(const f32x4*)&X[((size_t)(b * kC + c0 + c)) * kN + n0 + n4];
    tile[c][n4 + 0] = v[0];
    tile[c][n4 + 1] = v[1];
    tile[c][n4 + 2] = v[2];
    tile[c][n4 + 3] = v[3];
  }
  __syncthreads();
  const int n = t >> 2, c8 = (t & 3) * 8;
  bf16x8 o;
#pragma unroll
  for (int j = 0; j < 8; j++) o[j] = (bf16)tile[c8 + j][n];
  *(bf16x8*)&XT[((size_t)(b * kN + n0 + n)) * kC + c0 + c8] = o;
}

// -------------- projection to TRANSPOSED output: OT[b][n][128] = (W @ X)^T
__global__ __launch_bounds__(256) void k_projT(const bf16* __restrict__ XT,
                                               const bf16* __restrict__ W,
                                               bf16* __restrict__ OT) {
  const int b = blockIdx.y, n0 = blockIdx.x * 64;
  const int t = threadIdx.x, w = t >> 6, l = t & 63, lo4 = l & 15, g = l >> 4;
  const int n = n0 + w * 16 + lo4;
  f32x4 acc[8] = {};
  const bf16* xrow = &XT[((size_t)(b * kN + n)) * kC + g * 8];
#pragma unroll
  for (int ks = 0; ks < 16; ks++) {
    const bf16x8 bfr = *(const bf16x8*)&xrow[ks * 32];
#pragma unroll
    for (int mf = 0; mf < 8; mf++) {
      const bf16x8 afr =
          *(const bf16x8*)&W[(size_t)(mf * 16 + lo4) * kC + ks * 32 + g * 8];
      acc[mf] = MFMA16(afr, bfr, acc[mf]);
    }
  }
  bf16* orow = &OT[((size_t)(b * kN + n)) * kC4];
#pragma unroll
  for (int mf = 0; mf < 8; mf++) {
    bf16x4 o;
#pragma unroll
    for (int r = 0; r < 4; r++) o[r] = (bf16)acc[mf][r];
    *(bf16x4*)&orow[mf * 16 + g * 4] = o;
  }
}

// -------------- value projection -> TILED layout xv2[b][n>>6][c][n&63] bf16
__global__ __launch_bounds__(256) void k_projV(const bf16* __restrict__ XT,
                                               const bf16* __restrict__ Wv,
                                               const float* __restrict__ bv,
                                               bf16* __restrict__ xv2) {
  __shared__ __align__(16) bf16 bnc[4][16][136];
  const int b = blockIdx.z, c0 = blockIdx.y * 64, n0 = blockIdx.x * 128;
  const int t = threadIdx.x, w = t >> 6, l = t & 63, lo4 = l & 15, g = l >> 4;
  const int crow = c0 + w * 16 + lo4;
  f32x4 acc[8] = {};
#pragma unroll
  for (int ks = 0; ks < 16; ks++) {
    const bf16x8 afr = *(const bf16x8*)&Wv[(size_t)crow * kC + ks * 32 + g * 8];
#pragma unroll
    for (int nf = 0; nf < 8; nf++) {
      const bf16x8 bfr =
          *(const bf16x8*)&XT[((size_t)(b * kN + n0 + nf * 16 + lo4)) * kC +
                              ks * 32 + g * 8];
      acc[nf] = MFMA16(afr, bfr, acc[nf]);
    }
  }
  float bvv[4];
#pragma unroll
  for (int r = 0; r < 4; r++) bvv[r] = bv[c0 + w * 16 + 4 * g + r];
#pragma unroll
  for (int nf = 0; nf < 8; nf++)
#pragma unroll
    for (int r = 0; r < 4; r++)
      bnc[w][4 * g + r][nf * 16 + lo4] = (bf16)(acc[nf][r] + bvv[r]);
  const int rr = l >> 2, seg = (l & 3) * 32;
  const bf16x8 v0 = *(const bf16x8*)&bnc[w][rr][seg];
  const bf16x8 v1 = *(const bf16x8*)&bnc[w][rr][seg + 8];
  const bf16x8 v2 = *(const bf16x8*)&bnc[w][rr][seg + 16];
  const bf16x8 v3 = *(const bf16x8*)&bnc[w][rr][seg + 24];
  const int c = c0 + w * 16 + rr;
  const int nn = n0 + seg;  // multiple of 32
  const int nb2 = nn >> 6, ni0 = nn & 63;
  bf16* orow = &xv2[(((size_t)b * 32 + nb2) * kC + c) * 64 + ni0];
  *(bf16x8*)&orow[0] = v0;
  *(bf16x8*)&orow[8] = v1;
  *(bf16x8*)&orow[16] = v2;
  *(bf16x8*)&orow[24] = v3;
}

// ---------------- pass 1: U^T[m][n] = exp-factor, partial S[n] via atomics
__global__ __launch_bounds__(256) void k_sum(
    const bf16* __restrict__ qT, const bf16* __restrict__ kT,
    const int* __restrict__ mask, const float* __restrict__ cnt,
    bf16* __restrict__ UT, float* __restrict__ Ssum) {
  __shared__ __align__(16) bf16 kts[2][64][128];
  __shared__ int mss[2][64];
  const int blk = blockIdx.x;
  const int b = blk & 7, nb = (blk >> 3) & 31, mh2 = blk >> 8;
  const int m00 = mh2 * 1024;
  const int t_ = threadIdx.x, w = t_ >> 6, l = t_ & 63, lo4 = l & 15, g = l >> 4;
  const float invd = 1.0f / (cnt[b] + 1e-9f);
  const int n0 = nb * 64;
  bf16x8 aq[4];
#pragma unroll
  for (int ks = 0; ks < 4; ks++)
    aq[ks] = *(const bf16x8*)&qT[((size_t)(b * kN + n0 + w * 16 + lo4)) * kC4 +
                                 ks * 32 + g * 8];
  const int nq = n0 + w * 16 + g * 4;
  const int4 mi = *(const int4*)&mask[b * kN + nq];
  const int mn4[4] = {mi.x, mi.y, mi.z, mi.w};
  float rs4[4] = {0.0f, 0.0f, 0.0f, 0.0f};
  bf16x8 rg[4];
#pragma unroll
  for (int i = 0; i < 4; i++) {
    const int row = w * 16 + i * 4 + g;
    const int q = (l & 15) ^ (row & 7);
    rg[i] = *(const bf16x8*)&kT[((size_t)(b * kN + row)) * kC4 + q * 8];
  }
#pragma unroll
  for (int i = 0; i < 4; i++) {
    const int row = w * 16 + i * 4 + g;
    *(bf16x8*)&kts[0][row][(l & 15) * 8] = rg[i];
  }
  if (t_ < 16)
    *(int4*)&mss[0][t_ * 4] = *(const int4*)&mask[b * kN + m00 + t_ * 4];
  __syncthreads();
  for (int tt = 0; tt < 16; tt++) {
    const int buf = tt & 1;
    if (tt < 15) {
      const int m0 = m00 + (tt + 1) * 64;
#pragma unroll
      for (int i = 0; i < 4; i++) {
        const int row = w * 16 + i * 4 + g;
        const int q = (l & 15) ^ (row & 7);
        rg[i] = *(const bf16x8*)&kT[((size_t)(b * kN + m0 + row)) * kC4 + q * 8];
      }
    }
#pragma unroll
    for (int mf = 0; mf < 4; mf++) {
      f32x4 e = {};
#pragma unroll
      for (int ks = 0; ks < 4; ks++) {
        const bf16x8 bk =
            *(const bf16x8*)&kts[buf][mf * 16 + lo4]
                                 [((ks * 4 + g) ^ (lo4 & 7)) * 8];
        e = MFMA16(aq[ks], bk, e);
      }
      const int mmv = mss[buf][mf * 16 + lo4];
      bf16x4 pk;
#pragma unroll
      for (int r = 0; r < 4; r++) {
        const float u = mmv ? (mn4[r] ? __expf(e[r] * invd) : 1.0f) : 0.0f;
        pk[r] = (bf16)u;
        rs4[r] += (float)pk[r];
      }
      const int m = m00 + tt * 64 + mf * 16 + lo4;
      *(bf16x4*)&UT[((size_t)(b * kN + m)) * kN + nq] = pk;
    }
    if (tt < 15) {
#pragma unroll
      for (int i = 0; i < 4; i++) {
        const int row = w * 16 + i * 4 + g;
        *(bf16x8*)&kts[buf ^ 1][row][(l & 15) * 8] = rg[i];
      }
      if (t_ < 16)
        *(int4*)&mss[buf ^ 1][t_ * 4] =
            *(const int4*)&mask[b * kN + m00 + (tt + 1) * 64 + t_ * 4];
    }
    __syncthreads();
  }
#pragma unroll
  for (int r = 0; r < 4; r++) {
#pragma unroll
    for (int off = 1; off < 16; off <<= 1) rs4[r] += __shfl_xor(rs4[r], off);
  }
  if (lo4 == 0) {
#pragma unroll
    for (int r = 0; r < 4; r++) atomicAdd(&Ssum[b * kN + nq + r], rs4[r]);
  }
}

// NOTE: k_sum's kts prologue stages tile 0 of m00 -- but rows use kT[b*kN+row]
// (m00 offset missing would be a bug); m00=0 for blk<256. For mh2=1 the
// prologue must include m00. (Fixed below in launch: grid kept 512; prologue
// uses m00 explicitly.)

// ---------------- scale xv2 in place by 1/S[n]
__global__ __launch_bounds__(256) void k_scale(bf16* __restrict__ xv2,
                                               const float* __restrict__ Ssum) {
  const int blk = blockIdx.x;  // 512 = 8b x 64 parts
  const int b = blk & 7, part = blk >> 3;
  const size_t base = (size_t)b * (32 * kC * 64);
  for (int it = 0; it < 8; it++) {
    const int chunk = part * 2048 + it * 256 + threadIdx.x;
    const size_t e = (size_t)chunk * 8;
    const int n = ((int)(e >> 15)) * 64 + ((int)e & 63);
    bf16x8 v = *(bf16x8*)&xv2[base + e];
    const f32x4 s0 = *(const f32x4*)&Ssum[b * kN + n];
    const f32x4 s1 = *(const f32x4*)&Ssum[b * kN + n + 4];
    bf16x8 o;
#pragma unroll
    for (int j = 0; j < 4; j++) o[j] = (bf16)((float)v[j] / s0[j]);
#pragma unroll
    for (int j = 0; j < 4; j++) o[4 + j] = (bf16)((float)v[4 + j] / s1[j]);
    *(bf16x8*)&xv2[base + e] = o;
  }
}

// -------- pass 2 (m97-clone): x_r^T[m][c] = sum_n UT[m][n]*xv2'[c][n]
// 128m x 128c tile, BK=32, 4 waves (64x64 each), A+B dbuf in LDS (reg-staged,
// XOR-swizzled). grid 512 = 8b x (16mb x 4cb, cb inner for UT L2 reuse).
__global__ __launch_bounds__(256, 2) void k_attn2(
    const bf16* __restrict__ UT, const bf16* __restrict__ xv2,
    const float* __restrict__ x, bf16* __restrict__ hT) {
  __shared__ __align__(16) bf16 As[2][128][32];
  __shared__ __align__(16) bf16 Bs[2][128][32];
  const int blk = blockIdx.x;
  const int b = blk & 7, tile = blk >> 3;
  const int cb = tile & 3, mb = tile >> 2;
  const int m0 = mb * 128, c0 = cb * 128;
  const int t_ = threadIdx.x, w = t_ >> 6, l = t_ & 63, lo4 = l & 15, g = l >> 4;
  const int mh = w >> 1, ch = w & 1;
  const int rs = t_ >> 1, ps = t_ & 1;  // staging: row, 32B-halfline
  const bf16* gA = &UT[((size_t)(b * kN + m0 + rs)) * kN + ps * 16];
  f32x4 acc[4][4] = {};
  bf16x8 ra0, ra1, rb0, rb1;
  {
    ra0 = *(const bf16x8*)&gA[0];
    ra1 = *(const bf16x8*)&gA[8];
    const bf16* gB = &xv2[(((size_t)b * 32 + 0) * kC + c0 + rs) * 64 + ps * 16];
    rb0 = *(const bf16x8*)&gB[0];
    rb1 = *(const bf16x8*)&gB[8];
    *(bf16x8*)&As[0][rs][((2 * ps + 0) ^ (rs & 3)) * 8] = ra0;
    *(bf16x8*)&As[0][rs][((2 * ps + 1) ^ (rs & 3)) * 8] = ra1;
    *(bf16x8*)&Bs[0][rs][((2 * ps + 0) ^ (rs & 3)) * 8] = rb0;
    *(bf16x8*)&Bs[0][rs][((2 * ps + 1) ^ (rs & 3)) * 8] = rb1;
  }
  __syncthreads();
  for (int tt = 0; tt < 64; tt++) {
    const int buf = tt & 1;
    if (tt < 63) {
      const int n0 = (tt + 1) * 32;
      ra0 = *(const bf16x8*)&gA[n0];
      ra1 = *(const bf16x8*)&gA[n0 + 8];
      const bf16* gB = &xv2[(((size_t)b * 32 + (n0 >> 6)) * kC + c0 + rs) * 64 +
                            (n0 & 63) + ps * 16];
      rb0 = *(const bf16x8*)&gB[0];
      rb1 = *(const bf16x8*)&gB[8];
    }
    bf16x8 af[4], bfr[4];
#pragma unroll
    for (int mf = 0; mf < 4; mf++) {
      const int row = mh * 64 + mf * 16 + lo4;
      af[mf] = *(const bf16x8*)&As[buf][row][(g ^ (row & 3)) * 8];
    }
#pragma unroll
    for (int cf = 0; cf < 4; cf++) {
      const int row = ch * 64 + cf * 16 + lo4;
      bfr[cf] = *(const bf16x8*)&Bs[buf][row][(g ^ (row & 3)) * 8];
    }
#pragma unroll
    for (int mf = 0; mf < 4; mf++)
#pragma unroll
      for (int cf = 0; cf < 4; cf++)
        acc[mf][cf] = MFMA16(af[mf], bfr[cf], acc[mf][cf]);
    if (tt < 63) {
      *(bf16x8*)&As[buf ^ 1][rs][((2 * ps + 0) ^ (rs & 3)) * 8] = ra0;
      *(bf16x8*)&As[buf ^ 1][rs][((2 * ps + 1) ^ (rs & 3)) * 8] = ra1;
      *(bf16x8*)&Bs[buf ^ 1][rs][((2 * ps + 0) ^ (rs & 3)) * 8] = rb0;
      *(bf16x8*)&Bs[buf ^ 1][rs][((2 * ps + 1) ^ (rs & 3)) * 8] = rb1;
    }
    __syncthreads();
  }
  // epilogue: h = x - x_r; per-wave LDS transpose (alias As) -> hT[m][c]
  bf16* bncw = ((bf16*)As) + w * 16 * 72;  // [16][72] per wave
#pragma unroll
  for (int mf = 0; mf < 4; mf++) {
    const int mbase = m0 + mh * 64 + mf * 16;
    float hh[4][4];
#pragma unroll
    for (int cf = 0; cf < 4; cf++) {
      const int c = c0 + ch * 64 + cf * 16 + lo4;
      const f32x4 xval =
          *(const f32x4*)&x[((size_t)(b * kC + c)) * kN + mbase + g * 4];
#pragma unroll
      for (int r = 0; r < 4; r++) hh[cf][r] = xval[r] - acc[mf][cf][r];
    }
#pragma unroll
    for (int cf = 0; cf < 4; cf++)
#pragma unroll
      for (int r = 0; r < 4; r++)
        bncw[(4 * g + r) * 72 + cf * 16 + lo4] = (bf16)hh[cf][r];
    {
      const int rr = l >> 2, seg = (l & 3) * 16;
      const bf16x8 v0 = *(const bf16x8*)&bncw[rr * 72 + seg];
      const bf16x8 v1 = *(const bf16x8*)&bncw[rr * 72 + seg + 8];
      bf16* orow =
          &hT[((size_t)(b * kN + mbase + rr)) * kC + c0 + ch * 64 + seg];
      *(bf16x8*)&orow[0] = v0;
      *(bf16x8*)&orow[8] = v1;
    }
  }
}

// -------- final (m97-clone): D[n][c] = hT[n][k] wt[c][k]; BN+ReLU+residual.
// 128n x 128c tile, K=512, BK=32, 16 iters; direct f32x4 stores (no transpose).
__global__ __launch_bounds__(256, 2) void k_final(
    const bf16* __restrict__ hT, const bf16* __restrict__ wt_bf,
    const float* __restrict__ x, const float* __restrict__ bt,
    const float* __restrict__ beta, const float* __restrict__ rmean,
    const float* __restrict__ invg, float* __restrict__ out) {
  __shared__ __align__(16) bf16 As[2][128][32];
  __shared__ __align__(16) bf16 Bs[2][128][32];
  const int blk = blockIdx.x;  // 512 = 8b x (16nb x 4cb)
  const int b = blk & 7, tile = blk >> 3;
  const int cb = tile & 3, nb = tile >> 2;
  const int n0 = nb * 128, c0 = cb * 128;
  const int t_ = threadIdx.x, w = t_ >> 6, l = t_ & 63, lo4 = l & 15, g = l >> 4;
  const int mh = w >> 1, ch = w & 1;
  const int rs = t_ >> 1, ps = t_ & 1;
  const bf16* gA = &hT[((size_t)(b * kN + n0 + rs)) * kC + ps * 16];
  const bf16* gB = &wt_bf[(size_t)(c0 + rs) * kC + ps * 16];
  f32x4 acc[4][4] = {};
  bf16x8 ra0, ra1, rb0, rb1;
  {
    ra0 = *(const bf16x8*)&gA[0];
    ra1 = *(const bf16x8*)&gA[8];
    rb0 = *(const bf16x8*)&gB[0];
    rb1 = *(const bf16x8*)&gB[8];
    *(bf16x8*)&As[0][rs][((2 * ps + 0) ^ (rs & 3)) * 8] = ra0;
    *(bf16x8*)&As[0][rs][((2 * ps + 1) ^ (rs & 3)) * 8] = ra1;
    *(bf16x8*)&Bs[0][rs][((2 * ps + 0) ^ (rs & 3)) * 8] = rb0;
    *(bf16x8*)&Bs[0][rs][((2 * ps + 1) ^ (rs & 3)) * 8] = rb1;
  }
  __syncthreads();
  for (int tt = 0; tt < 16; tt++) {
    const int buf = tt & 1;
    if (tt < 15) {
      const int k0 = (tt + 1) * 32;
      ra0 = *(const bf16x8*)&gA[k0];
      ra1 = *(const bf16x8*)&gA[k0 + 8];
      rb0 = *(const bf16x8*)&gB[k0];
      rb1 = *(const bf16x8*)&gB[k0 + 8];
    }
    bf16x8 af[4], bfr[4];
#pragma unroll
    for (int nf = 0; nf < 4; nf++) {
      const int row = mh * 64 + nf * 16 + lo4;
      af[nf] = *(const bf16x8*)&As[buf][row][(g ^ (row & 3)) * 8];
    }
#pragma unroll
    for (int cf = 0; cf < 4; cf++) {
      const int row = ch * 64 + cf * 16 + lo4;
      bfr[cf] = *(const bf16x8*)&Bs[buf][row][(g ^ (row & 3)) * 8];
    }
#pragma unroll
    for (int nf = 0; nf < 4; nf++)
#pragma unroll
      for (int cf = 0; cf < 4; cf++)
        acc[nf][cf] = MFMA16(af[nf], bfr[cf], acc[nf][cf]);
    if (tt < 15) {
      *(bf16x8*)&As[buf ^ 1][rs][((2 * ps + 0) ^ (rs & 3)) * 8] = ra0;
      *(bf16x8*)&As[buf ^ 1][rs][((2 * ps + 1) ^ (rs & 3)) * 8] = ra1;
      *(bf16x8*)&Bs[buf ^ 1][rs][((2 * ps + 0) ^ (rs & 3)) * 8] = rb0;
      *(bf16x8*)&Bs[buf ^ 1][rs][((2 * ps + 1) ^ (rs & 3)) * 8] = rb1;
    }
    __syncthreads();
  }
  // epilogue: BN + ReLU + residual, direct stores (4 consecutive n per lane)
#pragma unroll
  for (int cf = 0; cf < 4; cf++) {
    const int c = c0 + ch * 64 + cf * 16 + lo4;
    const float btv = bt[c], rmv = rmean[c], igv = invg[c], bev = beta[c];
#pragma unroll
    for (int nf = 0; nf < 4; nf++) {
      const int nbase = n0 + mh * 64 + nf * 16 + g * 4;
      const size_t base = ((size_t)(b * kC + c)) * kN + nbase;
      const f32x4 xval = *(const f32x4*)&x[base];
      f32x4 o;
#pragma unroll
      for (int r = 0; r < 4; r++) {
        float v = (acc[nf][cf][r] + btv - rmv) * igv + bev;
        v = fmaxf(v, 0.0f);
        o[r] = xval[r] + v;
      }
      *(f32x4*)&out[base] = o;
    }
  }
}

extern "C" void kernel_launch(void* const* d_in, const int* in_sizes, int n_in,
                              void* d_out, int out_size, void* d_ws,
                              size_t ws_size, hipStream_t stream) {
  const float* x = (const float*)d_in[0];
  const float* query = (const float*)d_in[1];
  const int* mask = (const int*)d_in[2];
  const float* wqk = (const float*)d_in[3];
  const float* wv = (const float*)d_in[4];
  const float* bv = (const float*)d_in[5];
  const float* wt = (const float*)d_in[6];
  const float* bt = (const float*)d_in[7];
  const float* gamma = (const float*)d_in[8];
  const float* beta = (const float*)d_in[9];
  const float* rmean = (const float*)d_in[10];
  const float* rvar = (const float*)d_in[11];
  float* out = (float*)d_out;
  char* wsb = (char*)d_ws;

  const size_t MB = 1024 * 1024;
  bf16* UT = (bf16*)wsb;                          // 64 MB [b][m][n]
  bf16* trbuf = (bf16*)wsb;                       // 16 MB (overlaps UT; dead pre-k_sum)
  bf16* xv2 = (bf16*)(wsb + 64 * MB);             // 16 MB tiled
  bf16* hT = (bf16*)(wsb + 80 * MB);              // 8 MB [b][n][c]
  bf16* qT = (bf16*)(wsb + 88 * MB);              // 4 MB
  bf16* kT = (bf16*)(wsb + 92 * MB);              // 4 MB
  bf16* wqk_bf = (bf16*)(wsb + 96 * MB);          // 128 KB
  bf16* wv_bf = wqk_bf + 65536;                   // 512 KB
  bf16* wt_bf = wv_bf + 262144;                   // 512 KB
  float* invg = (float*)(wt_bf + 262144);         // 2 KB
  float* Ssum = invg + 512;                       // 64 KB
  float* cnt = Ssum + kB * kN;                    // 32 B

  k_prep<<<136, 256, 0, stream>>>(mask, wqk, wv, wt, gamma, rvar, cnt, wqk_bf,
                                  wv_bf, wt_bf, invg, Ssum);
  k_tr<<<dim3(kN / 64, kC / 32, kB), 256, 0, stream>>>(query, trbuf);
  k_projT<<<dim3(kN / 64, kB), 256, 0, stream>>>(trbuf, wqk_bf, qT);
  k_tr<<<dim3(kN / 64, kC / 32, kB), 256, 0, stream>>>(x, trbuf);
  k_projT<<<dim3(kN / 64, kB), 256, 0, stream>>>(trbuf, wqk_bf, kT);
  k_projV<<<dim3(kN / 128, kC / 64, kB), 256, 0, stream>>>(trbuf, wv_bf, bv,
                                                           xv2);
  k_sum<<<512, 256, 0, stream>>>(qT, kT, mask, cnt, UT, Ssum);
  k_scale<<<512, 256, 0, stream>>>(xv2, Ssum);
  k_attn2<<<512, 256, 0, stream>>>(UT, xv2, x, hT);
  k_final<<<512, 256, 0, stream>>>(hT, wt_bf, x, bt, beta, rmean, invg, out);
}

// Round 9
// 170.693 us; speedup vs baseline: 10.3265x; 1.4311x over previous
//
#include <hip/hip_runtime.h>
#include <math.h>

typedef __bf16 bf16;
typedef bf16 bf16x8 __attribute__((ext_vector_type(8)));
typedef bf16 bf16x4 __attribute__((ext_vector_type(4)));
typedef float f32x4 __attribute__((ext_vector_type(4)));

constexpr int kB = 8, kC = 512, kC4 = 128, kN = 2048;

#define MFMA16(a, b, c) __builtin_amdgcn_mfma_f32_16x16x32_bf16(a, b, c, 0, 0, 0)

// ---------------------------------------------------------------- prep
__global__ __launch_bounds__(256) void k_prep(
    const int* __restrict__ mask, const float* __restrict__ wqk,
    const float* __restrict__ wv, const float* __restrict__ wt,
    const float* __restrict__ gamma, const float* __restrict__ rvar,
    float* __restrict__ cnt, bf16* __restrict__ wqk_bf,
    bf16* __restrict__ wv_bf, bf16* __restrict__ wt_bf,
    float* __restrict__ invg, float* __restrict__ Ssum) {
  const int t = threadIdx.x;
  if (blockIdx.x < 8) {
    const int b = blockIdx.x;
    int s = 0;
    for (int i = t; i < kN; i += 256) s += mask[b * kN + i];
    __shared__ int red[256];
    red[t] = s;
    __syncthreads();
    for (int off = 128; off > 0; off >>= 1) {
      if (t < off) red[t] += red[t + off];
      __syncthreads();
    }
    if (t == 0) cnt[b] = (float)red[0];
    return;
  }
  const int total = 65536 + 262144 + 262144 + 512 + 16384;
  for (int i = (blockIdx.x - 8) * 256 + t; i < total; i += 128 * 256) {
    if (i < 65536) {
      wqk_bf[i] = (bf16)wqk[i];
    } else if (i < 327680) {
      wv_bf[i - 65536] = (bf16)wv[i - 65536];
    } else if (i < 589824) {
      wt_bf[i - 327680] = (bf16)wt[i - 327680];
    } else if (i < 590336) {
      const int j = i - 589824;
      invg[j] = gamma[j] * rsqrtf(rvar[j] + 1e-5f);
    } else {
      Ssum[i - 590336] = 0.0f;
    }
  }
}

// ---------------- transpose+convert both inputs: [C][N] f32 -> [N][C] bf16
__global__ __launch_bounds__(256) void k_tr2(const float* __restrict__ Q,
                                             const float* __restrict__ X,
                                             bf16* __restrict__ XTq,
                                             bf16* __restrict__ XTx) {
  __shared__ float tile[32][69];
  const int z = blockIdx.z, b = z & 7;
  const float* Xs = (z < 8) ? Q : X;
  bf16* XT = (z < 8) ? XTq : XTx;
  const int c0 = blockIdx.y * 32, n0 = blockIdx.x * 64;
  const int t = threadIdx.x;
  const int cc = t >> 4, n4 = (t & 15) * 4;
#pragma unroll
  for (int p = 0; p < 2; p++) {
    const int c = p * 16 + cc;
    const f32x4 v =
        *(const f32x4*)&Xs[((size_t)(b * kC + c0 + c)) * kN + n0 + n4];
    tile[c][n4 + 0] = v[0];
    tile[c][n4 + 1] = v[1];
    tile[c][n4 + 2] = v[2];
    tile[c][n4 + 3] = v[3];
  }
  __syncthreads();
  const int n = t >> 2, c8 = (t & 3) * 8;
  bf16x8 o;
#pragma unroll
  for (int j = 0; j < 8; j++) o[j] = (bf16)tile[c8 + j][n];
  *(bf16x8*)&XT[((size_t)(b * kN + n0 + n)) * kC + c0 + c8] = o;
}

// -------- q/k projections (staged GEMM): OT[b][n][128] = (wqk @ src)^T
// z selects src: 0 -> query -> qT, 1 -> x -> kT. 128n x 128d tile, BK=32.
__global__ __launch_bounds__(256, 2) void k_projQK(
    const bf16* __restrict__ XTq, const bf16* __restrict__ XTx,
    const bf16* __restrict__ W, bf16* __restrict__ qT, bf16* __restrict__ kT) {
  __shared__ __align__(16) bf16 As[2][128][32];
  __shared__ __align__(16) bf16 Bs[2][128][32];
  const int nb = blockIdx.x, b = blockIdx.y, src = blockIdx.z;
  const bf16* XT = src ? XTx : XTq;
  bf16* OT = src ? kT : qT;
  const int n0 = nb * 128;
  const int t_ = threadIdx.x, w = t_ >> 6, l = t_ & 63, lo4 = l & 15, g = l >> 4;
  const int mh = w >> 1, ch = w & 1;
  const int rs = t_ >> 1, ps = t_ & 1;
  const bf16* gA = &XT[((size_t)(b * kN + n0 + rs)) * kC + ps * 16];
  const bf16* gB = &W[(size_t)rs * kC + ps * 16];
  f32x4 acc[4][4] = {};
  bf16x8 ra0, ra1, rb0, rb1;
  {
    ra0 = *(const bf16x8*)&gA[0];
    ra1 = *(const bf16x8*)&gA[8];
    rb0 = *(const bf16x8*)&gB[0];
    rb1 = *(const bf16x8*)&gB[8];
    *(bf16x8*)&As[0][rs][((2 * ps + 0) ^ (rs & 3)) * 8] = ra0;
    *(bf16x8*)&As[0][rs][((2 * ps + 1) ^ (rs & 3)) * 8] = ra1;
    *(bf16x8*)&Bs[0][rs][((2 * ps + 0) ^ (rs & 3)) * 8] = rb0;
    *(bf16x8*)&Bs[0][rs][((2 * ps + 1) ^ (rs & 3)) * 8] = rb1;
  }
  __syncthreads();
  for (int tt = 0; tt < 16; tt++) {
    const int buf = tt & 1;
    if (tt < 15) {
      const int k0 = (tt + 1) * 32;
      ra0 = *(const bf16x8*)&gA[k0];
      ra1 = *(const bf16x8*)&gA[k0 + 8];
      rb0 = *(const bf16x8*)&gB[k0];
      rb1 = *(const bf16x8*)&gB[k0 + 8];
    }
    bf16x8 af[4], bfr[4];
#pragma unroll
    for (int nf = 0; nf < 4; nf++) {
      const int row = mh * 64 + nf * 16 + lo4;
      af[nf] = *(const bf16x8*)&As[buf][row][(g ^ (row & 3)) * 8];
    }
#pragma unroll
    for (int cf = 0; cf < 4; cf++) {
      const int row = ch * 64 + cf * 16 + lo4;
      bfr[cf] = *(const bf16x8*)&Bs[buf][row][(g ^ (row & 3)) * 8];
    }
#pragma unroll
    for (int nf = 0; nf < 4; nf++)
#pragma unroll
      for (int cf = 0; cf < 4; cf++)
        acc[nf][cf] = MFMA16(af[nf], bfr[cf], acc[nf][cf]);
    if (tt < 15) {
      *(bf16x8*)&As[buf ^ 1][rs][((2 * ps + 0) ^ (rs & 3)) * 8] = ra0;
      *(bf16x8*)&As[buf ^ 1][rs][((2 * ps + 1) ^ (rs & 3)) * 8] = ra1;
      *(bf16x8*)&Bs[buf ^ 1][rs][((2 * ps + 0) ^ (rs & 3)) * 8] = rb0;
      *(bf16x8*)&Bs[buf ^ 1][rs][((2 * ps + 1) ^ (rs & 3)) * 8] = rb1;
    }
    __syncthreads();
  }
  // epilogue: per-wave LDS transpose -> OT[n][d] (64 d contiguous per row)
  bf16* bncw = ((bf16*)As) + w * 16 * 72;
#pragma unroll
  for (int nf = 0; nf < 4; nf++) {
    const int nbase = n0 + mh * 64 + nf * 16;
#pragma unroll
    for (int cf = 0; cf < 4; cf++)
#pragma unroll
      for (int r = 0; r < 4; r++)
        bncw[(4 * g + r) * 72 + cf * 16 + lo4] = (bf16)acc[nf][cf][r];
    const int rr = l >> 2, seg = (l & 3) * 16;
    const bf16x8 v0 = *(const bf16x8*)&bncw[rr * 72 + seg];
    const bf16x8 v1 = *(const bf16x8*)&bncw[rr * 72 + seg + 8];
    bf16* orow = &OT[((size_t)(b * kN + nbase + rr)) * kC4 + ch * 64 + seg];
    *(bf16x8*)&orow[0] = v0;
    *(bf16x8*)&orow[8] = v1;
  }
}

// -------- value projection (staged GEMM) -> TILED xv2[b][n>>6][c][n&63]
// 128n x 128c tile, BK=32; A = XTx rows n, B = wv rows c; bias in epilogue.
__global__ __launch_bounds__(256, 2) void k_projV(
    const bf16* __restrict__ XTx, const bf16* __restrict__ Wv,
    const float* __restrict__ bv, bf16* __restrict__ xv2) {
  __shared__ __align__(16) bf16 As[2][128][32];
  __shared__ __align__(16) bf16 Bs[2][128][32];
  const int blk = blockIdx.x;  // 512 = 8b x (16nb x 4cb)
  const int b = blk & 7, tile = blk >> 3;
  const int cb = tile & 3, nb = tile >> 2;
  const int n0 = nb * 128, c0 = cb * 128;
  const int t_ = threadIdx.x, w = t_ >> 6, l = t_ & 63, lo4 = l & 15, g = l >> 4;
  const int mh = w >> 1, ch = w & 1;
  const int rs = t_ >> 1, ps = t_ & 1;
  const bf16* gA = &XTx[((size_t)(b * kN + n0 + rs)) * kC + ps * 16];
  const bf16* gB = &Wv[(size_t)(c0 + rs) * kC + ps * 16];
  f32x4 acc[4][4] = {};
  bf16x8 ra0, ra1, rb0, rb1;
  {
    ra0 = *(const bf16x8*)&gA[0];
    ra1 = *(const bf16x8*)&gA[8];
    rb0 = *(const bf16x8*)&gB[0];
    rb1 = *(const bf16x8*)&gB[8];
    *(bf16x8*)&As[0][rs][((2 * ps + 0) ^ (rs & 3)) * 8] = ra0;
    *(bf16x8*)&As[0][rs][((2 * ps + 1) ^ (rs & 3)) * 8] = ra1;
    *(bf16x8*)&Bs[0][rs][((2 * ps + 0) ^ (rs & 3)) * 8] = rb0;
    *(bf16x8*)&Bs[0][rs][((2 * ps + 1) ^ (rs & 3)) * 8] = rb1;
  }
  __syncthreads();
  for (int tt = 0; tt < 16; tt++) {
    const int buf = tt & 1;
    if (tt < 15) {
      const int k0 = (tt + 1) * 32;
      ra0 = *(const bf16x8*)&gA[k0];
      ra1 = *(const bf16x8*)&gA[k0 + 8];
      rb0 = *(const bf16x8*)&gB[k0];
      rb1 = *(const bf16x8*)&gB[k0 + 8];
    }
    bf16x8 af[4], bfr[4];
#pragma unroll
    for (int nf = 0; nf < 4; nf++) {
      const int row = mh * 64 + nf * 16 + lo4;
      af[nf] = *(const bf16x8*)&As[buf][row][(g ^ (row & 3)) * 8];
    }
#pragma unroll
    for (int cf = 0; cf < 4; cf++) {
      const int row = ch * 64 + cf * 16 + lo4;
      bfr[cf] = *(const bf16x8*)&Bs[buf][row][(g ^ (row & 3)) * 8];
    }
#pragma unroll
    for (int nf = 0; nf < 4; nf++)
#pragma unroll
      for (int cf = 0; cf < 4; cf++)
        acc[nf][cf] = MFMA16(af[nf], bfr[cf], acc[nf][cf]);
    if (tt < 15) {
      *(bf16x8*)&As[buf ^ 1][rs][((2 * ps + 0) ^ (rs & 3)) * 8] = ra0;
      *(bf16x8*)&As[buf ^ 1][rs][((2 * ps + 1) ^ (rs & 3)) * 8] = ra1;
      *(bf16x8*)&Bs[buf ^ 1][rs][((2 * ps + 0) ^ (rs & 3)) * 8] = rb0;
      *(bf16x8*)&Bs[buf ^ 1][rs][((2 * ps + 1) ^ (rs & 3)) * 8] = rb1;
    }
    __syncthreads();
  }
  // epilogue: + bias, packed bf16x4 stores into tiled layout
#pragma unroll
  for (int cf = 0; cf < 4; cf++) {
    const int c = c0 + ch * 64 + cf * 16 + lo4;
    const float bvv = bv[c];
#pragma unroll
    for (int nf = 0; nf < 4; nf++) {
      const int nbase = n0 + mh * 64 + nf * 16 + g * 4;
      bf16x4 o;
#pragma unroll
      for (int r = 0; r < 4; r++) o[r] = (bf16)(acc[nf][cf][r] + bvv);
      *(bf16x4*)&xv2[(((size_t)b * 32 + (nbase >> 6)) * kC + c) * 64 +
                     (nbase & 63)] = o;
    }
  }
}

// ---------------- pass 1: U^T[m][n] = exp-factor, partial S[n] via atomics
__global__ __launch_bounds__(256) void k_sum(
    const bf16* __restrict__ qT, const bf16* __restrict__ kT,
    const int* __restrict__ mask, const float* __restrict__ cnt,
    bf16* __restrict__ UT, float* __restrict__ Ssum) {
  __shared__ __align__(16) bf16 kts[2][64][128];
  __shared__ int mss[2][64];
  const int blk = blockIdx.x;
  const int b = blk & 7, nb = (blk >> 3) & 31, mh2 = blk >> 8;
  const int m00 = mh2 * 1024;
  const int t_ = threadIdx.x, w = t_ >> 6, l = t_ & 63, lo4 = l & 15, g = l >> 4;
  const float invd = 1.0f / (cnt[b] + 1e-9f);
  const int n0 = nb * 64;
  bf16x8 aq[4];
#pragma unroll
  for (int ks = 0; ks < 4; ks++)
    aq[ks] = *(const bf16x8*)&qT[((size_t)(b * kN + n0 + w * 16 + lo4)) * kC4 +
                                 ks * 32 + g * 8];
  const int nq = n0 + w * 16 + g * 4;
  const int4 mi = *(const int4*)&mask[b * kN + nq];
  const int mn4[4] = {mi.x, mi.y, mi.z, mi.w};
  float rs4[4] = {0.0f, 0.0f, 0.0f, 0.0f};
  bf16x8 rg[4];
#pragma unroll
  for (int i = 0; i < 4; i++) {
    const int row = w * 16 + i * 4 + g;
    const int q = (l & 15) ^ (row & 7);
    rg[i] = *(const bf16x8*)&kT[((size_t)(b * kN + m00 + row)) * kC4 + q * 8];
  }
#pragma unroll
  for (int i = 0; i < 4; i++) {
    const int row = w * 16 + i * 4 + g;
    *(bf16x8*)&kts[0][row][(l & 15) * 8] = rg[i];
  }
  if (t_ < 16)
    *(int4*)&mss[0][t_ * 4] = *(const int4*)&mask[b * kN + m00 + t_ * 4];
  __syncthreads();
  for (int tt = 0; tt < 16; tt++) {
    const int buf = tt & 1;
    if (tt < 15) {
      const int m0 = m00 + (tt + 1) * 64;
#pragma unroll
      for (int i = 0; i < 4; i++) {
        const int row = w * 16 + i * 4 + g;
        const int q = (l & 15) ^ (row & 7);
        rg[i] = *(const bf16x8*)&kT[((size_t)(b * kN + m0 + row)) * kC4 + q * 8];
      }
    }
#pragma unroll
    for (int mf = 0; mf < 4; mf++) {
      f32x4 e = {};
#pragma unroll
      for (int ks = 0; ks < 4; ks++) {
        const bf16x8 bk =
            *(const bf16x8*)&kts[buf][mf * 16 + lo4]
                                 [((ks * 4 + g) ^ (lo4 & 7)) * 8];
        e = MFMA16(aq[ks], bk, e);
      }
      const int mmv = mss[buf][mf * 16 + lo4];
      bf16x4 pk;
#pragma unroll
      for (int r = 0; r < 4; r++) {
        const float u = mmv ? (mn4[r] ? __expf(e[r] * invd) : 1.0f) : 0.0f;
        pk[r] = (bf16)u;
        rs4[r] += (float)pk[r];
      }
      const int m = m00 + tt * 64 + mf * 16 + lo4;
      *(bf16x4*)&UT[((size_t)(b * kN + m)) * kN + nq] = pk;
    }
    if (tt < 15) {
#pragma unroll
      for (int i = 0; i < 4; i++) {
        const int row = w * 16 + i * 4 + g;
        *(bf16x8*)&kts[buf ^ 1][row][(l & 15) * 8] = rg[i];
      }
      if (t_ < 16)
        *(int4*)&mss[buf ^ 1][t_ * 4] =
            *(const int4*)&mask[b * kN + m00 + (tt + 1) * 64 + t_ * 4];
    }
    __syncthreads();
  }
#pragma unroll
  for (int r = 0; r < 4; r++) {
#pragma unroll
    for (int off = 1; off < 16; off <<= 1) rs4[r] += __shfl_xor(rs4[r], off);
  }
  if (lo4 == 0) {
#pragma unroll
    for (int r = 0; r < 4; r++) atomicAdd(&Ssum[b * kN + nq + r], rs4[r]);
  }
}

// ---------------- scale xv2 in place by 1/S[n]
__global__ __launch_bounds__(256) void k_scale(bf16* __restrict__ xv2,
                                               const float* __restrict__ Ssum) {
  const int blk = blockIdx.x;  // 512 = 8b x 64 parts
  const int b = blk & 7, part = blk >> 3;
  const size_t base = (size_t)b * (32 * kC * 64);
  for (int it = 0; it < 8; it++) {
    const int chunk = part * 2048 + it * 256 + threadIdx.x;
    const size_t e = (size_t)chunk * 8;
    const int n = ((int)(e >> 15)) * 64 + ((int)e & 63);
    bf16x8 v = *(bf16x8*)&xv2[base + e];
    const f32x4 s0 = *(const f32x4*)&Ssum[b * kN + n];
    const f32x4 s1 = *(const f32x4*)&Ssum[b * kN + n + 4];
    bf16x8 o;
#pragma unroll
    for (int j = 0; j < 4; j++) o[j] = (bf16)((float)v[j] / s0[j]);
#pragma unroll
    for (int j = 0; j < 4; j++) o[4 + j] = (bf16)((float)v[4 + j] / s1[j]);
    *(bf16x8*)&xv2[base + e] = o;
  }
}

// -------- pass 2: x_r^T[m][c] = sum_n UT[m][n]*xv2'[c][n]; h = x - x_r
__global__ __launch_bounds__(256, 2) void k_attn2(
    const bf16* __restrict__ UT, const bf16* __restrict__ xv2,
    const float* __restrict__ x, bf16* __restrict__ hT) {
  __shared__ __align__(16) bf16 As[2][128][32];
  __shared__ __align__(16) bf16 Bs[2][128][32];
  const int blk = blockIdx.x;
  const int b = blk & 7, tile = blk >> 3;
  const int cb = tile & 3, mb = tile >> 2;
  const int m0 = mb * 128, c0 = cb * 128;
  const int t_ = threadIdx.x, w = t_ >> 6, l = t_ & 63, lo4 = l & 15, g = l >> 4;
  const int mh = w >> 1, ch = w & 1;
  const int rs = t_ >> 1, ps = t_ & 1;
  const bf16* gA = &UT[((size_t)(b * kN + m0 + rs)) * kN + ps * 16];
  f32x4 acc[4][4] = {};
  bf16x8 ra0, ra1, rb0, rb1;
  {
    ra0 = *(const bf16x8*)&gA[0];
    ra1 = *(const bf16x8*)&gA[8];
    const bf16* gB = &xv2[(((size_t)b * 32 + 0) * kC + c0 + rs) * 64 + ps * 16];
    rb0 = *(const bf16x8*)&gB[0];
    rb1 = *(const bf16x8*)&gB[8];
    *(bf16x8*)&As[0][rs][((2 * ps + 0) ^ (rs & 3)) * 8] = ra0;
    *(bf16x8*)&As[0][rs][((2 * ps + 1) ^ (rs & 3)) * 8] = ra1;
    *(bf16x8*)&Bs[0][rs][((2 * ps + 0) ^ (rs & 3)) * 8] = rb0;
    *(bf16x8*)&Bs[0][rs][((2 * ps + 1) ^ (rs & 3)) * 8] = rb1;
  }
  __syncthreads();
  for (int tt = 0; tt < 64; tt++) {
    const int buf = tt & 1;
    if (tt < 63) {
      const int n0 = (tt + 1) * 32;
      ra0 = *(const bf16x8*)&gA[n0];
      ra1 = *(const bf16x8*)&gA[n0 + 8];
      const bf16* gB = &xv2[(((size_t)b * 32 + (n0 >> 6)) * kC + c0 + rs) * 64 +
                            (n0 & 63) + ps * 16];
      rb0 = *(const bf16x8*)&gB[0];
      rb1 = *(const bf16x8*)&gB[8];
    }
    bf16x8 af[4], bfr[4];
#pragma unroll
    for (int mf = 0; mf < 4; mf++) {
      const int row = mh * 64 + mf * 16 + lo4;
      af[mf] = *(const bf16x8*)&As[buf][row][(g ^ (row & 3)) * 8];
    }
#pragma unroll
    for (int cf = 0; cf < 4; cf++) {
      const int row = ch * 64 + cf * 16 + lo4;
      bfr[cf] = *(const bf16x8*)&Bs[buf][row][(g ^ (row & 3)) * 8];
    }
#pragma unroll
    for (int mf = 0; mf < 4; mf++)
#pragma unroll
      for (int cf = 0; cf < 4; cf++)
        acc[mf][cf] = MFMA16(af[mf], bfr[cf], acc[mf][cf]);
    if (tt < 63) {
      *(bf16x8*)&As[buf ^ 1][rs][((2 * ps + 0) ^ (rs & 3)) * 8] = ra0;
      *(bf16x8*)&As[buf ^ 1][rs][((2 * ps + 1) ^ (rs & 3)) * 8] = ra1;
      *(bf16x8*)&Bs[buf ^ 1][rs][((2 * ps + 0) ^ (rs & 3)) * 8] = rb0;
      *(bf16x8*)&Bs[buf ^ 1][rs][((2 * ps + 1) ^ (rs & 3)) * 8] = rb1;
    }
    __syncthreads();
  }
  // epilogue: h = x - x_r; per-wave LDS transpose (alias As) -> hT[m][c]
  bf16* bncw = ((bf16*)As) + w * 16 * 72;
#pragma unroll
  for (int mf = 0; mf < 4; mf++) {
    const int mbase = m0 + mh * 64 + mf * 16;
    float hh[4][4];
#pragma unroll
    for (int cf = 0; cf < 4; cf++) {
      const int c = c0 + ch * 64 + cf * 16 + lo4;
      const f32x4 xval =
          *(const f32x4*)&x[((size_t)(b * kC + c)) * kN + mbase + g * 4];
#pragma unroll
      for (int r = 0; r < 4; r++) hh[cf][r] = xval[r] - acc[mf][cf][r];
    }
#pragma unroll
    for (int cf = 0; cf < 4; cf++)
#pragma unroll
      for (int r = 0; r < 4; r++)
        bncw[(4 * g + r) * 72 + cf * 16 + lo4] = (bf16)hh[cf][r];
    {
      const int rr = l >> 2, seg = (l & 3) * 16;
      const bf16x8 v0 = *(const bf16x8*)&bncw[rr * 72 + seg];
      const bf16x8 v1 = *(const bf16x8*)&bncw[rr * 72 + seg + 8];
      bf16* orow =
          &hT[((size_t)(b * kN + mbase + rr)) * kC + c0 + ch * 64 + seg];
      *(bf16x8*)&orow[0] = v0;
      *(bf16x8*)&orow[8] = v1;
    }
  }
}

// -------- final: D[n][c] = hT[n][k] wt[c][k]; BN+ReLU+residual
__global__ __launch_bounds__(256, 2) void k_final(
    const bf16* __restrict__ hT, const bf16* __restrict__ wt_bf,
    const float* __restrict__ x, const float* __restrict__ bt,
    const float* __restrict__ beta, const float* __restrict__ rmean,
    const float* __restrict__ invg, float* __restrict__ out) {
  __shared__ __align__(16) bf16 As[2][128][32];
  __shared__ __align__(16) bf16 Bs[2][128][32];
  const int blk = blockIdx.x;  // 512 = 8b x (16nb x 4cb)
  const int b = blk & 7, tile = blk >> 3;
  const int cb = tile & 3, nb = tile >> 2;
  const int n0 = nb * 128, c0 = cb * 128;
  const int t_ = threadIdx.x, w = t_ >> 6, l = t_ & 63, lo4 = l & 15, g = l >> 4;
  const int mh = w >> 1, ch = w & 1;
  const int rs = t_ >> 1, ps = t_ & 1;
  const bf16* gA = &hT[((size_t)(b * kN + n0 + rs)) * kC + ps * 16];
  const bf16* gB = &wt_bf[(size_t)(c0 + rs) * kC + ps * 16];
  f32x4 acc[4][4] = {};
  bf16x8 ra0, ra1, rb0, rb1;
  {
    ra0 = *(const bf16x8*)&gA[0];
    ra1 = *(const bf16x8*)&gA[8];
    rb0 = *(const bf16x8*)&gB[0];
    rb1 = *(const bf16x8*)&gB[8];
    *(bf16x8*)&As[0][rs][((2 * ps + 0) ^ (rs & 3)) * 8] = ra0;
    *(bf16x8*)&As[0][rs][((2 * ps + 1) ^ (rs & 3)) * 8] = ra1;
    *(bf16x8*)&Bs[0][rs][((2 * ps + 0) ^ (rs & 3)) * 8] = rb0;
    *(bf16x8*)&Bs[0][rs][((2 * ps + 1) ^ (rs & 3)) * 8] = rb1;
  }
  __syncthreads();
  for (int tt = 0; tt < 16; tt++) {
    const int buf = tt & 1;
    if (tt < 15) {
      const int k0 = (tt + 1) * 32;
      ra0 = *(const bf16x8*)&gA[k0];
      ra1 = *(const bf16x8*)&gA[k0 + 8];
      rb0 = *(const bf16x8*)&gB[k0];
      rb1 = *(const bf16x8*)&gB[k0 + 8];
    }
    bf16x8 af[4], bfr[4];
#pragma unroll
    for (int nf = 0; nf < 4; nf++) {
      const int row = mh * 64 + nf * 16 + lo4;
      af[nf] = *(const bf16x8*)&As[buf][row][(g ^ (row & 3)) * 8];
    }
#pragma unroll
    for (int cf = 0; cf < 4; cf++) {
      const int row = ch * 64 + cf * 16 + lo4;
      bfr[cf] = *(const bf16x8*)&Bs[buf][row][(g ^ (row & 3)) * 8];
    }
#pragma unroll
    for (int nf = 0; nf < 4; nf++)
#pragma unroll
      for (int cf = 0; cf < 4; cf++)
        acc[nf][cf] = MFMA16(af[nf], bfr[cf], acc[nf][cf]);
    if (tt < 15) {
      *(bf16x8*)&As[buf ^ 1][rs][((2 * ps + 0) ^ (rs & 3)) * 8] = ra0;
      *(bf16x8*)&As[buf ^ 1][rs][((2 * ps + 1) ^ (rs & 3)) * 8] = ra1;
      *(bf16x8*)&Bs[buf ^ 1][rs][((2 * ps + 0) ^ (rs & 3)) * 8] = rb0;
      *(bf16x8*)&Bs[buf ^ 1][rs][((2 * ps + 1) ^ (rs & 3)) * 8] = rb1;
    }
    __syncthreads();
  }
#pragma unroll
  for (int cf = 0; cf < 4; cf++) {
    const int c = c0 + ch * 64 + cf * 16 + lo4;
    const float btv = bt[c], rmv = rmean[c], igv = invg[c], bev = beta[c];
#pragma unroll
    for (int nf = 0; nf < 4; nf++) {
      const int nbase = n0 + mh * 64 + nf * 16 + g * 4;
      const size_t base = ((size_t)(b * kC + c)) * kN + nbase;
      const f32x4 xval = *(const f32x4*)&x[base];
      f32x4 o;
#pragma unroll
      for (int r = 0; r < 4; r++) {
        float v = (acc[nf][cf][r] + btv - rmv) * igv + bev;
        v = fmaxf(v, 0.0f);
        o[r] = xval[r] + v;
      }
      *(f32x4*)&out[base] = o;
    }
  }
}

extern "C" void kernel_launch(void* const* d_in, const int* in_sizes, int n_in,
                              void* d_out, int out_size, void* d_ws,
                              size_t ws_size, hipStream_t stream) {
  const float* x = (const float*)d_in[0];
  const float* query = (const float*)d_in[1];
  const int* mask = (const int*)d_in[2];
  const float* wqk = (const float*)d_in[3];
  const float* wv = (const float*)d_in[4];
  const float* bv = (const float*)d_in[5];
  const float* wt = (const float*)d_in[6];
  const float* bt = (const float*)d_in[7];
  const float* gamma = (const float*)d_in[8];
  const float* beta = (const float*)d_in[9];
  const float* rmean = (const float*)d_in[10];
  const float* rvar = (const float*)d_in[11];
  float* out = (float*)d_out;
  char* wsb = (char*)d_ws;

  const size_t MB = 1024 * 1024;
  bf16* UT = (bf16*)wsb;                        // 64 MB [b][m][n]
  bf16* trbufQ = (bf16*)wsb;                    // 16 MB (in UT dead zone)
  bf16* trbufX = (bf16*)(wsb + 16 * MB);        // 16 MB (in UT dead zone)
  bf16* xv2 = (bf16*)(wsb + 64 * MB);           // 16 MB tiled
  bf16* hT = (bf16*)(wsb + 80 * MB);            // 8 MB [b][n][c]
  bf16* qT = (bf16*)(wsb + 88 * MB);            // 4 MB
  bf16* kT = (bf16*)(wsb + 92 * MB);            // 4 MB
  bf16* wqk_bf = (bf16*)(wsb + 96 * MB);        // 128 KB
  bf16* wv_bf = wqk_bf + 65536;                 // 512 KB
  bf16* wt_bf = wv_bf + 262144;                 // 512 KB
  float* invg = (float*)(wt_bf + 262144);       // 2 KB
  float* Ssum = invg + 512;                     // 64 KB
  float* cnt = Ssum + kB * kN;                  // 32 B

  k_prep<<<136, 256, 0, stream>>>(mask, wqk, wv, wt, gamma, rvar, cnt, wqk_bf,
                                  wv_bf, wt_bf, invg, Ssum);
  k_tr2<<<dim3(kN / 64, kC / 32, 16), 256, 0, stream>>>(query, x, trbufQ,
                                                        trbufX);
  k_projQK<<<dim3(16, kB, 2), 256, 0, stream>>>(trbufQ, trbufX, wqk_bf, qT,
                                                kT);
  k_projV<<<512, 256, 0, stream>>>(trbufX, wv_bf, bv, xv2);
  k_sum<<<512, 256, 0, stream>>>(qT, kT, mask, cnt, UT, Ssum);
  k_scale<<<512, 256, 0, stream>>>(xv2, Ssum);
  k_attn2<<<512, 256, 0, stream>>>(UT, xv2, x, hT);
  k_final<<<512, 256, 0, stream>>>(hT, wt_bf, x, bt, beta, rmean, invg, out);
}

// Round 12
// 166.993 us; speedup vs baseline: 10.5553x; 1.0222x over previous
//
#include <hip/hip_runtime.h>
#include <math.h>

typedef __bf16 bf16;
typedef bf16 bf16x8 __attribute__((ext_vector_type(8)));
typedef bf16 bf16x4 __attribute__((ext_vector_type(4)));
typedef float f32x4 __attribute__((ext_vector_type(4)));

constexpr int kB = 8, kC = 512, kC4 = 128, kN = 2048;

#define MFMA16(a, b, c) __builtin_amdgcn_mfma_f32_16x16x32_bf16(a, b, c, 0, 0, 0)

__device__ __forceinline__ void gl_lds16(const bf16* g, bf16* l) {
  __builtin_amdgcn_global_load_lds(
      (const __attribute__((address_space(1))) unsigned int*)g,
      (__attribute__((address_space(3))) unsigned int*)l, 16, 0, 0);
}

// ---------------------------------------------------------------- prep
__global__ __launch_bounds__(256) void k_prep(
    const int* __restrict__ mask, const float* __restrict__ wqk,
    const float* __restrict__ wv, const float* __restrict__ wt,
    const float* __restrict__ gamma, const float* __restrict__ rvar,
    float* __restrict__ cnt, bf16* __restrict__ wqk_bf,
    bf16* __restrict__ wv_bf, bf16* __restrict__ wt_bf,
    float* __restrict__ invg, float* __restrict__ Ssum) {
  const int t = threadIdx.x;
  if (blockIdx.x < 8) {
    const int b = blockIdx.x;
    int s = 0;
    for (int i = t; i < kN; i += 256) s += mask[b * kN + i];
    __shared__ int red[256];
    red[t] = s;
    __syncthreads();
    for (int off = 128; off > 0; off >>= 1) {
      if (t < off) red[t] += red[t + off];
      __syncthreads();
    }
    if (t == 0) cnt[b] = (float)red[0];
    return;
  }
  const int total = 65536 + 262144 + 262144 + 512 + 16384;
  for (int i = (blockIdx.x - 8) * 256 + t; i < total; i += 128 * 256) {
    if (i < 65536) {
      wqk_bf[i] = (bf16)wqk[i];
    } else if (i < 327680) {
      wv_bf[i - 65536] = (bf16)wv[i - 65536];
    } else if (i < 589824) {
      wt_bf[i - 327680] = (bf16)wt[i - 327680];
    } else if (i < 590336) {
      const int j = i - 589824;
      invg[j] = gamma[j] * rsqrtf(rvar[j] + 1e-5f);
    } else {
      Ssum[i - 590336] = 0.0f;
    }
  }
}

// ---------------- transpose+convert both inputs: [C][N] f32 -> [N][C] bf16
__global__ __launch_bounds__(256) void k_tr2(const float* __restrict__ Q,
                                             const float* __restrict__ X,
                                             bf16* __restrict__ XTq,
                                             bf16* __restrict__ XTx) {
  __shared__ float tile[32][69];
  const int z = blockIdx.z, b = z & 7;
  const float* Xs = (z < 8) ? Q : X;
  bf16* XT = (z < 8) ? XTq : XTx;
  const int c0 = blockIdx.y * 32, n0 = blockIdx.x * 64;
  const int t = threadIdx.x;
  const int cc = t >> 4, n4 = (t & 15) * 4;
#pragma unroll
  for (int p = 0; p < 2; p++) {
    const int c = p * 16 + cc;
    const f32x4 v =
        *(const f32x4*)&Xs[((size_t)(b * kC + c0 + c)) * kN + n0 + n4];
    tile[c][n4 + 0] = v[0];
    tile[c][n4 + 1] = v[1];
    tile[c][n4 + 2] = v[2];
    tile[c][n4 + 3] = v[3];
  }
  __syncthreads();
  const int n = t >> 2, c8 = (t & 3) * 8;
  bf16x8 o;
#pragma unroll
  for (int j = 0; j < 8; j++) o[j] = (bf16)tile[c8 + j][n];
  *(bf16x8*)&XT[((size_t)(b * kN + n0 + n)) * kC + c0 + c8] = o;
}

// -------- q/k projections (staged GEMM): OT[b][n][128] = (wqk @ src)^T
__global__ __launch_bounds__(256, 2) void k_projQK(
    const bf16* __restrict__ XTq, const bf16* __restrict__ XTx,
    const bf16* __restrict__ W, bf16* __restrict__ qT, bf16* __restrict__ kT) {
  __shared__ __align__(16) bf16 As[2][128][32];
  __shared__ __align__(16) bf16 Bs[2][128][32];
  const int nb = blockIdx.x, b = blockIdx.y, src = blockIdx.z;
  const bf16* XT = src ? XTx : XTq;
  bf16* OT = src ? kT : qT;
  const int n0 = nb * 128;
  const int t_ = threadIdx.x, w = t_ >> 6, l = t_ & 63, lo4 = l & 15, g = l >> 4;
  const int mh = w >> 1, ch = w & 1;
  // staging: lane covers rows srow, srow+64; global chunk sch; swizzled pos
  const int srow = w * 16 + (l >> 2), sch = l & 3;
  const int spos = sch ^ ((l >> 3) & 3);
  const int rpos = g ^ ((lo4 >> 1) & 3);  // read pos (f(row)=(lo4>>1)&3)
  const bf16* gA0 = &XT[((size_t)(b * kN + n0 + srow)) * kC + sch * 8];
  const bf16* gA1 = gA0 + (size_t)64 * kC;
  const bf16* gB0 = &W[(size_t)srow * kC + sch * 8];
  const bf16* gB1 = gB0 + (size_t)64 * kC;
  f32x4 acc[4][4] = {};
  bf16x8 ra0, ra1, rb0, rb1;
  ra0 = *(const bf16x8*)&gA0[0];
  ra1 = *(const bf16x8*)&gA1[0];
  rb0 = *(const bf16x8*)&gB0[0];
  rb1 = *(const bf16x8*)&gB1[0];
  *(bf16x8*)&As[0][srow][spos * 8] = ra0;
  *(bf16x8*)&As[0][srow + 64][spos * 8] = ra1;
  *(bf16x8*)&Bs[0][srow][spos * 8] = rb0;
  *(bf16x8*)&Bs[0][srow + 64][spos * 8] = rb1;
  __syncthreads();
  for (int tt = 0; tt < 16; tt++) {
    const int buf = tt & 1;
    if (tt < 15) {
      const int k0 = (tt + 1) * 32;
      ra0 = *(const bf16x8*)&gA0[k0];
      ra1 = *(const bf16x8*)&gA1[k0];
      rb0 = *(const bf16x8*)&gB0[k0];
      rb1 = *(const bf16x8*)&gB1[k0];
    }
    bf16x8 af[4], bfr[4];
#pragma unroll
    for (int nf = 0; nf < 4; nf++)
      af[nf] = *(const bf16x8*)&As[buf][mh * 64 + nf * 16 + lo4][rpos * 8];
#pragma unroll
    for (int cf = 0; cf < 4; cf++)
      bfr[cf] = *(const bf16x8*)&Bs[buf][ch * 64 + cf * 16 + lo4][rpos * 8];
#pragma unroll
    for (int nf = 0; nf < 4; nf++)
#pragma unroll
      for (int cf = 0; cf < 4; cf++)
        acc[nf][cf] = MFMA16(af[nf], bfr[cf], acc[nf][cf]);
    if (tt < 15) {
      *(bf16x8*)&As[buf ^ 1][srow][spos * 8] = ra0;
      *(bf16x8*)&As[buf ^ 1][srow + 64][spos * 8] = ra1;
      *(bf16x8*)&Bs[buf ^ 1][srow][spos * 8] = rb0;
      *(bf16x8*)&Bs[buf ^ 1][srow + 64][spos * 8] = rb1;
    }
    __syncthreads();
  }
  // epilogue: per-wave LDS transpose -> OT[n][d]
  bf16* bncw = ((bf16*)As) + w * 16 * 72;
#pragma unroll
  for (int nf = 0; nf < 4; nf++) {
    const int nbase = n0 + mh * 64 + nf * 16;
#pragma unroll
    for (int cf = 0; cf < 4; cf++)
#pragma unroll
      for (int r = 0; r < 4; r++)
        bncw[(4 * g + r) * 72 + cf * 16 + lo4] = (bf16)acc[nf][cf][r];
    const int rr = l >> 2, seg = (l & 3) * 16;
    const bf16x8 v0 = *(const bf16x8*)&bncw[rr * 72 + seg];
    const bf16x8 v1 = *(const bf16x8*)&bncw[rr * 72 + seg + 8];
    bf16* orow = &OT[((size_t)(b * kN + nbase + rr)) * kC4 + ch * 64 + seg];
    *(bf16x8*)&orow[0] = v0;
    *(bf16x8*)&orow[8] = v1;
  }
}

// -------- value projection (staged GEMM) -> TILED xv2[b][n>>6][c][n&63]
__global__ __launch_bounds__(256, 2) void k_projV(
    const bf16* __restrict__ XTx, const bf16* __restrict__ Wv,
    const float* __restrict__ bv, bf16* __restrict__ xv2) {
  __shared__ __align__(16) bf16 As[2][128][32];
  __shared__ __align__(16) bf16 Bs[2][128][32];
  const int blk = blockIdx.x;  // 512 = 8b x (16nb x 4cb)
  const int b = blk & 7, tile = blk >> 3;
  const int cb = tile & 3, nb = tile >> 2;
  const int n0 = nb * 128, c0 = cb * 128;
  const int t_ = threadIdx.x, w = t_ >> 6, l = t_ & 63, lo4 = l & 15, g = l >> 4;
  const int mh = w >> 1, ch = w & 1;
  const int srow = w * 16 + (l >> 2), sch = l & 3;
  const int spos = sch ^ ((l >> 3) & 3);
  const int rpos = g ^ ((lo4 >> 1) & 3);
  const bf16* gA0 = &XTx[((size_t)(b * kN + n0 + srow)) * kC + sch * 8];
  const bf16* gA1 = gA0 + (size_t)64 * kC;
  const bf16* gB0 = &Wv[(size_t)(c0 + srow) * kC + sch * 8];
  const bf16* gB1 = gB0 + (size_t)64 * kC;
  f32x4 acc[4][4] = {};
  bf16x8 ra0, ra1, rb0, rb1;
  ra0 = *(const bf16x8*)&gA0[0];
  ra1 = *(const bf16x8*)&gA1[0];
  rb0 = *(const bf16x8*)&gB0[0];
  rb1 = *(const bf16x8*)&gB1[0];
  *(bf16x8*)&As[0][srow][spos * 8] = ra0;
  *(bf16x8*)&As[0][srow + 64][spos * 8] = ra1;
  *(bf16x8*)&Bs[0][srow][spos * 8] = rb0;
  *(bf16x8*)&Bs[0][srow + 64][spos * 8] = rb1;
  __syncthreads();
  for (int tt = 0; tt < 16; tt++) {
    const int buf = tt & 1;
    if (tt < 15) {
      const int k0 = (tt + 1) * 32;
      ra0 = *(const bf16x8*)&gA0[k0];
      ra1 = *(const bf16x8*)&gA1[k0];
      rb0 = *(const bf16x8*)&gB0[k0];
      rb1 = *(const bf16x8*)&gB1[k0];
    }
    bf16x8 af[4], bfr[4];
#pragma unroll
    for (int nf = 0; nf < 4; nf++)
      af[nf] = *(const bf16x8*)&As[buf][mh * 64 + nf * 16 + lo4][rpos * 8];
#pragma unroll
    for (int cf = 0; cf < 4; cf++)
      bfr[cf] = *(const bf16x8*)&Bs[buf][ch * 64 + cf * 16 + lo4][rpos * 8];
#pragma unroll
    for (int nf = 0; nf < 4; nf++)
#pragma unroll
      for (int cf = 0; cf < 4; cf++)
        acc[nf][cf] = MFMA16(af[nf], bfr[cf], acc[nf][cf]);
    if (tt < 15) {
      *(bf16x8*)&As[buf ^ 1][srow][spos * 8] = ra0;
      *(bf16x8*)&As[buf ^ 1][srow + 64][spos * 8] = ra1;
      *(bf16x8*)&Bs[buf ^ 1][srow][spos * 8] = rb0;
      *(bf16x8*)&Bs[buf ^ 1][srow + 64][spos * 8] = rb1;
    }
    __syncthreads();
  }
  // epilogue: + bias, packed bf16x4 stores into tiled layout
#pragma unroll
  for (int cf = 0; cf < 4; cf++) {
    const int c = c0 + ch * 64 + cf * 16 + lo4;
    const float bvv = bv[c];
#pragma unroll
    for (int nf = 0; nf < 4; nf++) {
      const int nbase = n0 + mh * 64 + nf * 16 + g * 4;
      bf16x4 o;
#pragma unroll
      for (int r = 0; r < 4; r++) o[r] = (bf16)(acc[nf][cf][r] + bvv);
      *(bf16x4*)&xv2[(((size_t)b * 32 + (nbase >> 6)) * kC + c) * 64 +
                     (nbase & 63)] = o;
    }
  }
}

// ---------------- pass 1: U^T[m][n] = exp-factor, partial S[n] via atomics
__global__ __launch_bounds__(256) void k_sum(
    const bf16* __restrict__ qT, const bf16* __restrict__ kT,
    const int* __restrict__ mask, const float* __restrict__ cnt,
    bf16* __restrict__ UT, float* __restrict__ Ssum) {
  __shared__ __align__(16) bf16 kts[2][64][128];
  __shared__ int mss[2][64];
  const int blk = blockIdx.x;
  const int b = blk & 7, nb = (blk >> 3) & 31, mh2 = blk >> 8;
  const int m00 = mh2 * 1024;
  const int t_ = threadIdx.x, w = t_ >> 6, l = t_ & 63, lo4 = l & 15, g = l >> 4;
  const float invd = 1.0f / (cnt[b] + 1e-9f);
  const int n0 = nb * 64;
  bf16x8 aq[4];
#pragma unroll
  for (int ks = 0; ks < 4; ks++)
    aq[ks] = *(const bf16x8*)&qT[((size_t)(b * kN + n0 + w * 16 + lo4)) * kC4 +
                                 ks * 32 + g * 8];
  const int nq = n0 + w * 16 + g * 4;
  const int4 mi = *(const int4*)&mask[b * kN + nq];
  const int mn4[4] = {mi.x, mi.y, mi.z, mi.w};
  float rs4[4] = {0.0f, 0.0f, 0.0f, 0.0f};
  bf16x8 rg[4];
#pragma unroll
  for (int i = 0; i < 4; i++) {
    const int row = w * 16 + i * 4 + g;
    const int q = (l & 15) ^ (row & 7);
    rg[i] = *(const bf16x8*)&kT[((size_t)(b * kN + m00 + row)) * kC4 + q * 8];
  }
#pragma unroll
  for (int i = 0; i < 4; i++) {
    const int row = w * 16 + i * 4 + g;
    *(bf16x8*)&kts[0][row][(l & 15) * 8] = rg[i];
  }
  if (t_ < 16)
    *(int4*)&mss[0][t_ * 4] = *(const int4*)&mask[b * kN + m00 + t_ * 4];
  __syncthreads();
  for (int tt = 0; tt < 16; tt++) {
    const int buf = tt & 1;
    if (tt < 15) {
      const int m0 = m00 + (tt + 1) * 64;
#pragma unroll
      for (int i = 0; i < 4; i++) {
        const int row = w * 16 + i * 4 + g;
        const int q = (l & 15) ^ (row & 7);
        rg[i] = *(const bf16x8*)&kT[((size_t)(b * kN + m0 + row)) * kC4 + q * 8];
      }
    }
#pragma unroll
    for (int mf = 0; mf < 4; mf++) {
      f32x4 e = {};
#pragma unroll
      for (int ks = 0; ks < 4; ks++) {
        const bf16x8 bk =
            *(const bf16x8*)&kts[buf][mf * 16 + lo4]
                                 [((ks * 4 + g) ^ (lo4 & 7)) * 8];
        e = MFMA16(aq[ks], bk, e);
      }
      const int mmv = mss[buf][mf * 16 + lo4];
      bf16x4 pk;
#pragma unroll
      for (int r = 0; r < 4; r++) {
        const float u = mmv ? (mn4[r] ? __expf(e[r] * invd) : 1.0f) : 0.0f;
        pk[r] = (bf16)u;
        rs4[r] += (float)pk[r];
      }
      const int m = m00 + tt * 64 + mf * 16 + lo4;
      *(bf16x4*)&UT[((size_t)(b * kN + m)) * kN + nq] = pk;
    }
    if (tt < 15) {
#pragma unroll
      for (int i = 0; i < 4; i++) {
        const int row = w * 16 + i * 4 + g;
        *(bf16x8*)&kts[buf ^ 1][row][(l & 15) * 8] = rg[i];
      }
      if (t_ < 16)
        *(int4*)&mss[buf ^ 1][t_ * 4] =
            *(const int4*)&mask[b * kN + m00 + (tt + 1) * 64 + t_ * 4];
    }
    __syncthreads();
  }
#pragma unroll
  for (int r = 0; r < 4; r++) {
#pragma unroll
    for (int off = 1; off < 16; off <<= 1) rs4[r] += __shfl_xor(rs4[r], off);
  }
  if (lo4 == 0) {
#pragma unroll
    for (int r = 0; r < 4; r++) atomicAdd(&Ssum[b * kN + nq + r], rs4[r]);
  }
}

// ---------------- scale xv2 in place by 1/S[n]
__global__ __launch_bounds__(256) void k_scale(bf16* __restrict__ xv2,
                                               const float* __restrict__ Ssum) {
  const int blk = blockIdx.x;  // 512 = 8b x 64 parts
  const int b = blk & 7, part = blk >> 3;
  const size_t base = (size_t)b * (32 * kC * 64);
  for (int it = 0; it < 8; it++) {
    const int chunk = part * 2048 + it * 256 + threadIdx.x;
    const size_t e = (size_t)chunk * 8;
    const int n = ((int)(e >> 15)) * 64 + ((int)e & 63);
    bf16x8 v = *(bf16x8*)&xv2[base + e];
    const f32x4 s0 = *(const f32x4*)&Ssum[b * kN + n];
    const f32x4 s1 = *(const f32x4*)&Ssum[b * kN + n + 4];
    bf16x8 o;
#pragma unroll
    for (int j = 0; j < 4; j++) o[j] = (bf16)((float)v[j] / s0[j]);
#pragma unroll
    for (int j = 0; j < 4; j++) o[4 + j] = (bf16)((float)v[4 + j] / s1[j]);
    *(bf16x8*)&xv2[base + e] = o;
  }
}

// -------- pass 2: x_r^T[m][c] = sum_n UT[m][n]*xv2'[c][n]; h = x - x_r
// global_load_lds staging (linear LDS, source pre-swizzled chunks).
__global__ __launch_bounds__(256, 2) void k_attn2(
    const bf16* __restrict__ UT, const bf16* __restrict__ xv2,
    const float* __restrict__ x, bf16* __restrict__ hT) {
  __shared__ __align__(16) bf16 As[2][128][32];
  __shared__ __align__(16) bf16 Bs[2][128][32];
  const int blk = blockIdx.x;
  const int b = blk & 7, tile = blk >> 3;
  const int cb = tile & 3, mb = tile >> 2;
  const int m0 = mb * 128, c0 = cb * 128;
  const int t_ = threadIdx.x, w = t_ >> 6, l = t_ & 63, lo4 = l & 15, g = l >> 4;
  const int mh = w >> 1, ch = w & 1;
  const int rpos = g ^ ((lo4 >> 1) & 3);
  // gl_lds: lane covers rows w*16+(l>>2) (+64j); fetches pre-swizzled chunk
  const int srow = w * 16 + (l >> 2);
  const int sch = (l & 3) ^ ((l >> 3) & 3);
  const bf16* gA0 = &UT[((size_t)(b * kN + m0 + srow)) * kN + sch * 8];
  const bf16* gA1 = gA0 + (size_t)64 * kN;
  const bf16* gB0 = &xv2[(((size_t)b * 32) * kC + c0 + srow) * 64 + sch * 8];
  const bf16* gB1 = gB0 + (size_t)64 * 64;
  f32x4 acc[4][4] = {};
  gl_lds16(gA0, &As[0][w * 16][0]);
  gl_lds16(gA1, &As[0][w * 16 + 64][0]);
  gl_lds16(gB0, &Bs[0][w * 16][0]);
  gl_lds16(gB1, &Bs[0][w * 16 + 64][0]);
  __syncthreads();
  for (int tt = 0; tt < 64; tt++) {
    const int buf = tt & 1;
    if (tt < 63) {
      const int n1 = tt + 1;
      const size_t boff = (size_t)(n1 >> 1) * (kC * 64) + (n1 & 1) * 32;
      gl_lds16(gA0 + n1 * 32, &As[buf ^ 1][w * 16][0]);
      gl_lds16(gA1 + n1 * 32, &As[buf ^ 1][w * 16 + 64][0]);
      gl_lds16(gB0 + boff, &Bs[buf ^ 1][w * 16][0]);
      gl_lds16(gB1 + boff, &Bs[buf ^ 1][w * 16 + 64][0]);
    }
    bf16x8 af[4], bfr[4];
#pragma unroll
    for (int mf = 0; mf < 4; mf++)
      af[mf] = *(const bf16x8*)&As[buf][mh * 64 + mf * 16 + lo4][rpos * 8];
#pragma unroll
    for (int cf = 0; cf < 4; cf++)
      bfr[cf] = *(const bf16x8*)&Bs[buf][ch * 64 + cf * 16 + lo4][rpos * 8];
#pragma unroll
    for (int mf = 0; mf < 4; mf++)
#pragma unroll
      for (int cf = 0; cf < 4; cf++)
        acc[mf][cf] = MFMA16(af[mf], bfr[cf], acc[mf][cf]);
    __syncthreads();
  }
  // epilogue: h = x - x_r; per-wave LDS transpose (alias As) -> hT[m][c]
  bf16* bncw = ((bf16*)As) + w * 16 * 72;
#pragma unroll
  for (int mf = 0; mf < 4; mf++) {
    const int mbase = m0 + mh * 64 + mf * 16;
    float hh[4][4];
#pragma unroll
    for (int cf = 0; cf < 4; cf++) {
      const int c = c0 + ch * 64 + cf * 16 + lo4;
      const f32x4 xval =
          *(const f32x4*)&x[((size_t)(b * kC + c)) * kN + mbase + g * 4];
#pragma unroll
      for (int r = 0; r < 4; r++) hh[cf][r] = xval[r] - acc[mf][cf][r];
    }
#pragma unroll
    for (int cf = 0; cf < 4; cf++)
#pragma unroll
      for (int r = 0; r < 4; r++)
        bncw[(4 * g + r) * 72 + cf * 16 + lo4] = (bf16)hh[cf][r];
    {
      const int rr = l >> 2, seg = (l & 3) * 16;
      const bf16x8 v0 = *(const bf16x8*)&bncw[rr * 72 + seg];
      const bf16x8 v1 = *(const bf16x8*)&bncw[rr * 72 + seg + 8];
      bf16* orow =
          &hT[((size_t)(b * kN + mbase + rr)) * kC + c0 + ch * 64 + seg];
      *(bf16x8*)&orow[0] = v0;
      *(bf16x8*)&orow[8] = v1;
    }
  }
}

// -------- final: D[n][c] = hT[n][k] wt[c][k]; BN+ReLU+residual
__global__ __launch_bounds__(256, 2) void k_final(
    const bf16* __restrict__ hT, const bf16* __restrict__ wt_bf,
    const float* __restrict__ x, const float* __restrict__ bt,
    const float* __restrict__ beta, const float* __restrict__ rmean,
    const float* __restrict__ invg, float* __restrict__ out) {
  __shared__ __align__(16) bf16 As[2][128][32];
  __shared__ __align__(16) bf16 Bs[2][128][32];
  const int blk = blockIdx.x;  // 512 = 8b x (16nb x 4cb)
  const int b = blk & 7, tile = blk >> 3;
  const int cb = tile & 3, nb = tile >> 2;
  const int n0 = nb * 128, c0 = cb * 128;
  const int t_ = threadIdx.x, w = t_ >> 6, l = t_ & 63, lo4 = l & 15, g = l >> 4;
  const int mh = w >> 1, ch = w & 1;
  const int srow = w * 16 + (l >> 2), sch = l & 3;
  const int spos = sch ^ ((l >> 3) & 3);
  const int rpos = g ^ ((lo4 >> 1) & 3);
  const bf16* gA0 = &hT[((size_t)(b * kN + n0 + srow)) * kC + sch * 8];
  const bf16* gA1 = gA0 + (size_t)64 * kC;
  const bf16* gB0 = &wt_bf[(size_t)(c0 + srow) * kC + sch * 8];
  const bf16* gB1 = gB0 + (size_t)64 * kC;
  f32x4 acc[4][4] = {};
  bf16x8 ra0, ra1, rb0, rb1;
  ra0 = *(const bf16x8*)&gA0[0];
  ra1 = *(const bf16x8*)&gA1[0];
  rb0 = *(const bf16x8*)&gB0[0];
  rb1 = *(const bf16x8*)&gB1[0];
  *(bf16x8*)&As[0][srow][spos * 8] = ra0;
  *(bf16x8*)&As[0][srow + 64][spos * 8] = ra1;
  *(bf16x8*)&Bs[0][srow][spos * 8] = rb0;
  *(bf16x8*)&Bs[0][srow + 64][spos * 8] = rb1;
  __syncthreads();
  for (int tt = 0; tt < 16; tt++) {
    const int buf = tt & 1;
    if (tt < 15) {
      const int k0 = (tt + 1) * 32;
      ra0 = *(const bf16x8*)&gA0[k0];
      ra1 = *(const bf16x8*)&gA1[k0];
      rb0 = *(const bf16x8*)&gB0[k0];
      rb1 = *(const bf16x8*)&gB1[k0];
    }
    bf16x8 af[4], bfr[4];
#pragma unroll
    for (int nf = 0; nf < 4; nf++)
      af[nf] = *(const bf16x8*)&As[buf][mh * 64 + nf * 16 + lo4][rpos * 8];
#pragma unroll
    for (int cf = 0; cf < 4; cf++)
      bfr[cf] = *(const bf16x8*)&Bs[buf][ch * 64 + cf * 16 + lo4][rpos * 8];
#pragma unroll
    for (int nf = 0; nf < 4; nf++)
#pragma unroll
      for (int cf = 0; cf < 4; cf++)
        acc[nf][cf] = MFMA16(af[nf], bfr[cf], acc[nf][cf]);
    if (tt < 15) {
      *(bf16x8*)&As[buf ^ 1][srow][spos * 8] = ra0;
      *(bf16x8*)&As[buf ^ 1][srow + 64][spos * 8] = ra1;
      *(bf16x8*)&Bs[buf ^ 1][srow][spos * 8] = rb0;
      *(bf16x8*)&Bs[buf ^ 1][srow + 64][spos * 8] = rb1;
    }
    __syncthreads();
  }
#pragma unroll
  for (int cf = 0; cf < 4; cf++) {
    const int c = c0 + ch * 64 + cf * 16 + lo4;
    const float btv = bt[c], rmv = rmean[c], igv = invg[c], bev = beta[c];
#pragma unroll
    for (int nf = 0; nf < 4; nf++) {
      const int nbase = n0 + mh * 64 + nf * 16 + g * 4;
      const size_t base = ((size_t)(b * kC + c)) * kN + nbase;
      const f32x4 xval = *(const f32x4*)&x[base];
      f32x4 o;
#pragma unroll
      for (int r = 0; r < 4; r++) {
        float v = (acc[nf][cf][r] + btv - rmv) * igv + bev;
        v = fmaxf(v, 0.0f);
        o[r] = xval[r] + v;
      }
      *(f32x4*)&out[base] = o;
    }
  }
}

extern "C" void kernel_launch(void* const* d_in, const int* in_sizes, int n_in,
                              void* d_out, int out_size, void* d_ws,
                              size_t ws_size, hipStream_t stream) {
  const float* x = (const float*)d_in[0];
  const float* query = (const float*)d_in[1];
  const int* mask = (const int*)d_in[2];
  const float* wqk = (const float*)d_in[3];
  const float* wv = (const float*)d_in[4];
  const float* bv = (const float*)d_in[5];
  const float* wt = (const float*)d_in[6];
  const float* bt = (const float*)d_in[7];
  const float* gamma = (const float*)d_in[8];
  const float* beta = (const float*)d_in[9];
  const float* rmean = (const float*)d_in[10];
  const float* rvar = (const float*)d_in[11];
  float* out = (float*)d_out;
  char* wsb = (char*)d_ws;

  const size_t MB = 1024 * 1024;
  bf16* UT = (bf16*)wsb;                        // 64 MB [b][m][n]
  bf16* trbufQ = (bf16*)wsb;                    // 16 MB (in UT dead zone)
  bf16* trbufX = (bf16*)(wsb + 16 * MB);        // 16 MB (in UT dead zone)
  bf16* xv2 = (bf16*)(wsb + 64 * MB);           // 16 MB tiled
  bf16* hT = (bf16*)(wsb + 80 * MB);            // 8 MB [b][n][c]
  bf16* qT = (bf16*)(wsb + 88 * MB);            // 4 MB
  bf16* kT = (bf16*)(wsb + 92 * MB);            // 4 MB
  bf16* wqk_bf = (bf16*)(wsb + 96 * MB);        // 128 KB
  bf16* wv_bf = wqk_bf + 65536;                 // 512 KB
  bf16* wt_bf = wv_bf + 262144;                 // 512 KB
  float* invg = (float*)(wt_bf + 262144);       // 2 KB
  float* Ssum = invg + 512;                     // 64 KB
  float* cnt = Ssum + kB * kN;                  // 32 B

  k_prep<<<136, 256, 0, stream>>>(mask, wqk, wv, wt, gamma, rvar, cnt, wqk_bf,
                                  wv_bf, wt_bf, invg, Ssum);
  k_tr2<<<dim3(kN / 64, kC / 32, 16), 256, 0, stream>>>(query, x, trbufQ,
                                                        trbufX);
  k_projQK<<<dim3(16, kB, 2), 256, 0, stream>>>(trbufQ, trbufX, wqk_bf, qT,
                                                kT);
  k_projV<<<512, 256, 0, stream>>>(trbufX, wv_bf, bv, xv2);
  k_sum<<<512, 256, 0, stream>>>(qT, kT, mask, cnt, UT, Ssum);
  k_scale<<<512, 256, 0, stream>>>(xv2, Ssum);
  k_attn2<<<512, 256, 0, stream>>>(UT, xv2, x, hT);
  k_final<<<512, 256, 0, stream>>>(hT, wt_bf, x, bt, beta, rmean, invg, out);
}

// Round 13
// 162.641 us; speedup vs baseline: 10.8377x; 1.0268x over previous
//
#include <hip/hip_runtime.h>
#include <math.h>

typedef __bf16 bf16;
typedef bf16 bf16x8 __attribute__((ext_vector_type(8)));
typedef bf16 bf16x4 __attribute__((ext_vector_type(4)));
typedef float f32x4 __attribute__((ext_vector_type(4)));

constexpr int kB = 8, kC = 512, kC4 = 128, kN = 2048;

#define MFMA16(a, b, c) __builtin_amdgcn_mfma_f32_16x16x32_bf16(a, b, c, 0, 0, 0)

// ---------------------------------------------------------------- prep
__global__ __launch_bounds__(256) void k_prep(
    const int* __restrict__ mask, const float* __restrict__ wqk,
    const float* __restrict__ wv, const float* __restrict__ wt,
    const float* __restrict__ gamma, const float* __restrict__ rvar,
    float* __restrict__ cnt, bf16* __restrict__ wqk_bf,
    bf16* __restrict__ wv_bf, bf16* __restrict__ wt_bf,
    float* __restrict__ invg, float* __restrict__ Ssum) {
  const int t = threadIdx.x;
  if (blockIdx.x < 8) {
    const int b = blockIdx.x;
    int s = 0;
    for (int i = t; i < kN; i += 256) s += mask[b * kN + i];
    __shared__ int red[256];
    red[t] = s;
    __syncthreads();
    for (int off = 128; off > 0; off >>= 1) {
      if (t < off) red[t] += red[t + off];
      __syncthreads();
    }
    if (t == 0) cnt[b] = (float)red[0];
    return;
  }
  const int total = 65536 + 262144 + 262144 + 512 + 16384;
  for (int i = (blockIdx.x - 8) * 256 + t; i < total; i += 128 * 256) {
    if (i < 65536) {
      wqk_bf[i] = (bf16)wqk[i];
    } else if (i < 327680) {
      wv_bf[i - 65536] = (bf16)wv[i - 65536];
    } else if (i < 589824) {
      wt_bf[i - 327680] = (bf16)wt[i - 327680];
    } else if (i < 590336) {
      const int j = i - 589824;
      invg[j] = gamma[j] * rsqrtf(rvar[j] + 1e-5f);
    } else {
      Ssum[i - 590336] = 0.0f;
    }
  }
}

// ---------------- transpose+convert both inputs: [C][N] f32 -> [N][C] bf16
__global__ __launch_bounds__(256) void k_tr2(const float* __restrict__ Q,
                                             const float* __restrict__ X,
                                             bf16* __restrict__ XTq,
                                             bf16* __restrict__ XTx) {
  __shared__ float tile[32][69];
  const int z = blockIdx.z, b = z & 7;
  const float* Xs = (z < 8) ? Q : X;
  bf16* XT = (z < 8) ? XTq : XTx;
  const int c0 = blockIdx.y * 32, n0 = blockIdx.x * 64;
  const int t = threadIdx.x;
  const int cc = t >> 4, n4 = (t & 15) * 4;
#pragma unroll
  for (int p = 0; p < 2; p++) {
    const int c = p * 16 + cc;
    const f32x4 v =
        *(const f32x4*)&Xs[((size_t)(b * kC + c0 + c)) * kN + n0 + n4];
    tile[c][n4 + 0] = v[0];
    tile[c][n4 + 1] = v[1];
    tile[c][n4 + 2] = v[2];
    tile[c][n4 + 3] = v[3];
  }
  __syncthreads();
  const int n = t >> 2, c8 = (t & 3) * 8;
  bf16x8 o;
#pragma unroll
  for (int j = 0; j < 8; j++) o[j] = (bf16)tile[c8 + j][n];
  *(bf16x8*)&XT[((size_t)(b * kN + n0 + n)) * kC + c0 + c8] = o;
}

// -------- q/k projections (staged GEMM): OT[b][n][128] = (wqk @ src)^T
__global__ __launch_bounds__(256, 2) void k_projQK(
    const bf16* __restrict__ XTq, const bf16* __restrict__ XTx,
    const bf16* __restrict__ W, bf16* __restrict__ qT, bf16* __restrict__ kT) {
  __shared__ __align__(16) bf16 As[2][128][32];
  __shared__ __align__(16) bf16 Bs[2][128][32];
  const int nb = blockIdx.x, b = blockIdx.y, src = blockIdx.z;
  const bf16* XT = src ? XTx : XTq;
  bf16* OT = src ? kT : qT;
  const int n0 = nb * 128;
  const int t_ = threadIdx.x, w = t_ >> 6, l = t_ & 63, lo4 = l & 15, g = l >> 4;
  const int mh = w >> 1, ch = w & 1;
  // staging: lane covers rows srow, srow+64; global chunk sch; swizzled pos
  const int srow = w * 16 + (l >> 2), sch = l & 3;
  const int spos = sch ^ ((l >> 3) & 3);
  const int rpos = g ^ ((lo4 >> 1) & 3);  // read pos (f(row)=(lo4>>1)&3)
  const bf16* gA0 = &XT[((size_t)(b * kN + n0 + srow)) * kC + sch * 8];
  const bf16* gA1 = gA0 + (size_t)64 * kC;
  const bf16* gB0 = &W[(size_t)srow * kC + sch * 8];
  const bf16* gB1 = gB0 + (size_t)64 * kC;
  f32x4 acc[4][4] = {};
  bf16x8 ra0, ra1, rb0, rb1;
  ra0 = *(const bf16x8*)&gA0[0];
  ra1 = *(const bf16x8*)&gA1[0];
  rb0 = *(const bf16x8*)&gB0[0];
  rb1 = *(const bf16x8*)&gB1[0];
  *(bf16x8*)&As[0][srow][spos * 8] = ra0;
  *(bf16x8*)&As[0][srow + 64][spos * 8] = ra1;
  *(bf16x8*)&Bs[0][srow][spos * 8] = rb0;
  *(bf16x8*)&Bs[0][srow + 64][spos * 8] = rb1;
  __syncthreads();
  for (int tt = 0; tt < 16; tt++) {
    const int buf = tt & 1;
    if (tt < 15) {
      const int k0 = (tt + 1) * 32;
      ra0 = *(const bf16x8*)&gA0[k0];
      ra1 = *(const bf16x8*)&gA1[k0];
      rb0 = *(const bf16x8*)&gB0[k0];
      rb1 = *(const bf16x8*)&gB1[k0];
    }
    bf16x8 af[4], bfr[4];
#pragma unroll
    for (int nf = 0; nf < 4; nf++)
      af[nf] = *(const bf16x8*)&As[buf][mh * 64 + nf * 16 + lo4][rpos * 8];
#pragma unroll
    for (int cf = 0; cf < 4; cf++)
      bfr[cf] = *(const bf16x8*)&Bs[buf][ch * 64 + cf * 16 + lo4][rpos * 8];
#pragma unroll
    for (int nf = 0; nf < 4; nf++)
#pragma unroll
      for (int cf = 0; cf < 4; cf++)
        acc[nf][cf] = MFMA16(af[nf], bfr[cf], acc[nf][cf]);
    if (tt < 15) {
      *(bf16x8*)&As[buf ^ 1][srow][spos * 8] = ra0;
      *(bf16x8*)&As[buf ^ 1][srow + 64][spos * 8] = ra1;
      *(bf16x8*)&Bs[buf ^ 1][srow][spos * 8] = rb0;
      *(bf16x8*)&Bs[buf ^ 1][srow + 64][spos * 8] = rb1;
    }
    __syncthreads();
  }
  // epilogue: per-wave LDS transpose -> OT[n][d]
  bf16* bncw = ((bf16*)As) + w * 16 * 72;
#pragma unroll
  for (int nf = 0; nf < 4; nf++) {
    const int nbase = n0 + mh * 64 + nf * 16;
#pragma unroll
    for (int cf = 0; cf < 4; cf++)
#pragma unroll
      for (int r = 0; r < 4; r++)
        bncw[(4 * g + r) * 72 + cf * 16 + lo4] = (bf16)acc[nf][cf][r];
    const int rr = l >> 2, seg = (l & 3) * 16;
    const bf16x8 v0 = *(const bf16x8*)&bncw[rr * 72 + seg];
    const bf16x8 v1 = *(const bf16x8*)&bncw[rr * 72 + seg + 8];
    bf16* orow = &OT[((size_t)(b * kN + nbase + rr)) * kC4 + ch * 64 + seg];
    *(bf16x8*)&orow[0] = v0;
    *(bf16x8*)&orow[8] = v1;
  }
}

// -------- value projection (staged GEMM) -> TILED xv2[b][n>>6][c][n&63]
__global__ __launch_bounds__(256, 2) void k_projV(
    const bf16* __restrict__ XTx, const bf16* __restrict__ Wv,
    const float* __restrict__ bv, bf16* __restrict__ xv2) {
  __shared__ __align__(16) bf16 As[2][128][32];
  __shared__ __align__(16) bf16 Bs[2][128][32];
  const int blk = blockIdx.x;  // 512 = 8b x (16nb x 4cb)
  const int b = blk & 7, tile = blk >> 3;
  const int cb = tile & 3, nb = tile >> 2;
  const int n0 = nb * 128, c0 = cb * 128;
  const int t_ = threadIdx.x, w = t_ >> 6, l = t_ & 63, lo4 = l & 15, g = l >> 4;
  const int mh = w >> 1, ch = w & 1;
  const int srow = w * 16 + (l >> 2), sch = l & 3;
  const int spos = sch ^ ((l >> 3) & 3);
  const int rpos = g ^ ((lo4 >> 1) & 3);
  const bf16* gA0 = &XTx[((size_t)(b * kN + n0 + srow)) * kC + sch * 8];
  const bf16* gA1 = gA0 + (size_t)64 * kC;
  const bf16* gB0 = &Wv[(size_t)(c0 + srow) * kC + sch * 8];
  const bf16* gB1 = gB0 + (size_t)64 * kC;
  f32x4 acc[4][4] = {};
  bf16x8 ra0, ra1, rb0, rb1;
  ra0 = *(const bf16x8*)&gA0[0];
  ra1 = *(const bf16x8*)&gA1[0];
  rb0 = *(const bf16x8*)&gB0[0];
  rb1 = *(const bf16x8*)&gB1[0];
  *(bf16x8*)&As[0][srow][spos * 8] = ra0;
  *(bf16x8*)&As[0][srow + 64][spos * 8] = ra1;
  *(bf16x8*)&Bs[0][srow][spos * 8] = rb0;
  *(bf16x8*)&Bs[0][srow + 64][spos * 8] = rb1;
  __syncthreads();
  for (int tt = 0; tt < 16; tt++) {
    const int buf = tt & 1;
    if (tt < 15) {
      const int k0 = (tt + 1) * 32;
      ra0 = *(const bf16x8*)&gA0[k0];
      ra1 = *(const bf16x8*)&gA1[k0];
      rb0 = *(const bf16x8*)&gB0[k0];
      rb1 = *(const bf16x8*)&gB1[k0];
    }
    bf16x8 af[4], bfr[4];
#pragma unroll
    for (int nf = 0; nf < 4; nf++)
      af[nf] = *(const bf16x8*)&As[buf][mh * 64 + nf * 16 + lo4][rpos * 8];
#pragma unroll
    for (int cf = 0; cf < 4; cf++)
      bfr[cf] = *(const bf16x8*)&Bs[buf][ch * 64 + cf * 16 + lo4][rpos * 8];
#pragma unroll
    for (int nf = 0; nf < 4; nf++)
#pragma unroll
      for (int cf = 0; cf < 4; cf++)
        acc[nf][cf] = MFMA16(af[nf], bfr[cf], acc[nf][cf]);
    if (tt < 15) {
      *(bf16x8*)&As[buf ^ 1][srow][spos * 8] = ra0;
      *(bf16x8*)&As[buf ^ 1][srow + 64][spos * 8] = ra1;
      *(bf16x8*)&Bs[buf ^ 1][srow][spos * 8] = rb0;
      *(bf16x8*)&Bs[buf ^ 1][srow + 64][spos * 8] = rb1;
    }
    __syncthreads();
  }
  // epilogue: + bias, packed bf16x4 stores into tiled layout
#pragma unroll
  for (int cf = 0; cf < 4; cf++) {
    const int c = c0 + ch * 64 + cf * 16 + lo4;
    const float bvv = bv[c];
#pragma unroll
    for (int nf = 0; nf < 4; nf++) {
      const int nbase = n0 + mh * 64 + nf * 16 + g * 4;
      bf16x4 o;
#pragma unroll
      for (int r = 0; r < 4; r++) o[r] = (bf16)(acc[nf][cf][r] + bvv);
      *(bf16x4*)&xv2[(((size_t)b * 32 + (nbase >> 6)) * kC + c) * 64 +
                     (nbase & 63)] = o;
    }
  }
}

// ---------------- pass 1: U^T[m][n] = exp-factor, partial S[n] via atomics
__global__ __launch_bounds__(256) void k_sum(
    const bf16* __restrict__ qT, const bf16* __restrict__ kT,
    const int* __restrict__ mask, const float* __restrict__ cnt,
    bf16* __restrict__ UT, float* __restrict__ Ssum) {
  __shared__ __align__(16) bf16 kts[2][64][128];
  __shared__ int mss[2][64];
  const int blk = blockIdx.x;
  const int b = blk & 7, nb = (blk >> 3) & 31, mh2 = blk >> 8;
  const int m00 = mh2 * 1024;
  const int t_ = threadIdx.x, w = t_ >> 6, l = t_ & 63, lo4 = l & 15, g = l >> 4;
  const float invd = 1.0f / (cnt[b] + 1e-9f);
  const int n0 = nb * 64;
  bf16x8 aq[4];
#pragma unroll
  for (int ks = 0; ks < 4; ks++)
    aq[ks] = *(const bf16x8*)&qT[((size_t)(b * kN + n0 + w * 16 + lo4)) * kC4 +
                                 ks * 32 + g * 8];
  const int nq = n0 + w * 16 + g * 4;
  const int4 mi = *(const int4*)&mask[b * kN + nq];
  const int mn4[4] = {mi.x, mi.y, mi.z, mi.w};
  float rs4[4] = {0.0f, 0.0f, 0.0f, 0.0f};
  bf16x8 rg[4];
#pragma unroll
  for (int i = 0; i < 4; i++) {
    const int row = w * 16 + i * 4 + g;
    const int q = (l & 15) ^ (row & 7);
    rg[i] = *(const bf16x8*)&kT[((size_t)(b * kN + m00 + row)) * kC4 + q * 8];
  }
#pragma unroll
  for (int i = 0; i < 4; i++) {
    const int row = w * 16 + i * 4 + g;
    *(bf16x8*)&kts[0][row][(l & 15) * 8] = rg[i];
  }
  if (t_ < 16)
    *(int4*)&mss[0][t_ * 4] = *(const int4*)&mask[b * kN + m00 + t_ * 4];
  __syncthreads();
  for (int tt = 0; tt < 16; tt++) {
    const int buf = tt & 1;
    if (tt < 15) {
      const int m0 = m00 + (tt + 1) * 64;
#pragma unroll
      for (int i = 0; i < 4; i++) {
        const int row = w * 16 + i * 4 + g;
        const int q = (l & 15) ^ (row & 7);
        rg[i] = *(const bf16x8*)&kT[((size_t)(b * kN + m0 + row)) * kC4 + q * 8];
      }
    }
#pragma unroll
    for (int mf = 0; mf < 4; mf++) {
      f32x4 e = {};
#pragma unroll
      for (int ks = 0; ks < 4; ks++) {
        const bf16x8 bk =
            *(const bf16x8*)&kts[buf][mf * 16 + lo4]
                                 [((ks * 4 + g) ^ (lo4 & 7)) * 8];
        e = MFMA16(aq[ks], bk, e);
      }
      const int mmv = mss[buf][mf * 16 + lo4];
      bf16x4 pk;
#pragma unroll
      for (int r = 0; r < 4; r++) {
        const float u = mmv ? (mn4[r] ? __expf(e[r] * invd) : 1.0f) : 0.0f;
        pk[r] = (bf16)u;
        rs4[r] += (float)pk[r];
      }
      const int m = m00 + tt * 64 + mf * 16 + lo4;
      *(bf16x4*)&UT[((size_t)(b * kN + m)) * kN + nq] = pk;
    }
    if (tt < 15) {
#pragma unroll
      for (int i = 0; i < 4; i++) {
        const int row = w * 16 + i * 4 + g;
        *(bf16x8*)&kts[buf ^ 1][row][(l & 15) * 8] = rg[i];
      }
      if (t_ < 16)
        *(int4*)&mss[buf ^ 1][t_ * 4] =
            *(const int4*)&mask[b * kN + m00 + (tt + 1) * 64 + t_ * 4];
    }
    __syncthreads();
  }
#pragma unroll
  for (int r = 0; r < 4; r++) {
#pragma unroll
    for (int off = 1; off < 16; off <<= 1) rs4[r] += __shfl_xor(rs4[r], off);
  }
  if (lo4 == 0) {
#pragma unroll
    for (int r = 0; r < 4; r++) atomicAdd(&Ssum[b * kN + nq + r], rs4[r]);
  }
}

// ---------------- scale xv2 in place by 1/S[n]
__global__ __launch_bounds__(256) void k_scale(bf16* __restrict__ xv2,
                                               const float* __restrict__ Ssum) {
  const int blk = blockIdx.x;  // 512 = 8b x 64 parts
  const int b = blk & 7, part = blk >> 3;
  const size_t base = (size_t)b * (32 * kC * 64);
  for (int it = 0; it < 8; it++) {
    const int chunk = part * 2048 + it * 256 + threadIdx.x;
    const size_t e = (size_t)chunk * 8;
    const int n = ((int)(e >> 15)) * 64 + ((int)e & 63);
    bf16x8 v = *(bf16x8*)&xv2[base + e];
    const f32x4 s0 = *(const f32x4*)&Ssum[b * kN + n];
    const f32x4 s1 = *(const f32x4*)&Ssum[b * kN + n + 4];
    bf16x8 o;
#pragma unroll
    for (int j = 0; j < 4; j++) o[j] = (bf16)((float)v[j] / s0[j]);
#pragma unroll
    for (int j = 0; j < 4; j++) o[4 + j] = (bf16)((float)v[4 + j] / s1[j]);
    *(bf16x8*)&xv2[base + e] = o;
  }
}

// -------- pass 2: x_r^T[m][c] = sum_n UT[m][n]*xv2'[c][n]; h = x - x_r
// DEPTH-2 register staging: loads for iter t+2 issued at iter t, ds_write at
// end of iter t+1 -> HBM latency (~900cy) hidden across barriers (T14).
__global__ __launch_bounds__(256, 2) void k_attn2(
    const bf16* __restrict__ UT, const bf16* __restrict__ xv2,
    const float* __restrict__ x, bf16* __restrict__ hT) {
  __shared__ __align__(16) bf16 As[2][128][32];
  __shared__ __align__(16) bf16 Bs[2][128][32];
  const int blk = blockIdx.x;
  const int b = blk & 7, tile = blk >> 3;
  const int cb = tile & 3, mb = tile >> 2;
  const int m0 = mb * 128, c0 = cb * 128;
  const int t_ = threadIdx.x, w = t_ >> 6, l = t_ & 63, lo4 = l & 15, g = l >> 4;
  const int mh = w >> 1, ch = w & 1;
  const int srow = w * 16 + (l >> 2), sch = l & 3;
  const int spos = sch ^ ((l >> 3) & 3);
  const int rpos = g ^ ((lo4 >> 1) & 3);
  const bf16* gA0 = &UT[((size_t)(b * kN + m0 + srow)) * kN + sch * 8];
  const bf16* gA1 = gA0 + (size_t)64 * kN;
  const bf16* gB0 = &xv2[(((size_t)b * 32) * kC + c0 + srow) * 64 + sch * 8];
  const bf16* gB1 = gB0 + (size_t)64 * 64;
  f32x4 acc[4][4] = {};
  // prologue: iter0 -> LDS[0]; iter1 -> setO (pending)
  {
    const bf16x8 a0 = *(const bf16x8*)&gA0[0];
    const bf16x8 a1 = *(const bf16x8*)&gA1[0];
    const bf16x8 b0 = *(const bf16x8*)&gB0[0];
    const bf16x8 b1 = *(const bf16x8*)&gB1[0];
    *(bf16x8*)&As[0][srow][spos * 8] = a0;
    *(bf16x8*)&As[0][srow + 64][spos * 8] = a1;
    *(bf16x8*)&Bs[0][srow][spos * 8] = b0;
    *(bf16x8*)&Bs[0][srow + 64][spos * 8] = b1;
  }
  bf16x8 oA0, oA1, oB0, oB1;  // data for odd iters (written end of even iter)
  bf16x8 eA0, eA1, eB0, eB1;  // data for even iters (written end of odd iter)
  oA0 = *(const bf16x8*)&gA0[32];
  oA1 = *(const bf16x8*)&gA1[32];
  oB0 = *(const bf16x8*)&gB0[32];
  oB1 = *(const bf16x8*)&gB1[32];
  __syncthreads();
#define FRAGS_MFMA(BUF)                                                        \
  {                                                                            \
    bf16x8 af[4], bfr[4];                                                      \
    _Pragma("unroll") for (int mf = 0; mf < 4; mf++) af[mf] =                  \
        *(const bf16x8*)&As[BUF][mh * 64 + mf * 16 + lo4][rpos * 8];           \
    _Pragma("unroll") for (int cf = 0; cf < 4; cf++) bfr[cf] =                 \
        *(const bf16x8*)&Bs[BUF][ch * 64 + cf * 16 + lo4][rpos * 8];           \
    _Pragma("unroll") for (int mf = 0; mf < 4; mf++)                           \
        _Pragma("unroll") for (int cf = 0; cf < 4; cf++) acc[mf][cf] =         \
            MFMA16(af[mf], bfr[cf], acc[mf][cf]);                              \
  }
  for (int tt2 = 0; tt2 < 64; tt2 += 2) {
    // ---- even iter tt2 (buf 0)
    if (tt2 + 2 < 64) {
      const int n2 = tt2 + 2;
      eA0 = *(const bf16x8*)&gA0[n2 * 32];
      eA1 = *(const bf16x8*)&gA1[n2 * 32];
      const size_t bo = (size_t)(n2 >> 1) * (kC * 64) + (n2 & 1) * 32;
      eB0 = *(const bf16x8*)&gB0[bo];
      eB1 = *(const bf16x8*)&gB1[bo];
    }
    FRAGS_MFMA(0);
    // write iter tt2+1 data (loaded ~1.5 iters ago)
    *(bf16x8*)&As[1][srow][spos * 8] = oA0;
    *(bf16x8*)&As[1][srow + 64][spos * 8] = oA1;
    *(bf16x8*)&Bs[1][srow][spos * 8] = oB0;
    *(bf16x8*)&Bs[1][srow + 64][spos * 8] = oB1;
    __syncthreads();
    // ---- odd iter tt2+1 (buf 1)
    if (tt2 + 3 < 64) {
      const int n3 = tt2 + 3;
      oA0 = *(const bf16x8*)&gA0[n3 * 32];
      oA1 = *(const bf16x8*)&gA1[n3 * 32];
      const size_t bo = (size_t)(n3 >> 1) * (kC * 64) + (n3 & 1) * 32;
      oB0 = *(const bf16x8*)&gB0[bo];
      oB1 = *(const bf16x8*)&gB1[bo];
    }
    FRAGS_MFMA(1);
    if (tt2 + 2 < 64) {
      *(bf16x8*)&As[0][srow][spos * 8] = eA0;
      *(bf16x8*)&As[0][srow + 64][spos * 8] = eA1;
      *(bf16x8*)&Bs[0][srow][spos * 8] = eB0;
      *(bf16x8*)&Bs[0][srow + 64][spos * 8] = eB1;
    }
    __syncthreads();
  }
#undef FRAGS_MFMA
  // epilogue: h = x - x_r; per-wave LDS transpose (alias As) -> hT[m][c]
  bf16* bncw = ((bf16*)As) + w * 16 * 72;
#pragma unroll
  for (int mf = 0; mf < 4; mf++) {
    const int mbase = m0 + mh * 64 + mf * 16;
    float hh[4][4];
#pragma unroll
    for (int cf = 0; cf < 4; cf++) {
      const int c = c0 + ch * 64 + cf * 16 + lo4;
      const f32x4 xval =
          *(const f32x4*)&x[((size_t)(b * kC + c)) * kN + mbase + g * 4];
#pragma unroll
      for (int r = 0; r < 4; r++) hh[cf][r] = xval[r] - acc[mf][cf][r];
    }
#pragma unroll
    for (int cf = 0; cf < 4; cf++)
#pragma unroll
      for (int r = 0; r < 4; r++)
        bncw[(4 * g + r) * 72 + cf * 16 + lo4] = (bf16)hh[cf][r];
    {
      const int rr = l >> 2, seg = (l & 3) * 16;
      const bf16x8 v0 = *(const bf16x8*)&bncw[rr * 72 + seg];
      const bf16x8 v1 = *(const bf16x8*)&bncw[rr * 72 + seg + 8];
      bf16* orow =
          &hT[((size_t)(b * kN + mbase + rr)) * kC + c0 + ch * 64 + seg];
      *(bf16x8*)&orow[0] = v0;
      *(bf16x8*)&orow[8] = v1;
    }
  }
}

// -------- final: D[n][c] = hT[n][k] wt[c][k]; BN+ReLU+residual
__global__ __launch_bounds__(256, 2) void k_final(
    const bf16* __restrict__ hT, const bf16* __restrict__ wt_bf,
    const float* __restrict__ x, const float* __restrict__ bt,
    const float* __restrict__ beta, const float* __restrict__ rmean,
    const float* __restrict__ invg, float* __restrict__ out) {
  __shared__ __align__(16) bf16 As[2][128][32];
  __shared__ __align__(16) bf16 Bs[2][128][32];
  const int blk = blockIdx.x;  // 512 = 8b x (16nb x 4cb)
  const int b = blk & 7, tile = blk >> 3;
  const int cb = tile & 3, nb = tile >> 2;
  const int n0 = nb * 128, c0 = cb * 128;
  const int t_ = threadIdx.x, w = t_ >> 6, l = t_ & 63, lo4 = l & 15, g = l >> 4;
  const int mh = w >> 1, ch = w & 1;
  const int srow = w * 16 + (l >> 2), sch = l & 3;
  const int spos = sch ^ ((l >> 3) & 3);
  const int rpos = g ^ ((lo4 >> 1) & 3);
  const bf16* gA0 = &hT[((size_t)(b * kN + n0 + srow)) * kC + sch * 8];
  const bf16* gA1 = gA0 + (size_t)64 * kC;
  const bf16* gB0 = &wt_bf[(size_t)(c0 + srow) * kC + sch * 8];
  const bf16* gB1 = gB0 + (size_t)64 * kC;
  f32x4 acc[4][4] = {};
  bf16x8 ra0, ra1, rb0, rb1;
  ra0 = *(const bf16x8*)&gA0[0];
  ra1 = *(const bf16x8*)&gA1[0];
  rb0 = *(const bf16x8*)&gB0[0];
  rb1 = *(const bf16x8*)&gB1[0];
  *(bf16x8*)&As[0][srow][spos * 8] = ra0;
  *(bf16x8*)&As[0][srow + 64][spos * 8] = ra1;
  *(bf16x8*)&Bs[0][srow][spos * 8] = rb0;
  *(bf16x8*)&Bs[0][srow + 64][spos * 8] = rb1;
  __syncthreads();
  for (int tt = 0; tt < 16; tt++) {
    const int buf = tt & 1;
    if (tt < 15) {
      const int k0 = (tt + 1) * 32;
      ra0 = *(const bf16x8*)&gA0[k0];
      ra1 = *(const bf16x8*)&gA1[k0];
      rb0 = *(const bf16x8*)&gB0[k0];
      rb1 = *(const bf16x8*)&gB1[k0];
    }
    bf16x8 af[4], bfr[4];
#pragma unroll
    for (int nf = 0; nf < 4; nf++)
      af[nf] = *(const bf16x8*)&As[buf][mh * 64 + nf * 16 + lo4][rpos * 8];
#pragma unroll
    for (int cf = 0; cf < 4; cf++)
      bfr[cf] = *(const bf16x8*)&Bs[buf][ch * 64 + cf * 16 + lo4][rpos * 8];
#pragma unroll
    for (int nf = 0; nf < 4; nf++)
#pragma unroll
      for (int cf = 0; cf < 4; cf++)
        acc[nf][cf] = MFMA16(af[nf], bfr[cf], acc[nf][cf]);
    if (tt < 15) {
      *(bf16x8*)&As[buf ^ 1][srow][spos * 8] = ra0;
      *(bf16x8*)&As[buf ^ 1][srow + 64][spos * 8] = ra1;
      *(bf16x8*)&Bs[buf ^ 1][srow][spos * 8] = rb0;
      *(bf16x8*)&Bs[buf ^ 1][srow + 64][spos * 8] = rb1;
    }
    __syncthreads();
  }
#pragma unroll
  for (int cf = 0; cf < 4; cf++) {
    const int c = c0 + ch * 64 + cf * 16 + lo4;
    const float btv = bt[c], rmv = rmean[c], igv = invg[c], bev = beta[c];
#pragma unroll
    for (int nf = 0; nf < 4; nf++) {
      const int nbase = n0 + mh * 64 + nf * 16 + g * 4;
      const size_t base = ((size_t)(b * kC + c)) * kN + nbase;
      const f32x4 xval = *(const f32x4*)&x[base];
      f32x4 o;
#pragma unroll
      for (int r = 0; r < 4; r++) {
        float v = (acc[nf][cf][r] + btv - rmv) * igv + bev;
        v = fmaxf(v, 0.0f);
        o[r] = xval[r] + v;
      }
      *(f32x4*)&out[base] = o;
    }
  }
}

extern "C" void kernel_launch(void* const* d_in, const int* in_sizes, int n_in,
                              void* d_out, int out_size, void* d_ws,
                              size_t ws_size, hipStream_t stream) {
  const float* x = (const float*)d_in[0];
  const float* query = (const float*)d_in[1];
  const int* mask = (const int*)d_in[2];
  const float* wqk = (const float*)d_in[3];
  const float* wv = (const float*)d_in[4];
  const float* bv = (const float*)d_in[5];
  const float* wt = (const float*)d_in[6];
  const float* bt = (const float*)d_in[7];
  const float* gamma = (const float*)d_in[8];
  const float* beta = (const float*)d_in[9];
  const float* rmean = (const float*)d_in[10];
  const float* rvar = (const float*)d_in[11];
  float* out = (float*)d_out;
  char* wsb = (char*)d_ws;

  const size_t MB = 1024 * 1024;
  bf16* UT = (bf16*)wsb;                        // 64 MB [b][m][n]
  bf16* trbufQ = (bf16*)wsb;                    // 16 MB (in UT dead zone)
  bf16* trbufX = (bf16*)(wsb + 16 * MB);        // 16 MB (in UT dead zone)
  bf16* xv2 = (bf16*)(wsb + 64 * MB);           // 16 MB tiled
  bf16* hT = (bf16*)(wsb + 80 * MB);            // 8 MB [b][n][c]
  bf16* qT = (bf16*)(wsb + 88 * MB);            // 4 MB
  bf16* kT = (bf16*)(wsb + 92 * MB);            // 4 MB
  bf16* wqk_bf = (bf16*)(wsb + 96 * MB);        // 128 KB
  bf16* wv_bf = wqk_bf + 65536;                 // 512 KB
  bf16* wt_bf = wv_bf + 262144;                 // 512 KB
  float* invg = (float*)(wt_bf + 262144);       // 2 KB
  float* Ssum = invg + 512;                     // 64 KB
  float* cnt = Ssum + kB * kN;                  // 32 B

  k_prep<<<136, 256, 0, stream>>>(mask, wqk, wv, wt, gamma, rvar, cnt, wqk_bf,
                                  wv_bf, wt_bf, invg, Ssum);
  k_tr2<<<dim3(kN / 64, kC / 32, 16), 256, 0, stream>>>(query, x, trbufQ,
                                                        trbufX);
  k_projQK<<<dim3(16, kB, 2), 256, 0, stream>>>(trbufQ, trbufX, wqk_bf, qT,
                                                kT);
  k_projV<<<512, 256, 0, stream>>>(trbufX, wv_bf, bv, xv2);
  k_sum<<<512, 256, 0, stream>>>(qT, kT, mask, cnt, UT, Ssum);
  k_scale<<<512, 256, 0, stream>>>(xv2, Ssum);
  k_attn2<<<512, 256, 0, stream>>>(UT, xv2, x, hT);
  k_final<<<512, 256, 0, stream>>>(hT, wt_bf, x, bt, beta, rmean, invg, out);
}